// Round 1
// baseline (931.374 us; speedup 1.0000x reference)
//
#include <hip/hip_runtime.h>
#include <math.h>

#define N_NODES 20000
#define N_EDGES 320000
#define NB 128
#define H 32
#define AF 64
#define BF 16

// h[n,o] = sum_k nf[n,k]*W[k,o] + b[o]
__global__ __launch_bounds__(256) void embed_nodes(const float* __restrict__ nf,
    const float* __restrict__ W, const float* __restrict__ b, float* __restrict__ h) {
  __shared__ float Ws[AF * H];     // 8 KB
  __shared__ float nfs[8][AF];
  int tid = threadIdx.x;
  for (int v = tid; v < AF * H; v += 256) Ws[v] = W[v];
  int n0 = blockIdx.x * 8;
  for (int v = tid; v < 8 * AF; v += 256) {
    int nl = v / AF, k = v % AF;
    int n = n0 + nl;
    nfs[nl][k] = (n < N_NODES) ? nf[n * AF + k] : 0.0f;
  }
  __syncthreads();
  int nl = tid / H, o = tid % H;
  int n = n0 + nl;
  if (n >= N_NODES) return;
  float acc = b[o];
#pragma unroll
  for (int k = 0; k < AF; k++) acc += nfs[nl][k] * Ws[k * H + o];
  h[n * H + o] = acc;
}

// r[e,o] = relu( (ef[e]@Wb + bb) @ We1 + be1 )[o]
__global__ __launch_bounds__(256) void edge_r(const float* __restrict__ ef,
    const float* __restrict__ Wb, const float* __restrict__ bb,
    const float* __restrict__ We1, const float* __restrict__ be1,
    float* __restrict__ r) {
  __shared__ float Wbs[BF * H];   // 2 KB
  __shared__ float W1s[H * H];    // 4 KB
  __shared__ float efs[8][BF];
  __shared__ float hbs[8][H + 1]; // +1 pad: broadcast reads anyway, cheap safety
  int tid = threadIdx.x;
  for (int v = tid; v < BF * H; v += 256) Wbs[v] = Wb[v];
  for (int v = tid; v < H * H; v += 256) W1s[v] = We1[v];
  int e0 = blockIdx.x * 8;
  for (int v = tid; v < 8 * BF; v += 256) {
    int el = v / BF, k = v % BF;
    int e = e0 + el;
    efs[el][k] = (e < N_EDGES) ? ef[e * BF + k] : 0.0f;
  }
  __syncthreads();
  int el = tid / H, o = tid % H;
  float hb = bb[o];
#pragma unroll
  for (int k = 0; k < BF; k++) hb += efs[el][k] * Wbs[k * H + o];
  hbs[el][o] = hb;
  __syncthreads();
  int e = e0 + el;
  if (e >= N_EDGES) return;
  float acc = be1[o];
#pragma unroll
  for (int j = 0; j < H; j++) acc += hbs[el][j] * W1s[j * H + o];
  r[e * H + o] = fmaxf(acc, 0.0f);
}

__global__ void deg_accum(const int* __restrict__ dst, float* __restrict__ deg) {
  int e = blockIdx.x * 256 + threadIdx.x;
  if (e < N_EDGES) atomicAdd(&deg[dst[e]], 1.0f);
}

__global__ void deg_inv(float* deg) {
  int n = blockIdx.x * 256 + threadIdx.x;
  if (n < N_NODES) deg[n] = 1.0f / fmaxf(deg[n], 1.0f);
}

// T[n,j,o] = sum_i h[n,i] * We2[j, i*H+o].  blockIdx.y = j, block handles 8 nodes.
__global__ __launch_bounds__(256) void compute_T(const float* __restrict__ h,
    const float* __restrict__ We2, float* __restrict__ T) {
  int j = blockIdx.y;
  __shared__ float Ws[H * H];   // We2 slice for this j: 4 KB
  __shared__ float hs[8][H];
  int tid = threadIdx.x;
  for (int v = tid; v < H * H; v += 256) Ws[v] = We2[j * (H * H) + v];
  int n0 = blockIdx.x * 8;
  for (int v = tid; v < 8 * H; v += 256) {
    int nl = v / H, i = v % H;
    int n = n0 + nl;
    hs[nl][i] = (n < N_NODES) ? h[n * H + i] : 0.0f;
  }
  __syncthreads();
  int nl = tid / H, o = tid % H;
  int n = n0 + nl;
  if (n >= N_NODES) return;
  float acc = 0.0f;
#pragma unroll
  for (int i = 0; i < H; i++) acc += hs[nl][i] * Ws[i * H + o];
  T[(size_t)n * (H * H) + j * H + o] = acc;
}

// hbias[n,o] = sum_i h[n,i] * be2[i*H+o]
__global__ void compute_hbias(const float* __restrict__ h, const float* __restrict__ be2,
                              float* __restrict__ hbias) {
  int idx = blockIdx.x * 256 + threadIdx.x;
  if (idx >= N_NODES * H) return;
  int n = idx / H, o = idx % H;
  float acc = 0.0f;
#pragma unroll
  for (int i = 0; i < H; i++) acc += h[n * H + i] * be2[i * H + o];
  hbias[idx] = acc;
}

// msg[e,o] = sum_j r[e,j]*T[src,j,o] + hbias[src,o]; atomically into agg[dst].
// 256 thr = 32 edges x 8 lanes; lane t handles o = 4t..4t+3 (float4).
__global__ __launch_bounds__(256) void edge_msg_agg(const float* __restrict__ r,
    const float* __restrict__ T, const float* __restrict__ hbias,
    const int* __restrict__ src, const int* __restrict__ dst,
    float* __restrict__ agg) {
  __shared__ float rs[32][H + 1];   // pad -> conflict-free broadcast
  int tid = threadIdx.x;
  int e0 = blockIdx.x * 32;
  for (int v = tid; v < 32 * H; v += 256) {
    int el = v / H, j = v % H;
    int e = e0 + el;
    rs[el][j] = (e < N_EDGES) ? r[e * H + j] : 0.0f;
  }
  __syncthreads();
  int el = tid / 8;
  int t = tid % 8;
  int e = e0 + el;
  if (e >= N_EDGES) return;
  int s = src[e], d = dst[e];
  const float4* Tp = (const float4*)(T + (size_t)s * (H * H));
  float4 acc = ((const float4*)(hbias + (size_t)s * H))[t];
#pragma unroll 8
  for (int j = 0; j < H; j++) {
    float rj = rs[el][j];
    float4 w = Tp[j * 8 + t];
    acc.x += rj * w.x; acc.y += rj * w.y; acc.z += rj * w.z; acc.w += rj * w.w;
  }
  float* ap = agg + (size_t)d * H + t * 4;
  atomicAdd(ap + 0, acc.x);
  atomicAdd(ap + 1, acc.y);
  atomicAdd(ap + 2, acc.z);
  atomicAdd(ap + 3, acc.w);
}

// GRU cell, in-place on h. 8 nodes/block, 32 lanes/node.
__global__ __launch_bounds__(256) void gru_update(const float* __restrict__ agg,
    const float* __restrict__ invdeg, const float* __restrict__ Wih,
    const float* __restrict__ Whh, const float* __restrict__ bih,
    const float* __restrict__ bhh, float* __restrict__ h) {
  __shared__ float Wis[3 * H][H + 1];  // pad +1: lanes read row o -> banks (o+i)%32
  __shared__ float Whs[3 * H][H + 1];
  __shared__ float xs[8][H + 1];
  __shared__ float hs[8][H + 1];
  int tid = threadIdx.x;
  for (int v = tid; v < 3 * H * H; v += 256) {
    int k = v / H, i = v % H;
    Wis[k][i] = Wih[v];
    Whs[k][i] = Whh[v];
  }
  int n0 = blockIdx.x * 8;
  for (int v = tid; v < 8 * H; v += 256) {
    int nl = v / H, i = v % H;
    int n = n0 + nl;
    float x = 0.0f, hh = 0.0f;
    if (n < N_NODES) {
      x = fmaxf(agg[n * H + i] * invdeg[n], 0.0f);   // m = relu(mean-agg)
      hh = h[n * H + i];
    }
    xs[nl][i] = x;
    hs[nl][i] = hh;
  }
  __syncthreads();
  int nl = tid / H, o = tid % H;
  int n = n0 + nl;
  if (n >= N_NODES) return;
  float gi0 = bih[o], gi1 = bih[H + o], gi2 = bih[2 * H + o];
  float gh0 = bhh[o], gh1 = bhh[H + o], gh2 = bhh[2 * H + o];
#pragma unroll
  for (int i = 0; i < H; i++) {
    float xi = xs[nl][i], hi = hs[nl][i];
    gi0 += xi * Wis[o][i];
    gh0 += hi * Whs[o][i];
    gi1 += xi * Wis[H + o][i];
    gh1 += hi * Whs[H + o][i];
    gi2 += xi * Wis[2 * H + o][i];
    gh2 += hi * Whs[2 * H + o][i];
  }
  float rg = 1.0f / (1.0f + expf(-(gi0 + gh0)));
  float zg = 1.0f / (1.0f + expf(-(gi1 + gh1)));
  float ng = tanhf(gi2 + rg * gh2);
  float ho = hs[nl][o];
  h[n * H + o] = (1.0f - zg) * ng + zg * ho;
}

__global__ void readout_sum(const float* __restrict__ h, const int* __restrict__ gid,
                            float* __restrict__ gsum, float* __restrict__ gcnt) {
  int idx = blockIdx.x * 256 + threadIdx.x;
  if (idx >= N_NODES * H) return;
  int n = idx / H, o = idx % H;
  int g = gid[n];
  atomicAdd(&gsum[g * H + o], h[idx]);
  if (o == 0) atomicAdd(&gcnt[g], 1.0f);
}

__global__ void readout_div(const float* __restrict__ gsum, const float* __restrict__ gcnt,
                            float* __restrict__ out) {
  int idx = blockIdx.x * 256 + threadIdx.x;
  if (idx >= NB * H) return;
  int g = idx / H;
  out[idx] = gsum[idx] / fmaxf(gcnt[g], 1.0f);
}

extern "C" void kernel_launch(void* const* d_in, const int* in_sizes, int n_in,
                              void* d_out, int out_size, void* d_ws, size_t ws_size,
                              hipStream_t stream) {
  const float* n_feat = (const float*)d_in[0];
  const float* e_feat = (const float*)d_in[1];
  const int*   src    = (const int*)d_in[2];
  const int*   dst    = (const int*)d_in[3];
  const int*   gid    = (const int*)d_in[4];
  const float* W_atom = (const float*)d_in[5];
  const float* b_atom = (const float*)d_in[6];
  const float* W_bond = (const float*)d_in[7];
  const float* b_bond = (const float*)d_in[8];
  const float* W_e1   = (const float*)d_in[9];
  const float* b_e1   = (const float*)d_in[10];
  const float* W_e2   = (const float*)d_in[11];
  const float* b_e2   = (const float*)d_in[12];
  const float* W_ih   = (const float*)d_in[13];
  const float* W_hh   = (const float*)d_in[14];
  const float* b_ih   = (const float*)d_in[15];
  const float* b_hh   = (const float*)d_in[16];
  float* out = (float*)d_out;

  // workspace carve-up (all fp32)
  char* ws = (char*)d_ws;
  size_t off = 0;
  float* h     = (float*)(ws + off); off += (size_t)N_NODES * H * 4;       // 2.56 MB
  float* rbuf  = (float*)(ws + off); off += (size_t)N_EDGES * H * 4;       // 40.96 MB
  float* T     = (float*)(ws + off); off += (size_t)N_NODES * H * H * 4;   // 81.92 MB
  float* hbias = (float*)(ws + off); off += (size_t)N_NODES * H * 4;       // 2.56 MB
  float* agg   = (float*)(ws + off); off += (size_t)N_NODES * H * 4;       // 2.56 MB
  float* deg   = (float*)(ws + off); off += (size_t)N_NODES * 4;           // 80 KB
  float* gsum  = (float*)(ws + off); off += (size_t)NB * H * 4;            // 16 KB
  float* gcnt  = (float*)(ws + off); off += (size_t)NB * 4;

  // node embedding + edge-net first layer (layer-invariant)
  embed_nodes<<<N_NODES / 8, 256, 0, stream>>>(n_feat, W_atom, b_atom, h);
  edge_r<<<N_EDGES / 8, 256, 0, stream>>>(e_feat, W_bond, b_bond, W_e1, b_e1, rbuf);

  // in-degree -> inverse
  hipMemsetAsync(deg, 0, (size_t)N_NODES * 4, stream);
  deg_accum<<<(N_EDGES + 255) / 256, 256, 0, stream>>>(dst, deg);
  deg_inv<<<(N_NODES + 255) / 256, 256, 0, stream>>>(deg);

  for (int layer = 0; layer < 2; layer++) {
    dim3 gT(N_NODES / 8, H);
    compute_T<<<gT, 256, 0, stream>>>(h, W_e2, T);
    compute_hbias<<<(N_NODES * H + 255) / 256, 256, 0, stream>>>(h, b_e2, hbias);
    hipMemsetAsync(agg, 0, (size_t)N_NODES * H * 4, stream);
    edge_msg_agg<<<N_EDGES / 32, 256, 0, stream>>>(rbuf, T, hbias, src, dst, agg);
    gru_update<<<N_NODES / 8, 256, 0, stream>>>(agg, deg, W_ih, W_hh, b_ih, b_hh, h);
  }

  // graph mean readout
  hipMemsetAsync(gsum, 0, (size_t)(NB * H + NB) * 4, stream);
  readout_sum<<<(N_NODES * H + 255) / 256, 256, 0, stream>>>(h, gid, gsum, gcnt);
  readout_div<<<(NB * H + 255) / 256, 256, 0, stream>>>(gsum, gcnt, out);
}

// Round 2
// 701.105 us; speedup vs baseline: 1.3284x; 1.3284x over previous
//
#include <hip/hip_runtime.h>
#include <math.h>

#define N_NODES 20000
#define N_EDGES 320000
#define NB 128
#define H 32
#define AF 64
#define BF 16

// ---------------- node embedding: h = nf @ W_atom + b ----------------
__global__ __launch_bounds__(256) void embed_nodes(const float* __restrict__ nf,
    const float* __restrict__ W, const float* __restrict__ b, float* __restrict__ h) {
  __shared__ float Ws[AF * H];     // 8 KB
  __shared__ float nfs[8][AF];
  int tid = threadIdx.x;
  for (int v = tid; v < AF * H; v += 256) Ws[v] = W[v];
  int n0 = blockIdx.x * 8;
  for (int v = tid; v < 8 * AF; v += 256) {
    int nl = v / AF, k = v % AF;
    int n = n0 + nl;
    nfs[nl][k] = (n < N_NODES) ? nf[n * AF + k] : 0.0f;
  }
  __syncthreads();
  int nl = tid / H, o = tid % H;
  int n = n0 + nl;
  if (n >= N_NODES) return;
  float acc = b[o];
#pragma unroll
  for (int k = 0; k < AF; k++) acc += nfs[nl][k] * Ws[k * H + o];
  h[n * H + o] = acc;
}

// ---------------- counting sort of edges by src ----------------
__global__ void hist_src(const int* __restrict__ src, int* __restrict__ hist) {
  int e = blockIdx.x * 256 + threadIdx.x;
  if (e < N_EDGES) atomicAdd(&hist[src[e]], 1);
}

// single-block exclusive scan over N_NODES ints -> base and cursor
__global__ __launch_bounds__(1024) void exscan(const int* __restrict__ hist,
    int* __restrict__ cursor) {
  __shared__ int wsum[16];
  __shared__ int carry;
  if (threadIdx.x == 0) carry = 0;
  __syncthreads();
  int lid = threadIdx.x & 63, wid = threadIdx.x >> 6;
  for (int start = 0; start < N_NODES; start += 1024) {
    int i = start + threadIdx.x;
    int v = (i < N_NODES) ? hist[i] : 0;
    int incl = v;
#pragma unroll
    for (int off = 1; off < 64; off <<= 1) {
      int t = __shfl_up(incl, off, 64);
      if (lid >= off) incl += t;
    }
    if (lid == 63) wsum[wid] = incl;
    __syncthreads();
    if (threadIdx.x == 0) {
      int run = carry;
#pragma unroll
      for (int w = 0; w < 16; w++) { int t = wsum[w]; wsum[w] = run; run += t; }
      carry = run;
    }
    __syncthreads();
    int ex = wsum[wid] + incl - v;
    if (i < N_NODES) cursor[i] = ex;
    __syncthreads();
  }
}

__global__ void scatter_edges(const int* __restrict__ src, const int* __restrict__ dst,
    int* __restrict__ cursor, int* __restrict__ src_s, int* __restrict__ dst_s,
    int* __restrict__ eidx) {
  int e = blockIdx.x * 256 + threadIdx.x;
  if (e >= N_EDGES) return;
  int s = src[e];
  int pos = atomicAdd(&cursor[s], 1);
  src_s[pos] = s;
  dst_s[pos] = dst[e];
  eidx[pos] = e;
}

// ---------------- edge hidden: r = relu((ef@Wb+bb)@We1+be1), sorted order ----------------
// 32 edges/block, gathered through eidx.
__global__ __launch_bounds__(256) void edge_r(const float* __restrict__ ef,
    const float* __restrict__ Wb, const float* __restrict__ bb,
    const float* __restrict__ We1, const float* __restrict__ be1,
    const int* __restrict__ eidx, float* __restrict__ r) {
  __shared__ float Wbs[BF * H];   // 2 KB
  __shared__ float W1s[H * H];    // 4 KB
  __shared__ float efs[32][BF + 1];
  __shared__ float hbs[32][H + 1];
  int tid = threadIdx.x;
  for (int v = tid; v < BF * H; v += 256) Wbs[v] = Wb[v];
  for (int v = tid; v < H * H; v += 256) W1s[v] = We1[v];
  int e0 = blockIdx.x * 32;
  for (int v = tid; v < 32 * BF; v += 256) {
    int el = v >> 4, k = v & 15;
    int ee = eidx[e0 + el];
    efs[el][k] = ef[ee * BF + k];
  }
  __syncthreads();
  int el = tid >> 3, oq = tid & 7, o0 = oq * 4;
  const float4* Wb4 = (const float4*)Wbs;
  const float4* W14 = (const float4*)W1s;
  float4 hb = ((const float4*)bb)[oq];
#pragma unroll
  for (int kk = 0; kk < BF; kk++) {
    float e_ = efs[el][kk];
    float4 w = Wb4[kk * 8 + oq];
    hb.x += e_ * w.x; hb.y += e_ * w.y; hb.z += e_ * w.z; hb.w += e_ * w.w;
  }
  hbs[el][o0 + 0] = hb.x; hbs[el][o0 + 1] = hb.y;
  hbs[el][o0 + 2] = hb.z; hbs[el][o0 + 3] = hb.w;
  __syncthreads();
  float4 acc = ((const float4*)be1)[oq];
#pragma unroll
  for (int j = 0; j < H; j++) {
    float hj = hbs[el][j];
    float4 w = W14[j * 8 + oq];
    acc.x += hj * w.x; acc.y += hj * w.y; acc.z += hj * w.z; acc.w += hj * w.w;
  }
  acc.x = fmaxf(acc.x, 0.0f); acc.y = fmaxf(acc.y, 0.0f);
  acc.z = fmaxf(acc.z, 0.0f); acc.w = fmaxf(acc.w, 0.0f);
  ((float4*)(r + (size_t)(e0 + el) * H))[oq] = acc;
}

// ---------------- in-degree ----------------
__global__ void deg_accum(const int* __restrict__ dst, float* __restrict__ deg) {
  int e = blockIdx.x * 256 + threadIdx.x;
  if (e < N_EDGES) atomicAdd(&deg[dst[e]], 1.0f);
}

__global__ void deg_inv(float* deg) {
  int n = blockIdx.x * 256 + threadIdx.x;
  if (n < N_NODES) deg[n] = 1.0f / fmaxf(deg[n], 1.0f);
}

// ---------------- T[n,j,o] = sum_i h[n,i]*We2[j,i*H+o]; j=32 iter does hbias with be2 ----
// 32 nodes/block, 625 blocks. h cached in registers; 4 KB We2 slice per j in LDS.
__global__ __launch_bounds__(256) void compute_T_fused(const float* __restrict__ h,
    const float* __restrict__ We2, const float* __restrict__ be2,
    float* __restrict__ T, float* __restrict__ hbias) {
  __shared__ float hs[32][H + 1];
  __shared__ float Ws[H * H];     // 4 KB slice
  int tid = threadIdx.x;
  int n0 = blockIdx.x * 32;
  for (int v = tid; v < 32 * H; v += 256) {
    int nl = v >> 5, i = v & 31;
    int n = n0 + nl;
    hs[nl][i] = (n < N_NODES) ? h[n * H + i] : 0.0f;
  }
  __syncthreads();
  int nl = tid >> 3, oq = tid & 7;
  float hreg[H];
#pragma unroll
  for (int i = 0; i < H; i++) hreg[i] = hs[nl][i];
  int n = n0 + nl;
  const float4* W4 = (const float4*)Ws;
  for (int j = 0; j < H + 1; j++) {
    const float* srcW = (j < H) ? (We2 + (size_t)j * (H * H)) : be2;
    ((float4*)Ws)[tid] = ((const float4*)srcW)[tid];
    __syncthreads();
    float4 acc = make_float4(0.f, 0.f, 0.f, 0.f);
#pragma unroll
    for (int i = 0; i < H; i++) {
      float hi = hreg[i];
      float4 w = W4[i * 8 + oq];
      acc.x += hi * w.x; acc.y += hi * w.y; acc.z += hi * w.z; acc.w += hi * w.w;
    }
    if (n < N_NODES) {
      if (j < H) ((float4*)(T + (size_t)n * (H * H) + j * H))[oq] = acc;
      else       ((float4*)(hbias + (size_t)n * H))[oq] = acc;
    }
    __syncthreads();   // protect Ws before next iteration's overwrite
  }
}

// ---------------- msg + scatter-add, edges sorted by src ----------------
// 32 edges/block, 8 lanes/edge (float4 over o). XCD-aware swizzle: each XCD
// gets a contiguous edge range so shared T rows stay in its L2.
__global__ __launch_bounds__(256) void edge_msg_agg(const float* __restrict__ r,
    const float* __restrict__ T, const float* __restrict__ hbias,
    const int* __restrict__ src_s, const int* __restrict__ dst_s,
    float* __restrict__ agg) {
  __shared__ float rs[32][H + 1];
  int tid = threadIdx.x;
  int nchunk = gridDim.x;                       // 10000, divisible by 8
  int c = (blockIdx.x & 7) * (nchunk >> 3) + (blockIdx.x >> 3);
  int e0 = c * 32;
  for (int v = tid; v < 32 * H; v += 256) {
    int el = v >> 5, j = v & 31;
    rs[el][j] = r[(size_t)(e0 + el) * H + j];
  }
  __syncthreads();
  int el = tid >> 3;
  int t = tid & 7;
  int e = e0 + el;
  int s = src_s[e], d = dst_s[e];
  const float4* Tp = (const float4*)(T + (size_t)s * (H * H));
  float4 acc = ((const float4*)(hbias + (size_t)s * H))[t];
#pragma unroll 8
  for (int j = 0; j < H; j++) {
    float rj = rs[el][j];
    float4 w = Tp[j * 8 + t];
    acc.x += rj * w.x; acc.y += rj * w.y; acc.z += rj * w.z; acc.w += rj * w.w;
  }
  float* ap = agg + (size_t)d * H + t * 4;
  atomicAdd(ap + 0, acc.x);
  atomicAdd(ap + 1, acc.y);
  atomicAdd(ap + 2, acc.z);
  atomicAdd(ap + 3, acc.w);
}

// ---------------- GRU cell, in-place on h ----------------
__global__ __launch_bounds__(256) void gru_update(const float* __restrict__ agg,
    const float* __restrict__ invdeg, const float* __restrict__ Wih,
    const float* __restrict__ Whh, const float* __restrict__ bih,
    const float* __restrict__ bhh, float* __restrict__ h) {
  __shared__ float Wis[3 * H][H + 1];
  __shared__ float Whs[3 * H][H + 1];
  __shared__ float xs[8][H + 1];
  __shared__ float hs[8][H + 1];
  int tid = threadIdx.x;
  for (int v = tid; v < 3 * H * H; v += 256) {
    int k = v / H, i = v % H;
    Wis[k][i] = Wih[v];
    Whs[k][i] = Whh[v];
  }
  int n0 = blockIdx.x * 8;
  for (int v = tid; v < 8 * H; v += 256) {
    int nl = v / H, i = v % H;
    int n = n0 + nl;
    float x = 0.0f, hh = 0.0f;
    if (n < N_NODES) {
      x = fmaxf(agg[n * H + i] * invdeg[n], 0.0f);   // m = relu(mean-agg)
      hh = h[n * H + i];
    }
    xs[nl][i] = x;
    hs[nl][i] = hh;
  }
  __syncthreads();
  int nl = tid / H, o = tid % H;
  int n = n0 + nl;
  if (n >= N_NODES) return;
  float gi0 = bih[o], gi1 = bih[H + o], gi2 = bih[2 * H + o];
  float gh0 = bhh[o], gh1 = bhh[H + o], gh2 = bhh[2 * H + o];
#pragma unroll
  for (int i = 0; i < H; i++) {
    float xi = xs[nl][i], hi = hs[nl][i];
    gi0 += xi * Wis[o][i];
    gh0 += hi * Whs[o][i];
    gi1 += xi * Wis[H + o][i];
    gh1 += hi * Whs[H + o][i];
    gi2 += xi * Wis[2 * H + o][i];
    gh2 += hi * Whs[2 * H + o][i];
  }
  float rg = 1.0f / (1.0f + expf(-(gi0 + gh0)));
  float zg = 1.0f / (1.0f + expf(-(gi1 + gh1)));
  float ng = tanhf(gi2 + rg * gh2);
  float ho = hs[nl][o];
  h[n * H + o] = (1.0f - zg) * ng + zg * ho;
}

// ---------------- graph mean readout ----------------
__global__ void readout_sum(const float* __restrict__ h, const int* __restrict__ gid,
                            float* __restrict__ gsum, float* __restrict__ gcnt) {
  int idx = blockIdx.x * 256 + threadIdx.x;
  if (idx >= N_NODES * H) return;
  int n = idx / H, o = idx % H;
  int g = gid[n];
  atomicAdd(&gsum[g * H + o], h[idx]);
  if (o == 0) atomicAdd(&gcnt[g], 1.0f);
}

__global__ void readout_div(const float* __restrict__ gsum, const float* __restrict__ gcnt,
                            float* __restrict__ out) {
  int idx = blockIdx.x * 256 + threadIdx.x;
  if (idx >= NB * H) return;
  int g = idx / H;
  out[idx] = gsum[idx] / fmaxf(gcnt[g], 1.0f);
}

extern "C" void kernel_launch(void* const* d_in, const int* in_sizes, int n_in,
                              void* d_out, int out_size, void* d_ws, size_t ws_size,
                              hipStream_t stream) {
  const float* n_feat = (const float*)d_in[0];
  const float* e_feat = (const float*)d_in[1];
  const int*   src    = (const int*)d_in[2];
  const int*   dst    = (const int*)d_in[3];
  const int*   gid    = (const int*)d_in[4];
  const float* W_atom = (const float*)d_in[5];
  const float* b_atom = (const float*)d_in[6];
  const float* W_bond = (const float*)d_in[7];
  const float* b_bond = (const float*)d_in[8];
  const float* W_e1   = (const float*)d_in[9];
  const float* b_e1   = (const float*)d_in[10];
  const float* W_e2   = (const float*)d_in[11];
  const float* b_e2   = (const float*)d_in[12];
  const float* W_ih   = (const float*)d_in[13];
  const float* W_hh   = (const float*)d_in[14];
  const float* b_ih   = (const float*)d_in[15];
  const float* b_hh   = (const float*)d_in[16];
  float* out = (float*)d_out;

  // workspace carve-up (all fp32 / int32)
  char* ws = (char*)d_ws;
  size_t off = 0;
  float* h     = (float*)(ws + off); off += (size_t)N_NODES * H * 4;       // 2.56 MB
  float* rbuf  = (float*)(ws + off); off += (size_t)N_EDGES * H * 4;       // 40.96 MB
  float* T     = (float*)(ws + off); off += (size_t)N_NODES * H * H * 4;   // 81.92 MB
  float* hbias = (float*)(ws + off); off += (size_t)N_NODES * H * 4;       // 2.56 MB
  float* agg   = (float*)(ws + off); off += (size_t)N_NODES * H * 4;       // 2.56 MB
  float* deg   = (float*)(ws + off); off += (size_t)N_NODES * 4;           // 80 KB
  float* gsum  = (float*)(ws + off); off += (size_t)NB * H * 4;
  float* gcnt  = (float*)(ws + off); off += (size_t)NB * 4;
  int*   hist  = (int*)(ws + off);   off += (size_t)N_NODES * 4;
  int*   cursor= (int*)(ws + off);   off += (size_t)N_NODES * 4;
  int*   src_s = (int*)(ws + off);   off += (size_t)N_EDGES * 4;           // 1.28 MB
  int*   dst_s = (int*)(ws + off);   off += (size_t)N_EDGES * 4;           // 1.28 MB
  int*   eidx  = (int*)T;  // alias: only needed before first compute_T

  // node embedding
  embed_nodes<<<N_NODES / 8, 256, 0, stream>>>(n_feat, W_atom, b_atom, h);

  // counting sort of edges by src
  hipMemsetAsync(hist, 0, (size_t)N_NODES * 4, stream);
  hist_src<<<(N_EDGES + 255) / 256, 256, 0, stream>>>(src, hist);
  exscan<<<1, 1024, 0, stream>>>(hist, cursor);
  scatter_edges<<<(N_EDGES + 255) / 256, 256, 0, stream>>>(src, dst, cursor,
                                                           src_s, dst_s, eidx);

  // edge-net first layer in sorted order (layer-invariant)
  edge_r<<<N_EDGES / 32, 256, 0, stream>>>(e_feat, W_bond, b_bond, W_e1, b_e1,
                                           eidx, rbuf);

  // in-degree -> inverse
  hipMemsetAsync(deg, 0, (size_t)N_NODES * 4, stream);
  deg_accum<<<(N_EDGES + 255) / 256, 256, 0, stream>>>(dst, deg);
  deg_inv<<<(N_NODES + 255) / 256, 256, 0, stream>>>(deg);

  for (int layer = 0; layer < 2; layer++) {
    compute_T_fused<<<N_NODES / 32, 256, 0, stream>>>(h, W_e2, b_e2, T, hbias);
    hipMemsetAsync(agg, 0, (size_t)N_NODES * H * 4, stream);
    edge_msg_agg<<<N_EDGES / 32, 256, 0, stream>>>(rbuf, T, hbias, src_s, dst_s, agg);
    gru_update<<<N_NODES / 8, 256, 0, stream>>>(agg, deg, W_ih, W_hh, b_ih, b_hh, h);
  }

  // graph mean readout
  hipMemsetAsync(gsum, 0, (size_t)(NB * H + NB) * 4, stream);
  readout_sum<<<(N_NODES * H + 255) / 256, 256, 0, stream>>>(h, gid, gsum, gcnt);
  readout_div<<<(NB * H + 255) / 256, 256, 0, stream>>>(gsum, gcnt, out);
}

// Round 3
// 659.113 us; speedup vs baseline: 1.4131x; 1.0637x over previous
//
#include <hip/hip_runtime.h>
#include <math.h>

#define N_NODES 20000
#define N_EDGES 320000
#define NB 128
#define H 32
#define AF 64
#define BF 16

// ---------------- node embedding: h = nf @ W_atom + b ----------------
__global__ __launch_bounds__(256) void embed_nodes(const float* __restrict__ nf,
    const float* __restrict__ W, const float* __restrict__ b, float* __restrict__ h) {
  __shared__ float Ws[AF * H];     // 8 KB
  __shared__ float nfs[8][AF];
  int tid = threadIdx.x;
  for (int v = tid; v < AF * H; v += 256) Ws[v] = W[v];
  int n0 = blockIdx.x * 8;
  for (int v = tid; v < 8 * AF; v += 256) {
    int nl = v / AF, k = v % AF;
    int n = n0 + nl;
    nfs[nl][k] = (n < N_NODES) ? nf[n * AF + k] : 0.0f;
  }
  __syncthreads();
  int nl = tid / H, o = tid % H;
  int n = n0 + nl;
  if (n >= N_NODES) return;
  float acc = b[o];
#pragma unroll
  for (int k = 0; k < AF; k++) acc += nfs[nl][k] * Ws[k * H + o];
  h[n * H + o] = acc;
}

// ---------------- histograms over src AND dst ----------------
__global__ void hist2(const int* __restrict__ src, const int* __restrict__ dst,
                      int* __restrict__ hsrc, int* __restrict__ hdst) {
  int e = blockIdx.x * 256 + threadIdx.x;
  if (e < N_EDGES) {
    atomicAdd(&hsrc[src[e]], 1);
    atomicAdd(&hdst[dst[e]], 1);
  }
}

// single-block exclusive scan of both histograms.
// pass0: hist_src -> cur_s ; pass1: hist_dst -> cur_d + seg_start + inv_deg
__global__ __launch_bounds__(1024) void exscan2(const int* __restrict__ hist_s,
    const int* __restrict__ hist_d, int* __restrict__ cur_s, int* __restrict__ cur_d,
    int* __restrict__ seg_start, float* __restrict__ inv_deg) {
  __shared__ int wsum[16];
  __shared__ int carry;
  int lid = threadIdx.x & 63, wid = threadIdx.x >> 6;
  for (int pass = 0; pass < 2; pass++) {
    if (threadIdx.x == 0) carry = 0;
    __syncthreads();
    const int* __restrict__ hh = pass ? hist_d : hist_s;
    for (int start = 0; start < N_NODES; start += 1024) {
      int i = start + threadIdx.x;
      int v = (i < N_NODES) ? hh[i] : 0;
      int incl = v;
#pragma unroll
      for (int off = 1; off < 64; off <<= 1) {
        int t = __shfl_up(incl, off, 64);
        if (lid >= off) incl += t;
      }
      if (lid == 63) wsum[wid] = incl;
      __syncthreads();
      if (threadIdx.x == 0) {
        int run = carry;
#pragma unroll
        for (int w = 0; w < 16; w++) { int t = wsum[w]; wsum[w] = run; run += t; }
        carry = run;
      }
      __syncthreads();
      int ex = wsum[wid] + incl - v;
      if (i < N_NODES) {
        if (pass == 0) {
          cur_s[i] = ex;
        } else {
          cur_d[i] = ex;
          seg_start[i] = ex;
          inv_deg[i] = 1.0f / fmaxf((float)v, 1.0f);
        }
      }
      __syncthreads();
    }
  }
  if (threadIdx.x == 0) seg_start[N_NODES] = N_EDGES;
}

// scatter: src-sorted position ps gets (src, orig-edge, dst-sorted position)
__global__ void scatter2(const int* __restrict__ src, const int* __restrict__ dst,
    int* __restrict__ cur_s, int* __restrict__ cur_d,
    int* __restrict__ src_s, int* __restrict__ dst_s,
    int* __restrict__ eidx, int* __restrict__ dpos) {
  int e = blockIdx.x * 256 + threadIdx.x;
  if (e >= N_EDGES) return;
  int s = src[e], d = dst[e];
  int ps = atomicAdd(&cur_s[s], 1);
  int pd = atomicAdd(&cur_d[d], 1);
  src_s[ps] = s;
  dst_s[ps] = d;
  eidx[ps] = e;
  dpos[ps] = pd;
}

// ---------------- edge hidden: r = relu((ef@Wb+bb)@We1+be1), src-sorted order ------
__global__ __launch_bounds__(256) void edge_r(const float* __restrict__ ef,
    const float* __restrict__ Wb, const float* __restrict__ bb,
    const float* __restrict__ We1, const float* __restrict__ be1,
    const int* __restrict__ eidx, float* __restrict__ r) {
  __shared__ float Wbs[BF * H];   // 2 KB
  __shared__ float W1s[H * H];    // 4 KB
  __shared__ float efs[32][BF + 1];
  __shared__ float hbs[32][H + 1];
  int tid = threadIdx.x;
  for (int v = tid; v < BF * H; v += 256) Wbs[v] = Wb[v];
  for (int v = tid; v < H * H; v += 256) W1s[v] = We1[v];
  int e0 = blockIdx.x * 32;
  for (int v = tid; v < 32 * BF; v += 256) {
    int el = v >> 4, k = v & 15;
    int ee = eidx[e0 + el];
    efs[el][k] = ef[ee * BF + k];
  }
  __syncthreads();
  int el = tid >> 3, oq = tid & 7, o0 = oq * 4;
  const float4* Wb4 = (const float4*)Wbs;
  const float4* W14 = (const float4*)W1s;
  float4 hb = ((const float4*)bb)[oq];
#pragma unroll
  for (int kk = 0; kk < BF; kk++) {
    float e_ = efs[el][kk];
    float4 w = Wb4[kk * 8 + oq];
    hb.x += e_ * w.x; hb.y += e_ * w.y; hb.z += e_ * w.z; hb.w += e_ * w.w;
  }
  hbs[el][o0 + 0] = hb.x; hbs[el][o0 + 1] = hb.y;
  hbs[el][o0 + 2] = hb.z; hbs[el][o0 + 3] = hb.w;
  __syncthreads();
  float4 acc = ((const float4*)be1)[oq];
#pragma unroll
  for (int j = 0; j < H; j++) {
    float hj = hbs[el][j];
    float4 w = W14[j * 8 + oq];
    acc.x += hj * w.x; acc.y += hj * w.y; acc.z += hj * w.z; acc.w += hj * w.w;
  }
  acc.x = fmaxf(acc.x, 0.0f); acc.y = fmaxf(acc.y, 0.0f);
  acc.z = fmaxf(acc.z, 0.0f); acc.w = fmaxf(acc.w, 0.0f);
  ((float4*)(r + (size_t)(e0 + el) * H))[oq] = acc;
}

// ---------------- T[n,j,o] = sum_i h[n,i]*We2[j,i*H+o]; iter 32 does hbias ----------
__global__ __launch_bounds__(256) void compute_T_fused(const float* __restrict__ h,
    const float* __restrict__ We2, const float* __restrict__ be2,
    float* __restrict__ T, float* __restrict__ hbias) {
  __shared__ float hs[32][H + 1];
  __shared__ float Ws[H * H];     // 4 KB slice
  int tid = threadIdx.x;
  int n0 = blockIdx.x * 32;
  for (int v = tid; v < 32 * H; v += 256) {
    int nl = v >> 5, i = v & 31;
    int n = n0 + nl;
    hs[nl][i] = (n < N_NODES) ? h[n * H + i] : 0.0f;
  }
  __syncthreads();
  int nl = tid >> 3, oq = tid & 7;
  float hreg[H];
#pragma unroll
  for (int i = 0; i < H; i++) hreg[i] = hs[nl][i];
  int n = n0 + nl;
  const float4* W4 = (const float4*)Ws;
  for (int j = 0; j < H + 1; j++) {
    const float* srcW = (j < H) ? (We2 + (size_t)j * (H * H)) : be2;
    ((float4*)Ws)[tid] = ((const float4*)srcW)[tid];
    __syncthreads();
    float4 acc = make_float4(0.f, 0.f, 0.f, 0.f);
#pragma unroll
    for (int i = 0; i < H; i++) {
      float hi = hreg[i];
      float4 w = W4[i * 8 + oq];
      acc.x += hi * w.x; acc.y += hi * w.y; acc.z += hi * w.z; acc.w += hi * w.w;
    }
    if (n < N_NODES) {
      if (j < H) ((float4*)(T + (size_t)n * (H * H) + j * H))[oq] = acc;
      else       ((float4*)(hbias + (size_t)n * H))[oq] = acc;
    }
    __syncthreads();
  }
}

// ---------------- msg in src-sorted order, STORED at dst-sorted position -----------
__global__ __launch_bounds__(256) void edge_msg_store(const float* __restrict__ r,
    const float* __restrict__ T, const float* __restrict__ hbias,
    const int* __restrict__ src_s, const int* __restrict__ dpos,
    float* __restrict__ msg_d) {
  __shared__ float rs[32][H + 1];
  int tid = threadIdx.x;
  int nchunk = gridDim.x;                       // 10000, divisible by 8
  int c = (blockIdx.x & 7) * (nchunk >> 3) + (blockIdx.x >> 3);
  int e0 = c * 32;
  for (int v = tid; v < 32 * H; v += 256) {
    int el = v >> 5, j = v & 31;
    rs[el][j] = r[(size_t)(e0 + el) * H + j];
  }
  __syncthreads();
  int el = tid >> 3;
  int t = tid & 7;
  int e = e0 + el;
  int s = src_s[e], pd = dpos[e];
  const float4* Tp = (const float4*)(T + (size_t)s * (H * H));
  float4 acc = ((const float4*)(hbias + (size_t)s * H))[t];
#pragma unroll 8
  for (int j = 0; j < H; j++) {
    float rj = rs[el][j];
    float4 w = Tp[j * 8 + t];
    acc.x += rj * w.x; acc.y += rj * w.y; acc.z += rj * w.z; acc.w += rj * w.w;
  }
  ((float4*)(msg_d + (size_t)pd * H))[t] = acc;
}

// ---------------- fallback: atomic scatter-add (if workspace too small) ------------
__global__ __launch_bounds__(256) void edge_msg_atomic(const float* __restrict__ r,
    const float* __restrict__ T, const float* __restrict__ hbias,
    const int* __restrict__ src_s, const int* __restrict__ dst_s,
    float* __restrict__ agg) {
  __shared__ float rs[32][H + 1];
  int tid = threadIdx.x;
  int nchunk = gridDim.x;
  int c = (blockIdx.x & 7) * (nchunk >> 3) + (blockIdx.x >> 3);
  int e0 = c * 32;
  for (int v = tid; v < 32 * H; v += 256) {
    int el = v >> 5, j = v & 31;
    rs[el][j] = r[(size_t)(e0 + el) * H + j];
  }
  __syncthreads();
  int el = tid >> 3;
  int t = tid & 7;
  int e = e0 + el;
  int s = src_s[e], d = dst_s[e];
  const float4* Tp = (const float4*)(T + (size_t)s * (H * H));
  float4 acc = ((const float4*)(hbias + (size_t)s * H))[t];
#pragma unroll 8
  for (int j = 0; j < H; j++) {
    float rj = rs[el][j];
    float4 w = Tp[j * 8 + t];
    acc.x += rj * w.x; acc.y += rj * w.y; acc.z += rj * w.z; acc.w += rj * w.w;
  }
  float* ap = agg + (size_t)d * H + t * 4;
  atomicAdd(ap + 0, acc.x);
  atomicAdd(ap + 1, acc.y);
  atomicAdd(ap + 2, acc.z);
  atomicAdd(ap + 3, acc.w);
}

// ---------------- fused segment-reduce + mean + relu + GRU, 32 nodes/block ---------
__global__ __launch_bounds__(256) void seg_gru(const float* __restrict__ msg_d,
    const int* __restrict__ seg_start, const float* __restrict__ invdeg,
    const float* __restrict__ Wih, const float* __restrict__ Whh,
    const float* __restrict__ bih, const float* __restrict__ bhh,
    float* __restrict__ h) {
  __shared__ float Wis[3 * H][H + 1];   // 12.4 KB
  __shared__ float Whs[3 * H][H + 1];   // 12.4 KB
  __shared__ float xs[8][H + 1];
  __shared__ float hs[8][H + 1];
  int tid = threadIdx.x;
  for (int v = tid; v < 3 * H * H; v += 256) {
    int k = v / H, i = v % H;
    Wis[k][i] = Wih[v];
    Whs[k][i] = Whh[v];
  }
  int nl = tid >> 5, o = tid & 31;      // 8 nodes x 32 lanes
  __syncthreads();
  for (int g = 0; g < 4; g++) {
    int n = blockIdx.x * 32 + g * 8 + nl;       // 625*32 == 20000 exactly
    // segment reduce (dst-sorted msg rows are contiguous per node)
    int a = seg_start[n], bseg = seg_start[n + 1];
    float ssum = 0.0f;
    const float* mp = msg_d + (size_t)a * H + o;
    for (int p = a; p < bseg; p++) { ssum += *mp; mp += H; }
    xs[nl][o] = fmaxf(ssum * invdeg[n], 0.0f);
    hs[nl][o] = h[n * H + o];
    __syncthreads();
    float gi0 = bih[o], gi1 = bih[H + o], gi2 = bih[2 * H + o];
    float gh0 = bhh[o], gh1 = bhh[H + o], gh2 = bhh[2 * H + o];
#pragma unroll
    for (int i = 0; i < H; i++) {
      float xi = xs[nl][i], hi = hs[nl][i];
      gi0 += xi * Wis[o][i];
      gh0 += hi * Whs[o][i];
      gi1 += xi * Wis[H + o][i];
      gh1 += hi * Whs[H + o][i];
      gi2 += xi * Wis[2 * H + o][i];
      gh2 += hi * Whs[2 * H + o][i];
    }
    float rg = 1.0f / (1.0f + expf(-(gi0 + gh0)));
    float zg = 1.0f / (1.0f + expf(-(gi1 + gh1)));
    float ng = tanhf(gi2 + rg * gh2);
    float ho = hs[nl][o];
    h[n * H + o] = (1.0f - zg) * ng + zg * ho;
    __syncthreads();
  }
}

// ---------------- fallback GRU reading agg ----------------
__global__ __launch_bounds__(256) void gru_update(const float* __restrict__ agg,
    const float* __restrict__ invdeg, const float* __restrict__ Wih,
    const float* __restrict__ Whh, const float* __restrict__ bih,
    const float* __restrict__ bhh, float* __restrict__ h) {
  __shared__ float Wis[3 * H][H + 1];
  __shared__ float Whs[3 * H][H + 1];
  __shared__ float xs[8][H + 1];
  __shared__ float hs[8][H + 1];
  int tid = threadIdx.x;
  for (int v = tid; v < 3 * H * H; v += 256) {
    int k = v / H, i = v % H;
    Wis[k][i] = Wih[v];
    Whs[k][i] = Whh[v];
  }
  int nl = tid >> 5, o = tid & 31;
  __syncthreads();
  for (int g = 0; g < 4; g++) {
    int n = blockIdx.x * 32 + g * 8 + nl;
    xs[nl][o] = fmaxf(agg[n * H + o] * invdeg[n], 0.0f);
    hs[nl][o] = h[n * H + o];
    __syncthreads();
    float gi0 = bih[o], gi1 = bih[H + o], gi2 = bih[2 * H + o];
    float gh0 = bhh[o], gh1 = bhh[H + o], gh2 = bhh[2 * H + o];
#pragma unroll
    for (int i = 0; i < H; i++) {
      float xi = xs[nl][i], hi = hs[nl][i];
      gi0 += xi * Wis[o][i];
      gh0 += hi * Whs[o][i];
      gi1 += xi * Wis[H + o][i];
      gh1 += hi * Whs[H + o][i];
      gi2 += xi * Wis[2 * H + o][i];
      gh2 += hi * Whs[2 * H + o][i];
    }
    float rg = 1.0f / (1.0f + expf(-(gi0 + gh0)));
    float zg = 1.0f / (1.0f + expf(-(gi1 + gh1)));
    float ng = tanhf(gi2 + rg * gh2);
    float ho = hs[nl][o];
    h[n * H + o] = (1.0f - zg) * ng + zg * ho;
    __syncthreads();
  }
}

// ---------------- graph mean readout ----------------
__global__ void readout_sum(const float* __restrict__ h, const int* __restrict__ gid,
                            float* __restrict__ gsum, float* __restrict__ gcnt) {
  int idx = blockIdx.x * 256 + threadIdx.x;
  if (idx >= N_NODES * H) return;
  int n = idx / H, o = idx % H;
  int g = gid[n];
  atomicAdd(&gsum[g * H + o], h[idx]);
  if (o == 0) atomicAdd(&gcnt[g], 1.0f);
}

__global__ void readout_div(const float* __restrict__ gsum, const float* __restrict__ gcnt,
                            float* __restrict__ out) {
  int idx = blockIdx.x * 256 + threadIdx.x;
  if (idx >= NB * H) return;
  int g = idx / H;
  out[idx] = gsum[idx] / fmaxf(gcnt[g], 1.0f);
}

extern "C" void kernel_launch(void* const* d_in, const int* in_sizes, int n_in,
                              void* d_out, int out_size, void* d_ws, size_t ws_size,
                              hipStream_t stream) {
  const float* n_feat = (const float*)d_in[0];
  const float* e_feat = (const float*)d_in[1];
  const int*   src    = (const int*)d_in[2];
  const int*   dst    = (const int*)d_in[3];
  const int*   gid    = (const int*)d_in[4];
  const float* W_atom = (const float*)d_in[5];
  const float* b_atom = (const float*)d_in[6];
  const float* W_bond = (const float*)d_in[7];
  const float* b_bond = (const float*)d_in[8];
  const float* W_e1   = (const float*)d_in[9];
  const float* b_e1   = (const float*)d_in[10];
  const float* W_e2   = (const float*)d_in[11];
  const float* b_e2   = (const float*)d_in[12];
  const float* W_ih   = (const float*)d_in[13];
  const float* W_hh   = (const float*)d_in[14];
  const float* b_ih   = (const float*)d_in[15];
  const float* b_hh   = (const float*)d_in[16];
  float* out = (float*)d_out;

  // workspace carve-up
  char* ws = (char*)d_ws;
  size_t off = 0;
  float* h      = (float*)(ws + off); off += (size_t)N_NODES * H * 4;       // 2.56 MB
  float* rbuf   = (float*)(ws + off); off += (size_t)N_EDGES * H * 4;       // 40.96 MB
  float* T      = (float*)(ws + off); off += (size_t)N_NODES * H * H * 4;   // 81.92 MB
  float* hbias  = (float*)(ws + off); off += (size_t)N_NODES * H * 4;       // 2.56 MB
  int*   hist_s = (int*)(ws + off);   off += (size_t)N_NODES * 4;
  int*   hist_d = (int*)(ws + off);   off += (size_t)N_NODES * 4;
  int*   cur_s  = (int*)(ws + off);   off += (size_t)N_NODES * 4;
  int*   cur_d  = (int*)(ws + off);   off += (size_t)N_NODES * 4;
  int*   seg    = (int*)(ws + off);   off += (size_t)(N_NODES + 1) * 4;
  float* invdeg = (float*)(ws + off); off += (size_t)N_NODES * 4;
  int*   src_s  = (int*)(ws + off);   off += (size_t)N_EDGES * 4;           // 1.28 MB
  int*   dst_s  = (int*)(ws + off);   off += (size_t)N_EDGES * 4;           // 1.28 MB
  int*   dpos   = (int*)(ws + off);   off += (size_t)N_EDGES * 4;           // 1.28 MB
  float* gsum   = (float*)(ws + off); off += (size_t)NB * H * 4;
  float* gcnt   = (float*)(ws + off); off += (size_t)NB * 4;
  float* agg    = (float*)(ws + off); off += (size_t)N_NODES * H * 4;       // 2.56 MB (fallback)
  float* msg_d  = (float*)(ws + off); off += (size_t)N_EDGES * H * 4;       // 40.96 MB
  int use_msg = (ws_size >= off) ? 1 : 0;
  int* eidx = (int*)T;   // alias: eidx only live before first compute_T

  // node embedding
  embed_nodes<<<N_NODES / 8, 256, 0, stream>>>(n_feat, W_atom, b_atom, h);

  // dual counting sort prep: histograms -> scans (+inv_deg) -> scatter
  hipMemsetAsync(hist_s, 0, (size_t)2 * N_NODES * 4, stream);  // hist_s+hist_d adjacent
  hist2<<<(N_EDGES + 255) / 256, 256, 0, stream>>>(src, dst, hist_s, hist_d);
  exscan2<<<1, 1024, 0, stream>>>(hist_s, hist_d, cur_s, cur_d, seg, invdeg);
  scatter2<<<(N_EDGES + 255) / 256, 256, 0, stream>>>(src, dst, cur_s, cur_d,
                                                      src_s, dst_s, eidx, dpos);

  // edge-net first layer in src-sorted order (layer-invariant)
  edge_r<<<N_EDGES / 32, 256, 0, stream>>>(e_feat, W_bond, b_bond, W_e1, b_e1,
                                           eidx, rbuf);

  for (int layer = 0; layer < 2; layer++) {
    compute_T_fused<<<N_NODES / 32, 256, 0, stream>>>(h, W_e2, b_e2, T, hbias);
    if (use_msg) {
      edge_msg_store<<<N_EDGES / 32, 256, 0, stream>>>(rbuf, T, hbias, src_s, dpos,
                                                       msg_d);
      seg_gru<<<N_NODES / 32, 256, 0, stream>>>(msg_d, seg, invdeg,
                                                W_ih, W_hh, b_ih, b_hh, h);
    } else {
      hipMemsetAsync(agg, 0, (size_t)N_NODES * H * 4, stream);
      edge_msg_atomic<<<N_EDGES / 32, 256, 0, stream>>>(rbuf, T, hbias, src_s, dst_s,
                                                        agg);
      gru_update<<<N_NODES / 32, 256, 0, stream>>>(agg, invdeg,
                                                   W_ih, W_hh, b_ih, b_hh, h);
    }
  }

  // graph mean readout
  hipMemsetAsync(gsum, 0, (size_t)(NB * H + NB) * 4, stream);
  readout_sum<<<(N_NODES * H + 255) / 256, 256, 0, stream>>>(h, gid, gsum, gcnt);
  readout_div<<<(NB * H + 255) / 256, 256, 0, stream>>>(gsum, gcnt, out);
}

// Round 4
// 500.875 us; speedup vs baseline: 1.8595x; 1.3159x over previous
//
#include <hip/hip_runtime.h>
#include <math.h>

#define N_NODES 20000
#define N_EDGES 320000
#define NB 128
#define H 32
#define AF 64
#define BF 16

// ---------------- node embedding: h = nf @ W_atom + b ----------------
__global__ __launch_bounds__(256) void embed_nodes(const float* __restrict__ nf,
    const float* __restrict__ W, const float* __restrict__ b, float* __restrict__ h) {
  __shared__ float Ws[AF * H];     // 8 KB
  __shared__ float nfs[8][AF];
  int tid = threadIdx.x;
  for (int v = tid; v < AF * H; v += 256) Ws[v] = W[v];
  int n0 = blockIdx.x * 8;
  for (int v = tid; v < 8 * AF; v += 256) {
    int nl = v / AF, k = v % AF;
    int n = n0 + nl;
    nfs[nl][k] = (n < N_NODES) ? nf[n * AF + k] : 0.0f;
  }
  __syncthreads();
  int nl = tid / H, o = tid % H;
  int n = n0 + nl;
  if (n >= N_NODES) return;
  float acc = b[o];
#pragma unroll
  for (int k = 0; k < AF; k++) acc += nfs[nl][k] * Ws[k * H + o];
  h[n * H + o] = acc;
}

// ---------------- histograms over src AND dst ----------------
__global__ void hist2(const int* __restrict__ src, const int* __restrict__ dst,
                      int* __restrict__ hsrc, int* __restrict__ hdst) {
  int e = blockIdx.x * 256 + threadIdx.x;
  if (e < N_EDGES) {
    atomicAdd(&hsrc[src[e]], 1);
    atomicAdd(&hdst[dst[e]], 1);
  }
}

// single-block exclusive scan of both histograms.
__global__ __launch_bounds__(1024) void exscan2(const int* __restrict__ hist_s,
    const int* __restrict__ hist_d, int* __restrict__ cur_s, int* __restrict__ cur_d,
    int* __restrict__ seg_start, float* __restrict__ inv_deg) {
  __shared__ int wsum[16];
  __shared__ int carry;
  int lid = threadIdx.x & 63, wid = threadIdx.x >> 6;
  for (int pass = 0; pass < 2; pass++) {
    if (threadIdx.x == 0) carry = 0;
    __syncthreads();
    const int* __restrict__ hh = pass ? hist_d : hist_s;
    for (int start = 0; start < N_NODES; start += 1024) {
      int i = start + threadIdx.x;
      int v = (i < N_NODES) ? hh[i] : 0;
      int incl = v;
#pragma unroll
      for (int off = 1; off < 64; off <<= 1) {
        int t = __shfl_up(incl, off, 64);
        if (lid >= off) incl += t;
      }
      if (lid == 63) wsum[wid] = incl;
      __syncthreads();
      if (threadIdx.x == 0) {
        int run = carry;
#pragma unroll
        for (int w = 0; w < 16; w++) { int t = wsum[w]; wsum[w] = run; run += t; }
        carry = run;
      }
      __syncthreads();
      int ex = wsum[wid] + incl - v;
      if (i < N_NODES) {
        if (pass == 0) {
          cur_s[i] = ex;
        } else {
          cur_d[i] = ex;
          seg_start[i] = ex;
          inv_deg[i] = 1.0f / fmaxf((float)v, 1.0f);
        }
      }
      __syncthreads();
    }
  }
  if (threadIdx.x == 0) seg_start[N_NODES] = N_EDGES;
}

// scatter: src-sorted position ps gets (src, orig-edge, dst-sorted position)
__global__ void scatter2(const int* __restrict__ src, const int* __restrict__ dst,
    int* __restrict__ cur_s, int* __restrict__ cur_d,
    int* __restrict__ src_s, int* __restrict__ dst_s,
    int* __restrict__ eidx, int* __restrict__ dpos) {
  int e = blockIdx.x * 256 + threadIdx.x;
  if (e >= N_EDGES) return;
  int s = src[e], d = dst[e];
  int ps = atomicAdd(&cur_s[s], 1);
  int pd = atomicAdd(&cur_d[d], 1);
  src_s[ps] = s;
  dst_s[ps] = d;
  eidx[ps] = e;
  dpos[ps] = pd;
}

// ---------------- graph segment bounds via binary search (gid is sorted) -----------
__global__ void graph_bounds(const int* __restrict__ gid, int* __restrict__ gstart) {
  int g = threadIdx.x;            // blockDim.x == NB
  int lo = 0, hi = N_NODES;
  while (lo < hi) { int mid = (lo + hi) >> 1; if (gid[mid] < g) lo = mid + 1; else hi = mid; }
  gstart[g] = lo;
  if (g == 0) gstart[NB] = N_NODES;
}

// ---------------- edge hidden: r = relu((ef@Wb+bb)@We1+be1), src-sorted order ------
__global__ __launch_bounds__(256) void edge_r(const float* __restrict__ ef,
    const float* __restrict__ Wb, const float* __restrict__ bb,
    const float* __restrict__ We1, const float* __restrict__ be1,
    const int* __restrict__ eidx, float* __restrict__ r) {
  __shared__ float Wbs[BF * H];   // 2 KB
  __shared__ float W1s[H * H];    // 4 KB
  __shared__ float efs[32][BF + 1];
  __shared__ float hbs[32][H + 1];
  int tid = threadIdx.x;
  for (int v = tid; v < BF * H; v += 256) Wbs[v] = Wb[v];
  for (int v = tid; v < H * H; v += 256) W1s[v] = We1[v];
  int e0 = blockIdx.x * 32;
  for (int v = tid; v < 32 * BF; v += 256) {
    int el = v >> 4, k = v & 15;
    int ee = eidx[e0 + el];
    efs[el][k] = ef[ee * BF + k];
  }
  __syncthreads();
  int el = tid >> 3, oq = tid & 7, o0 = oq * 4;
  const float4* Wb4 = (const float4*)Wbs;
  const float4* W14 = (const float4*)W1s;
  float4 hb = ((const float4*)bb)[oq];
#pragma unroll
  for (int kk = 0; kk < BF; kk++) {
    float e_ = efs[el][kk];
    float4 w = Wb4[kk * 8 + oq];
    hb.x += e_ * w.x; hb.y += e_ * w.y; hb.z += e_ * w.z; hb.w += e_ * w.w;
  }
  hbs[el][o0 + 0] = hb.x; hbs[el][o0 + 1] = hb.y;
  hbs[el][o0 + 2] = hb.z; hbs[el][o0 + 3] = hb.w;
  __syncthreads();
  float4 acc = ((const float4*)be1)[oq];
#pragma unroll
  for (int j = 0; j < H; j++) {
    float hj = hbs[el][j];
    float4 w = W14[j * 8 + oq];
    acc.x += hj * w.x; acc.y += hj * w.y; acc.z += hj * w.z; acc.w += hj * w.w;
  }
  acc.x = fmaxf(acc.x, 0.0f); acc.y = fmaxf(acc.y, 0.0f);
  acc.z = fmaxf(acc.z, 0.0f); acc.w = fmaxf(acc.w, 0.0f);
  ((float4*)(r + (size_t)(e0 + el) * H))[oq] = acc;
}

// ---------------- T[n,j,o] = sum_i h[n,i]*We2[j,i*H+o]; iter 32 does hbias ----------
__global__ __launch_bounds__(256) void compute_T_fused(const float* __restrict__ h,
    const float* __restrict__ We2, const float* __restrict__ be2,
    float* __restrict__ T, float* __restrict__ hbias) {
  __shared__ float hs[32][H + 1];
  __shared__ float Ws[H * H];     // 4 KB slice
  int tid = threadIdx.x;
  int n0 = blockIdx.x * 32;
  for (int v = tid; v < 32 * H; v += 256) {
    int nl = v >> 5, i = v & 31;
    int n = n0 + nl;
    hs[nl][i] = (n < N_NODES) ? h[n * H + i] : 0.0f;
  }
  __syncthreads();
  int nl = tid >> 3, oq = tid & 7;
  float hreg[H];
#pragma unroll
  for (int i = 0; i < H; i++) hreg[i] = hs[nl][i];
  int n = n0 + nl;
  const float4* W4 = (const float4*)Ws;
  for (int j = 0; j < H + 1; j++) {
    const float* srcW = (j < H) ? (We2 + (size_t)j * (H * H)) : be2;
    ((float4*)Ws)[tid] = ((const float4*)srcW)[tid];
    __syncthreads();
    float4 acc = make_float4(0.f, 0.f, 0.f, 0.f);
#pragma unroll
    for (int i = 0; i < H; i++) {
      float hi = hreg[i];
      float4 w = W4[i * 8 + oq];
      acc.x += hi * w.x; acc.y += hi * w.y; acc.z += hi * w.z; acc.w += hi * w.w;
    }
    if (n < N_NODES) {
      if (j < H) ((float4*)(T + (size_t)n * (H * H) + j * H))[oq] = acc;
      else       ((float4*)(hbias + (size_t)n * H))[oq] = acc;
    }
    __syncthreads();
  }
}

// ---------------- msg in src-sorted order, STORED at dst-sorted position -----------
__global__ __launch_bounds__(256) void edge_msg_store(const float* __restrict__ r,
    const float* __restrict__ T, const float* __restrict__ hbias,
    const int* __restrict__ src_s, const int* __restrict__ dpos,
    float* __restrict__ msg_d) {
  __shared__ float rs[32][H + 1];
  int tid = threadIdx.x;
  int nchunk = gridDim.x;                       // 10000, divisible by 8
  int c = (blockIdx.x & 7) * (nchunk >> 3) + (blockIdx.x >> 3);
  int e0 = c * 32;
  for (int v = tid; v < 32 * H; v += 256) {
    int el = v >> 5, j = v & 31;
    rs[el][j] = r[(size_t)(e0 + el) * H + j];
  }
  __syncthreads();
  int el = tid >> 3;
  int t = tid & 7;
  int e = e0 + el;
  int s = src_s[e], pd = dpos[e];
  const float4* Tp = (const float4*)(T + (size_t)s * (H * H));
  float4 acc = ((const float4*)(hbias + (size_t)s * H))[t];
#pragma unroll 8
  for (int j = 0; j < H; j++) {
    float rj = rs[el][j];
    float4 w = Tp[j * 8 + t];
    acc.x += rj * w.x; acc.y += rj * w.y; acc.z += rj * w.z; acc.w += rj * w.w;
  }
  ((float4*)(msg_d + (size_t)pd * H))[t] = acc;
}

// ---------------- fallback: atomic scatter-add (if workspace too small) ------------
__global__ __launch_bounds__(256) void edge_msg_atomic(const float* __restrict__ r,
    const float* __restrict__ T, const float* __restrict__ hbias,
    const int* __restrict__ src_s, const int* __restrict__ dst_s,
    float* __restrict__ agg) {
  __shared__ float rs[32][H + 1];
  int tid = threadIdx.x;
  int nchunk = gridDim.x;
  int c = (blockIdx.x & 7) * (nchunk >> 3) + (blockIdx.x >> 3);
  int e0 = c * 32;
  for (int v = tid; v < 32 * H; v += 256) {
    int el = v >> 5, j = v & 31;
    rs[el][j] = r[(size_t)(e0 + el) * H + j];
  }
  __syncthreads();
  int el = tid >> 3;
  int t = tid & 7;
  int e = e0 + el;
  int s = src_s[e], d = dst_s[e];
  const float4* Tp = (const float4*)(T + (size_t)s * (H * H));
  float4 acc = ((const float4*)(hbias + (size_t)s * H))[t];
#pragma unroll 8
  for (int j = 0; j < H; j++) {
    float rj = rs[el][j];
    float4 w = Tp[j * 8 + t];
    acc.x += rj * w.x; acc.y += rj * w.y; acc.z += rj * w.z; acc.w += rj * w.w;
  }
  float* ap = agg + (size_t)d * H + t * 4;
  atomicAdd(ap + 0, acc.x);
  atomicAdd(ap + 1, acc.y);
  atomicAdd(ap + 2, acc.z);
  atomicAdd(ap + 3, acc.w);
}

// ---------------- fused segment-reduce + mean + relu + GRU, 32 nodes/block ---------
// phase1: 8 thr/node, float4 over cols -> 4x fewer reduce iters; phase2: GRU matvec.
__global__ __launch_bounds__(256) void seg_gru(const float* __restrict__ msg_d,
    const int* __restrict__ seg_start, const float* __restrict__ invdeg,
    const float* __restrict__ Wih, const float* __restrict__ Whh,
    const float* __restrict__ bih, const float* __restrict__ bhh,
    float* __restrict__ h) {
  __shared__ float Wis[3 * H][H + 1];   // 12.4 KB
  __shared__ float Whs[3 * H][H + 1];   // 12.4 KB
  __shared__ float xs[32][H + 1];       // 4.2 KB
  __shared__ float hs[32][H + 1];       // 4.2 KB
  int tid = threadIdx.x;
  for (int v = tid; v < 3 * H * H; v += 256) {
    int k = v / H, i = v % H;
    Wis[k][i] = Wih[v];
    Whs[k][i] = Whh[v];
  }
  int n0 = blockIdx.x * 32;             // 625*32 == 20000 exactly
  // stage h rows
  for (int v = tid; v < 32 * H; v += 256) {
    int nl = v >> 5, i = v & 31;
    hs[nl][i] = h[(size_t)(n0 + nl) * H + i];
  }
  // phase 1: segment reduce, 8 threads per node (float4 per thread)
  {
    int node = tid >> 3, q = tid & 7;
    int n = n0 + node;
    int a = seg_start[n], bseg = seg_start[n + 1];
    float4 acc = make_float4(0.f, 0.f, 0.f, 0.f);
    const float4* mp = (const float4*)(msg_d + (size_t)a * H) + q;
    for (int p = a; p < bseg; p++) {
      float4 m = *mp; mp += 8;
      acc.x += m.x; acc.y += m.y; acc.z += m.z; acc.w += m.w;
    }
    float idg = invdeg[n];
    xs[node][q * 4 + 0] = fmaxf(acc.x * idg, 0.0f);
    xs[node][q * 4 + 1] = fmaxf(acc.y * idg, 0.0f);
    xs[node][q * 4 + 2] = fmaxf(acc.z * idg, 0.0f);
    xs[node][q * 4 + 3] = fmaxf(acc.w * idg, 0.0f);
  }
  __syncthreads();
  // phase 2: GRU matvec, 8 nodes x 32 lanes per pass, 4 passes
  int nl = tid >> 5, o = tid & 31;
#pragma unroll
  for (int g = 0; g < 4; g++) {
    int node = g * 8 + nl;
    int n = n0 + node;
    float gi0 = bih[o], gi1 = bih[H + o], gi2 = bih[2 * H + o];
    float gh0 = bhh[o], gh1 = bhh[H + o], gh2 = bhh[2 * H + o];
#pragma unroll
    for (int i = 0; i < H; i++) {
      float xi = xs[node][i], hi = hs[node][i];
      gi0 += xi * Wis[o][i];
      gh0 += hi * Whs[o][i];
      gi1 += xi * Wis[H + o][i];
      gh1 += hi * Whs[H + o][i];
      gi2 += xi * Wis[2 * H + o][i];
      gh2 += hi * Whs[2 * H + o][i];
    }
    float rg = 1.0f / (1.0f + expf(-(gi0 + gh0)));
    float zg = 1.0f / (1.0f + expf(-(gi1 + gh1)));
    float ng = tanhf(gi2 + rg * gh2);
    float ho = hs[node][o];
    h[(size_t)n * H + o] = (1.0f - zg) * ng + zg * ho;
  }
}

// ---------------- fallback GRU reading agg ----------------
__global__ __launch_bounds__(256) void gru_update(const float* __restrict__ agg,
    const float* __restrict__ invdeg, const float* __restrict__ Wih,
    const float* __restrict__ Whh, const float* __restrict__ bih,
    const float* __restrict__ bhh, float* __restrict__ h) {
  __shared__ float Wis[3 * H][H + 1];
  __shared__ float Whs[3 * H][H + 1];
  __shared__ float xs[32][H + 1];
  __shared__ float hs[32][H + 1];
  int tid = threadIdx.x;
  for (int v = tid; v < 3 * H * H; v += 256) {
    int k = v / H, i = v % H;
    Wis[k][i] = Wih[v];
    Whs[k][i] = Whh[v];
  }
  int n0 = blockIdx.x * 32;
  for (int v = tid; v < 32 * H; v += 256) {
    int nl = v >> 5, i = v & 31;
    int n = n0 + nl;
    hs[nl][i] = h[(size_t)n * H + i];
    xs[nl][i] = fmaxf(agg[(size_t)n * H + i] * invdeg[n], 0.0f);
  }
  __syncthreads();
  int nl = tid >> 5, o = tid & 31;
#pragma unroll
  for (int g = 0; g < 4; g++) {
    int node = g * 8 + nl;
    int n = n0 + node;
    float gi0 = bih[o], gi1 = bih[H + o], gi2 = bih[2 * H + o];
    float gh0 = bhh[o], gh1 = bhh[H + o], gh2 = bhh[2 * H + o];
#pragma unroll
    for (int i = 0; i < H; i++) {
      float xi = xs[node][i], hi = hs[node][i];
      gi0 += xi * Wis[o][i];
      gh0 += hi * Whs[o][i];
      gi1 += xi * Wis[H + o][i];
      gh1 += hi * Whs[H + o][i];
      gi2 += xi * Wis[2 * H + o][i];
      gh2 += hi * Whs[2 * H + o][i];
    }
    float rg = 1.0f / (1.0f + expf(-(gi0 + gh0)));
    float zg = 1.0f / (1.0f + expf(-(gi1 + gh1)));
    float ng = tanhf(gi2 + rg * gh2);
    float ho = hs[node][o];
    h[(size_t)n * H + o] = (1.0f - zg) * ng + zg * ho;
  }
}

// ---------------- graph mean readout: segmented (gid sorted), no atomics -----------
__global__ __launch_bounds__(256) void readout_graph(const float* __restrict__ h,
    const int* __restrict__ gstart, float* __restrict__ out) {
  __shared__ float red[8][H + 1];
  int g = blockIdx.x;
  int a = gstart[g], b = gstart[g + 1];
  int r = threadIdx.x >> 5, o = threadIdx.x & 31;
  float s = 0.0f;
  for (int n = a + r; n < b; n += 8) s += h[(size_t)n * H + o];
  red[r][o] = s;
  __syncthreads();
  if (r == 0) {
    float t = 0.0f;
#pragma unroll
    for (int k = 0; k < 8; k++) t += red[k][o];
    out[g * H + o] = t / fmaxf((float)(b - a), 1.0f);
  }
}

extern "C" void kernel_launch(void* const* d_in, const int* in_sizes, int n_in,
                              void* d_out, int out_size, void* d_ws, size_t ws_size,
                              hipStream_t stream) {
  const float* n_feat = (const float*)d_in[0];
  const float* e_feat = (const float*)d_in[1];
  const int*   src    = (const int*)d_in[2];
  const int*   dst    = (const int*)d_in[3];
  const int*   gid    = (const int*)d_in[4];
  const float* W_atom = (const float*)d_in[5];
  const float* b_atom = (const float*)d_in[6];
  const float* W_bond = (const float*)d_in[7];
  const float* b_bond = (const float*)d_in[8];
  const float* W_e1   = (const float*)d_in[9];
  const float* b_e1   = (const float*)d_in[10];
  const float* W_e2   = (const float*)d_in[11];
  const float* b_e2   = (const float*)d_in[12];
  const float* W_ih   = (const float*)d_in[13];
  const float* W_hh   = (const float*)d_in[14];
  const float* b_ih   = (const float*)d_in[15];
  const float* b_hh   = (const float*)d_in[16];
  float* out = (float*)d_out;

  // workspace carve-up
  char* ws = (char*)d_ws;
  size_t off = 0;
  float* h      = (float*)(ws + off); off += (size_t)N_NODES * H * 4;       // 2.56 MB
  float* rbuf   = (float*)(ws + off); off += (size_t)N_EDGES * H * 4;       // 40.96 MB
  float* T      = (float*)(ws + off); off += (size_t)N_NODES * H * H * 4;   // 81.92 MB
  float* hbias  = (float*)(ws + off); off += (size_t)N_NODES * H * 4;       // 2.56 MB
  int*   hist_s = (int*)(ws + off);   off += (size_t)N_NODES * 4;
  int*   hist_d = (int*)(ws + off);   off += (size_t)N_NODES * 4;
  int*   cur_s  = (int*)(ws + off);   off += (size_t)N_NODES * 4;
  int*   cur_d  = (int*)(ws + off);   off += (size_t)N_NODES * 4;
  int*   seg    = (int*)(ws + off);   off += (size_t)(N_NODES + 1) * 4;
  float* invdeg = (float*)(ws + off); off += (size_t)N_NODES * 4;
  int*   src_s  = (int*)(ws + off);   off += (size_t)N_EDGES * 4;           // 1.28 MB
  int*   dst_s  = (int*)(ws + off);   off += (size_t)N_EDGES * 4;           // 1.28 MB
  int*   dpos   = (int*)(ws + off);   off += (size_t)N_EDGES * 4;           // 1.28 MB
  int*   gstart = (int*)(ws + off);   off += (size_t)(NB + 1) * 4;
  float* agg    = (float*)(ws + off); off += (size_t)N_NODES * H * 4;       // 2.56 MB (fallback)
  float* msg_d  = (float*)(ws + off); off += (size_t)N_EDGES * H * 4;       // 40.96 MB
  int use_msg = (ws_size >= off) ? 1 : 0;
  int* eidx = (int*)T;   // alias: eidx only live before first compute_T

  // node embedding
  embed_nodes<<<N_NODES / 8, 256, 0, stream>>>(n_feat, W_atom, b_atom, h);

  // dual counting sort prep: histograms -> scans (+inv_deg) -> scatter
  hipMemsetAsync(hist_s, 0, (size_t)2 * N_NODES * 4, stream);  // hist_s+hist_d adjacent
  hist2<<<(N_EDGES + 255) / 256, 256, 0, stream>>>(src, dst, hist_s, hist_d);
  exscan2<<<1, 1024, 0, stream>>>(hist_s, hist_d, cur_s, cur_d, seg, invdeg);
  scatter2<<<(N_EDGES + 255) / 256, 256, 0, stream>>>(src, dst, cur_s, cur_d,
                                                      src_s, dst_s, eidx, dpos);
  graph_bounds<<<1, NB, 0, stream>>>(gid, gstart);

  // edge-net first layer in src-sorted order (layer-invariant)
  edge_r<<<N_EDGES / 32, 256, 0, stream>>>(e_feat, W_bond, b_bond, W_e1, b_e1,
                                           eidx, rbuf);

  for (int layer = 0; layer < 2; layer++) {
    compute_T_fused<<<N_NODES / 32, 256, 0, stream>>>(h, W_e2, b_e2, T, hbias);
    if (use_msg) {
      edge_msg_store<<<N_EDGES / 32, 256, 0, stream>>>(rbuf, T, hbias, src_s, dpos,
                                                       msg_d);
      seg_gru<<<N_NODES / 32, 256, 0, stream>>>(msg_d, seg, invdeg,
                                                W_ih, W_hh, b_ih, b_hh, h);
    } else {
      hipMemsetAsync(agg, 0, (size_t)N_NODES * H * 4, stream);
      edge_msg_atomic<<<N_EDGES / 32, 256, 0, stream>>>(rbuf, T, hbias, src_s, dst_s,
                                                        agg);
      gru_update<<<N_NODES / 32, 256, 0, stream>>>(agg, invdeg,
                                                   W_ih, W_hh, b_ih, b_hh, h);
    }
  }

  // graph mean readout (segmented, atomic-free)
  readout_graph<<<NB, 256, 0, stream>>>(h, gstart, out);
}

// Round 5
// 478.761 us; speedup vs baseline: 1.9454x; 1.0462x over previous
//
#include <hip/hip_runtime.h>
#include <math.h>

#define N_NODES 20000
#define N_EDGES 320000
#define NB 128
#define H 32
#define AF 64
#define BF 16
#define TSTR 1028   // padded LDS stride (floats) for one T row: rotates banks per node

// ---------------- node embedding: h = nf @ W_atom + b ----------------
__global__ __launch_bounds__(256) void embed_nodes(const float* __restrict__ nf,
    const float* __restrict__ W, const float* __restrict__ b, float* __restrict__ h) {
  __shared__ float Ws[AF * H];     // 8 KB
  __shared__ float nfs[8][AF];
  int tid = threadIdx.x;
  for (int v = tid; v < AF * H; v += 256) Ws[v] = W[v];
  int n0 = blockIdx.x * 8;
  for (int v = tid; v < 8 * AF; v += 256) {
    int nl = v / AF, k = v % AF;
    int n = n0 + nl;
    nfs[nl][k] = (n < N_NODES) ? nf[n * AF + k] : 0.0f;
  }
  __syncthreads();
  int nl = tid / H, o = tid % H;
  int n = n0 + nl;
  if (n >= N_NODES) return;
  float acc = b[o];
#pragma unroll
  for (int k = 0; k < AF; k++) acc += nfs[nl][k] * Ws[k * H + o];
  h[n * H + o] = acc;
}

// ---------------- histograms over src AND dst ----------------
__global__ void hist2(const int* __restrict__ src, const int* __restrict__ dst,
                      int* __restrict__ hsrc, int* __restrict__ hdst) {
  int e = blockIdx.x * 256 + threadIdx.x;
  if (e < N_EDGES) {
    atomicAdd(&hsrc[src[e]], 1);
    atomicAdd(&hdst[dst[e]], 1);
  }
}

// single-block exclusive scan of both histograms.
// pass0: hist_src -> cur_s + seg_s ; pass1: hist_dst -> cur_d + seg_d + inv_deg
__global__ __launch_bounds__(1024) void exscan2(const int* __restrict__ hist_s,
    const int* __restrict__ hist_d, int* __restrict__ cur_s, int* __restrict__ cur_d,
    int* __restrict__ seg_s, int* __restrict__ seg_d, float* __restrict__ inv_deg) {
  __shared__ int wsum[16];
  __shared__ int carry;
  int lid = threadIdx.x & 63, wid = threadIdx.x >> 6;
  for (int pass = 0; pass < 2; pass++) {
    if (threadIdx.x == 0) carry = 0;
    __syncthreads();
    const int* __restrict__ hh = pass ? hist_d : hist_s;
    for (int start = 0; start < N_NODES; start += 1024) {
      int i = start + threadIdx.x;
      int v = (i < N_NODES) ? hh[i] : 0;
      int incl = v;
#pragma unroll
      for (int off = 1; off < 64; off <<= 1) {
        int t = __shfl_up(incl, off, 64);
        if (lid >= off) incl += t;
      }
      if (lid == 63) wsum[wid] = incl;
      __syncthreads();
      if (threadIdx.x == 0) {
        int run = carry;
#pragma unroll
        for (int w = 0; w < 16; w++) { int t = wsum[w]; wsum[w] = run; run += t; }
        carry = run;
      }
      __syncthreads();
      int ex = wsum[wid] + incl - v;
      if (i < N_NODES) {
        if (pass == 0) {
          cur_s[i] = ex;
          seg_s[i] = ex;
        } else {
          cur_d[i] = ex;
          seg_d[i] = ex;
          inv_deg[i] = 1.0f / fmaxf((float)v, 1.0f);
        }
      }
      __syncthreads();
    }
  }
  if (threadIdx.x == 0) { seg_s[N_NODES] = N_EDGES; seg_d[N_NODES] = N_EDGES; }
}

// scatter: src-sorted position ps gets (src, orig-edge, dst-sorted position)
__global__ void scatter2(const int* __restrict__ src, const int* __restrict__ dst,
    int* __restrict__ cur_s, int* __restrict__ cur_d,
    int* __restrict__ src_s, int* __restrict__ dst_s,
    int* __restrict__ eidx, int* __restrict__ dpos) {
  int e = blockIdx.x * 256 + threadIdx.x;
  if (e >= N_EDGES) return;
  int s = src[e], d = dst[e];
  int ps = atomicAdd(&cur_s[s], 1);
  int pd = atomicAdd(&cur_d[d], 1);
  src_s[ps] = s;
  dst_s[ps] = d;
  eidx[ps] = e;
  dpos[ps] = pd;
}

// ---------------- graph segment bounds via binary search (gid is sorted) -----------
__global__ void graph_bounds(const int* __restrict__ gid, int* __restrict__ gstart) {
  int g = threadIdx.x;            // blockDim.x == NB
  int lo = 0, hi = N_NODES;
  while (lo < hi) { int mid = (lo + hi) >> 1; if (gid[mid] < g) lo = mid + 1; else hi = mid; }
  gstart[g] = lo;
  if (g == 0) gstart[NB] = N_NODES;
}

// ---------------- edge hidden: r = relu((ef@Wb+bb)@We1+be1), src-sorted order ------
__global__ __launch_bounds__(256) void edge_r(const float* __restrict__ ef,
    const float* __restrict__ Wb, const float* __restrict__ bb,
    const float* __restrict__ We1, const float* __restrict__ be1,
    const int* __restrict__ eidx, float* __restrict__ r) {
  __shared__ float Wbs[BF * H];   // 2 KB
  __shared__ float W1s[H * H];    // 4 KB
  __shared__ float efs[32][BF + 1];
  __shared__ float hbs[32][H + 1];
  int tid = threadIdx.x;
  for (int v = tid; v < BF * H; v += 256) Wbs[v] = Wb[v];
  for (int v = tid; v < H * H; v += 256) W1s[v] = We1[v];
  int e0 = blockIdx.x * 32;
  for (int v = tid; v < 32 * BF; v += 256) {
    int el = v >> 4, k = v & 15;
    int ee = eidx[e0 + el];
    efs[el][k] = ef[ee * BF + k];
  }
  __syncthreads();
  int el = tid >> 3, oq = tid & 7, o0 = oq * 4;
  const float4* Wb4 = (const float4*)Wbs;
  const float4* W14 = (const float4*)W1s;
  float4 hb = ((const float4*)bb)[oq];
#pragma unroll
  for (int kk = 0; kk < BF; kk++) {
    float e_ = efs[el][kk];
    float4 w = Wb4[kk * 8 + oq];
    hb.x += e_ * w.x; hb.y += e_ * w.y; hb.z += e_ * w.z; hb.w += e_ * w.w;
  }
  hbs[el][o0 + 0] = hb.x; hbs[el][o0 + 1] = hb.y;
  hbs[el][o0 + 2] = hb.z; hbs[el][o0 + 3] = hb.w;
  __syncthreads();
  float4 acc = ((const float4*)be1)[oq];
#pragma unroll
  for (int j = 0; j < H; j++) {
    float hj = hbs[el][j];
    float4 w = W14[j * 8 + oq];
    acc.x += hj * w.x; acc.y += hj * w.y; acc.z += hj * w.z; acc.w += hj * w.w;
  }
  acc.x = fmaxf(acc.x, 0.0f); acc.y = fmaxf(acc.y, 0.0f);
  acc.z = fmaxf(acc.z, 0.0f); acc.w = fmaxf(acc.w, 0.0f);
  ((float4*)(r + (size_t)(e0 + el) * H))[oq] = acc;
}

// ---------------- T[n,j,o] = sum_i h[n,i]*We2[j,i*H+o] ----------------
// grid (625, 4): blockIdx.y owns j in [8y, 8y+8); y==3 also does hbias (be2).
__global__ __launch_bounds__(256) void compute_T_fused(const float* __restrict__ h,
    const float* __restrict__ We2, const float* __restrict__ be2,
    float* __restrict__ T, float* __restrict__ hbias) {
  __shared__ float hs[32][H + 1];
  __shared__ float Ws[H * H];     // 4 KB slice
  int tid = threadIdx.x;
  int n0 = blockIdx.x * 32;
  int jb = blockIdx.y;
  for (int v = tid; v < 32 * H; v += 256) {
    int nl = v >> 5, i = v & 31;
    hs[nl][i] = h[(size_t)(n0 + nl) * H + i];
  }
  __syncthreads();
  int nl = tid >> 3, oq = tid & 7;
  float hreg[H];
#pragma unroll
  for (int i = 0; i < H; i++) hreg[i] = hs[nl][i];
  int n = n0 + nl;
  const float4* W4 = (const float4*)Ws;
  int jcount = (jb == 3) ? 9 : 8;     // y==3 appends the be2 (hbias) slice
  for (int jj = 0; jj < jcount; jj++) {
    int j = jb * 8 + jj;              // j==32 -> hbias
    const float* srcW = (j < H) ? (We2 + (size_t)j * (H * H)) : be2;
    ((float4*)Ws)[tid] = ((const float4*)srcW)[tid];
    __syncthreads();
    float4 acc = make_float4(0.f, 0.f, 0.f, 0.f);
#pragma unroll
    for (int i = 0; i < H; i++) {
      float hi = hreg[i];
      float4 w = W4[i * 8 + oq];
      acc.x += hi * w.x; acc.y += hi * w.y; acc.z += hi * w.z; acc.w += hi * w.w;
    }
    if (j < H) ((float4*)(T + (size_t)n * (H * H) + j * H))[oq] = acc;
    else       ((float4*)(hbias + (size_t)n * H))[oq] = acc;
    __syncthreads();
  }
}

// ---------------- msg: block = 8 src-segments, T rows staged in LDS ----------------
// Edges of nodes [n0, n0+8) are contiguous in src-sorted order. 8 lanes/edge.
__global__ __launch_bounds__(256) void edge_msg_seg(const float* __restrict__ r,
    const float* __restrict__ T, const float* __restrict__ hbias,
    const int* __restrict__ seg_s, const int* __restrict__ src_s,
    const int* __restrict__ dpos, float* __restrict__ msg_d) {
  __shared__ float Ts[8 * TSTR];  // 32.9 KB, padded stride rotates banks per node
  __shared__ float hb[8 * H];     // 1 KB
  int tid = threadIdx.x;
  int n0 = blockIdx.x * 8;        // 2500 * 8 == 20000
  const float4* Tg = (const float4*)(T + (size_t)n0 * (H * H));
#pragma unroll
  for (int rr = 0; rr < 8; rr++) {
    ((float4*)(Ts + rr * TSTR))[tid] = Tg[rr * 256 + tid];
  }
  if (tid < 8 * H) hb[tid] = hbias[(size_t)n0 * H + tid];
  __syncthreads();
  int estart = seg_s[n0], eend = seg_s[n0 + 8];
  int t = tid & 7;
  for (int e = estart + (tid >> 3); e < eend; e += 32) {
    int s = src_s[e] - n0;        // 0..7
    int pd = dpos[e];
    float4 rv = ((const float4*)(r + (size_t)e * H))[t];
    float4 acc = ((const float4*)(hb + s * H))[t];
    const float4* Trow = (const float4*)(Ts + s * TSTR);
#pragma unroll
    for (int j = 0; j < H; j++) {
      float mine = ((j & 3) == 0) ? rv.x : ((j & 3) == 1) ? rv.y
                 : ((j & 3) == 2) ? rv.z : rv.w;
      float rj = __shfl(mine, j >> 2, 8);      // broadcast within 8-lane edge group
      float4 w = Trow[j * 8 + t];
      acc.x += rj * w.x; acc.y += rj * w.y; acc.z += rj * w.z; acc.w += rj * w.w;
    }
    ((float4*)(msg_d + (size_t)pd * H))[t] = acc;
  }
}

// ---------------- fallback: atomic scatter-add (if workspace too small) ------------
__global__ __launch_bounds__(256) void edge_msg_atomic(const float* __restrict__ r,
    const float* __restrict__ T, const float* __restrict__ hbias,
    const int* __restrict__ src_s, const int* __restrict__ dst_s,
    float* __restrict__ agg) {
  __shared__ float rs[32][H + 1];
  int tid = threadIdx.x;
  int nchunk = gridDim.x;
  int c = (blockIdx.x & 7) * (nchunk >> 3) + (blockIdx.x >> 3);
  int e0 = c * 32;
  for (int v = tid; v < 32 * H; v += 256) {
    int el = v >> 5, j = v & 31;
    rs[el][j] = r[(size_t)(e0 + el) * H + j];
  }
  __syncthreads();
  int el = tid >> 3;
  int t = tid & 7;
  int e = e0 + el;
  int s = src_s[e], d = dst_s[e];
  const float4* Tp = (const float4*)(T + (size_t)s * (H * H));
  float4 acc = ((const float4*)(hbias + (size_t)s * H))[t];
#pragma unroll 8
  for (int j = 0; j < H; j++) {
    float rj = rs[el][j];
    float4 w = Tp[j * 8 + t];
    acc.x += rj * w.x; acc.y += rj * w.y; acc.z += rj * w.z; acc.w += rj * w.w;
  }
  float* ap = agg + (size_t)d * H + t * 4;
  atomicAdd(ap + 0, acc.x);
  atomicAdd(ap + 1, acc.y);
  atomicAdd(ap + 2, acc.z);
  atomicAdd(ap + 3, acc.w);
}

// ---------------- fused segment-reduce + mean + relu + GRU, 32 nodes/block ---------
__global__ __launch_bounds__(256) void seg_gru(const float* __restrict__ msg_d,
    const int* __restrict__ seg_d, const float* __restrict__ invdeg,
    const float* __restrict__ Wih, const float* __restrict__ Whh,
    const float* __restrict__ bih, const float* __restrict__ bhh,
    float* __restrict__ h) {
  __shared__ float Wis[3 * H][H + 1];   // 12.4 KB
  __shared__ float Whs[3 * H][H + 1];   // 12.4 KB
  __shared__ float xs[32][H + 1];       // 4.2 KB
  __shared__ float hs[32][H + 1];       // 4.2 KB
  int tid = threadIdx.x;
  for (int v = tid; v < 3 * H * H; v += 256) {
    int k = v / H, i = v % H;
    Wis[k][i] = Wih[v];
    Whs[k][i] = Whh[v];
  }
  int n0 = blockIdx.x * 32;             // 625*32 == 20000 exactly
  for (int v = tid; v < 32 * H; v += 256) {
    int nl = v >> 5, i = v & 31;
    hs[nl][i] = h[(size_t)(n0 + nl) * H + i];
  }
  // phase 1: segment reduce, 8 threads per node (float4 per thread)
  {
    int node = tid >> 3, q = tid & 7;
    int n = n0 + node;
    int a = seg_d[n], bseg = seg_d[n + 1];
    float4 acc = make_float4(0.f, 0.f, 0.f, 0.f);
    const float4* mp = (const float4*)(msg_d + (size_t)a * H) + q;
    for (int p = a; p < bseg; p++) {
      float4 m = *mp; mp += 8;
      acc.x += m.x; acc.y += m.y; acc.z += m.z; acc.w += m.w;
    }
    float idg = invdeg[n];
    xs[node][q * 4 + 0] = fmaxf(acc.x * idg, 0.0f);
    xs[node][q * 4 + 1] = fmaxf(acc.y * idg, 0.0f);
    xs[node][q * 4 + 2] = fmaxf(acc.z * idg, 0.0f);
    xs[node][q * 4 + 3] = fmaxf(acc.w * idg, 0.0f);
  }
  __syncthreads();
  // phase 2: GRU matvec, 8 nodes x 32 lanes per pass, 4 passes
  int nl = tid >> 5, o = tid & 31;
#pragma unroll
  for (int g = 0; g < 4; g++) {
    int node = g * 8 + nl;
    int n = n0 + node;
    float gi0 = bih[o], gi1 = bih[H + o], gi2 = bih[2 * H + o];
    float gh0 = bhh[o], gh1 = bhh[H + o], gh2 = bhh[2 * H + o];
#pragma unroll
    for (int i = 0; i < H; i++) {
      float xi = xs[node][i], hi = hs[node][i];
      gi0 += xi * Wis[o][i];
      gh0 += hi * Whs[o][i];
      gi1 += xi * Wis[H + o][i];
      gh1 += hi * Whs[H + o][i];
      gi2 += xi * Wis[2 * H + o][i];
      gh2 += hi * Whs[2 * H + o][i];
    }
    float rg = 1.0f / (1.0f + expf(-(gi0 + gh0)));
    float zg = 1.0f / (1.0f + expf(-(gi1 + gh1)));
    float ng = tanhf(gi2 + rg * gh2);
    float ho = hs[node][o];
    h[(size_t)n * H + o] = (1.0f - zg) * ng + zg * ho;
  }
}

// ---------------- fallback GRU reading agg ----------------
__global__ __launch_bounds__(256) void gru_update(const float* __restrict__ agg,
    const float* __restrict__ invdeg, const float* __restrict__ Wih,
    const float* __restrict__ Whh, const float* __restrict__ bih,
    const float* __restrict__ bhh, float* __restrict__ h) {
  __shared__ float Wis[3 * H][H + 1];
  __shared__ float Whs[3 * H][H + 1];
  __shared__ float xs[32][H + 1];
  __shared__ float hs[32][H + 1];
  int tid = threadIdx.x;
  for (int v = tid; v < 3 * H * H; v += 256) {
    int k = v / H, i = v % H;
    Wis[k][i] = Wih[v];
    Whs[k][i] = Whh[v];
  }
  int n0 = blockIdx.x * 32;
  for (int v = tid; v < 32 * H; v += 256) {
    int nl = v >> 5, i = v & 31;
    int n = n0 + nl;
    hs[nl][i] = h[(size_t)n * H + i];
    xs[nl][i] = fmaxf(agg[(size_t)n * H + i] * invdeg[n], 0.0f);
  }
  __syncthreads();
  int nl = tid >> 5, o = tid & 31;
#pragma unroll
  for (int g = 0; g < 4; g++) {
    int node = g * 8 + nl;
    int n = n0 + node;
    float gi0 = bih[o], gi1 = bih[H + o], gi2 = bih[2 * H + o];
    float gh0 = bhh[o], gh1 = bhh[H + o], gh2 = bhh[2 * H + o];
#pragma unroll
    for (int i = 0; i < H; i++) {
      float xi = xs[node][i], hi = hs[node][i];
      gi0 += xi * Wis[o][i];
      gh0 += hi * Whs[o][i];
      gi1 += xi * Wis[H + o][i];
      gh1 += hi * Whs[H + o][i];
      gi2 += xi * Wis[2 * H + o][i];
      gh2 += hi * Whs[2 * H + o][i];
    }
    float rg = 1.0f / (1.0f + expf(-(gi0 + gh0)));
    float zg = 1.0f / (1.0f + expf(-(gi1 + gh1)));
    float ng = tanhf(gi2 + rg * gh2);
    float ho = hs[node][o];
    h[(size_t)n * H + o] = (1.0f - zg) * ng + zg * ho;
  }
}

// ---------------- graph mean readout: segmented (gid sorted), no atomics -----------
__global__ __launch_bounds__(256) void readout_graph(const float* __restrict__ h,
    const int* __restrict__ gstart, float* __restrict__ out) {
  __shared__ float red[8][H + 1];
  int g = blockIdx.x;
  int a = gstart[g], b = gstart[g + 1];
  int r = threadIdx.x >> 5, o = threadIdx.x & 31;
  float s = 0.0f;
  for (int n = a + r; n < b; n += 8) s += h[(size_t)n * H + o];
  red[r][o] = s;
  __syncthreads();
  if (r == 0) {
    float t = 0.0f;
#pragma unroll
    for (int k = 0; k < 8; k++) t += red[k][o];
    out[g * H + o] = t / fmaxf((float)(b - a), 1.0f);
  }
}

extern "C" void kernel_launch(void* const* d_in, const int* in_sizes, int n_in,
                              void* d_out, int out_size, void* d_ws, size_t ws_size,
                              hipStream_t stream) {
  const float* n_feat = (const float*)d_in[0];
  const float* e_feat = (const float*)d_in[1];
  const int*   src    = (const int*)d_in[2];
  const int*   dst    = (const int*)d_in[3];
  const int*   gid    = (const int*)d_in[4];
  const float* W_atom = (const float*)d_in[5];
  const float* b_atom = (const float*)d_in[6];
  const float* W_bond = (const float*)d_in[7];
  const float* b_bond = (const float*)d_in[8];
  const float* W_e1   = (const float*)d_in[9];
  const float* b_e1   = (const float*)d_in[10];
  const float* W_e2   = (const float*)d_in[11];
  const float* b_e2   = (const float*)d_in[12];
  const float* W_ih   = (const float*)d_in[13];
  const float* W_hh   = (const float*)d_in[14];
  const float* b_ih   = (const float*)d_in[15];
  const float* b_hh   = (const float*)d_in[16];
  float* out = (float*)d_out;

  // workspace carve-up
  char* ws = (char*)d_ws;
  size_t off = 0;
  float* h      = (float*)(ws + off); off += (size_t)N_NODES * H * 4;       // 2.56 MB
  float* rbuf   = (float*)(ws + off); off += (size_t)N_EDGES * H * 4;       // 40.96 MB
  float* T      = (float*)(ws + off); off += (size_t)N_NODES * H * H * 4;   // 81.92 MB
  float* hbias  = (float*)(ws + off); off += (size_t)N_NODES * H * 4;       // 2.56 MB
  int*   hist_s = (int*)(ws + off);   off += (size_t)N_NODES * 4;
  int*   hist_d = (int*)(ws + off);   off += (size_t)N_NODES * 4;
  int*   cur_s  = (int*)(ws + off);   off += (size_t)N_NODES * 4;
  int*   cur_d  = (int*)(ws + off);   off += (size_t)N_NODES * 4;
  int*   seg_s  = (int*)(ws + off);   off += (size_t)(N_NODES + 1) * 4;
  int*   seg_d  = (int*)(ws + off);   off += (size_t)(N_NODES + 1) * 4;
  float* invdeg = (float*)(ws + off); off += (size_t)N_NODES * 4;
  int*   src_s  = (int*)(ws + off);   off += (size_t)N_EDGES * 4;           // 1.28 MB
  int*   dst_s  = (int*)(ws + off);   off += (size_t)N_EDGES * 4;           // 1.28 MB
  int*   dpos   = (int*)(ws + off);   off += (size_t)N_EDGES * 4;           // 1.28 MB
  int*   gstart = (int*)(ws + off);   off += (size_t)(NB + 1) * 4;
  float* agg    = (float*)(ws + off); off += (size_t)N_NODES * H * 4;       // 2.56 MB (fallback)
  float* msg_d  = (float*)(ws + off); off += (size_t)N_EDGES * H * 4;       // 40.96 MB
  int use_msg = (ws_size >= off) ? 1 : 0;
  int* eidx = (int*)T;   // alias: eidx only live before first compute_T

  // node embedding
  embed_nodes<<<N_NODES / 8, 256, 0, stream>>>(n_feat, W_atom, b_atom, h);

  // dual counting sort prep: histograms -> scans (+inv_deg) -> scatter
  hipMemsetAsync(hist_s, 0, (size_t)2 * N_NODES * 4, stream);  // hist_s+hist_d adjacent
  hist2<<<(N_EDGES + 255) / 256, 256, 0, stream>>>(src, dst, hist_s, hist_d);
  exscan2<<<1, 1024, 0, stream>>>(hist_s, hist_d, cur_s, cur_d, seg_s, seg_d, invdeg);
  scatter2<<<(N_EDGES + 255) / 256, 256, 0, stream>>>(src, dst, cur_s, cur_d,
                                                      src_s, dst_s, eidx, dpos);
  graph_bounds<<<1, NB, 0, stream>>>(gid, gstart);

  // edge-net first layer in src-sorted order (layer-invariant)
  edge_r<<<N_EDGES / 32, 256, 0, stream>>>(e_feat, W_bond, b_bond, W_e1, b_e1,
                                           eidx, rbuf);

  for (int layer = 0; layer < 2; layer++) {
    dim3 gT(N_NODES / 32, 4);
    compute_T_fused<<<gT, 256, 0, stream>>>(h, W_e2, b_e2, T, hbias);
    if (use_msg) {
      edge_msg_seg<<<N_NODES / 8, 256, 0, stream>>>(rbuf, T, hbias, seg_s, src_s,
                                                    dpos, msg_d);
      seg_gru<<<N_NODES / 32, 256, 0, stream>>>(msg_d, seg_d, invdeg,
                                                W_ih, W_hh, b_ih, b_hh, h);
    } else {
      hipMemsetAsync(agg, 0, (size_t)N_NODES * H * 4, stream);
      edge_msg_atomic<<<N_EDGES / 32, 256, 0, stream>>>(rbuf, T, hbias, src_s, dst_s,
                                                        agg);
      gru_update<<<N_NODES / 32, 256, 0, stream>>>(agg, invdeg,
                                                   W_ih, W_hh, b_ih, b_hh, h);
    }
  }

  // graph mean readout (segmented, atomic-free)
  readout_graph<<<NB, 256, 0, stream>>>(h, gstart, out);
}

// Round 6
// 478.590 us; speedup vs baseline: 1.9461x; 1.0004x over previous
//
#include <hip/hip_runtime.h>
#include <math.h>

#define N_NODES 20000
#define N_EDGES 320000
#define NB 128
#define H 32
#define AF 64
#define BF 16
#define TSTR 1028   // padded LDS stride (floats) for one T row: rotates banks per node

__device__ __forceinline__ float fast_sigmoid(float x) {
  return 1.0f / (1.0f + __expf(-x));
}
__device__ __forceinline__ float fast_tanh(float x) {
  float e2 = __expf(2.0f * x);
  return 1.0f - 2.0f / (e2 + 1.0f);    // inf-safe: x>>0 -> 1, x<<0 -> -1
}

// ---------------- node embedding: h = nf @ W_atom + b ----------------
__global__ __launch_bounds__(256) void embed_nodes(const float* __restrict__ nf,
    const float* __restrict__ W, const float* __restrict__ b, float* __restrict__ h) {
  __shared__ float Ws[AF * H];     // 8 KB
  __shared__ float nfs[8][AF];
  int tid = threadIdx.x;
  for (int v = tid; v < AF * H; v += 256) Ws[v] = W[v];
  int n0 = blockIdx.x * 8;
  for (int v = tid; v < 8 * AF; v += 256) {
    int nl = v / AF, k = v % AF;
    int n = n0 + nl;
    nfs[nl][k] = (n < N_NODES) ? nf[n * AF + k] : 0.0f;
  }
  __syncthreads();
  int nl = tid / H, o = tid % H;
  int n = n0 + nl;
  if (n >= N_NODES) return;
  float acc = b[o];
#pragma unroll
  for (int k = 0; k < AF; k++) acc += nfs[nl][k] * Ws[k * H + o];
  h[n * H + o] = acc;
}

// ---------------- histograms over src AND dst ----------------
__global__ void hist2(const int* __restrict__ src, const int* __restrict__ dst,
                      int* __restrict__ hsrc, int* __restrict__ hdst) {
  int e = blockIdx.x * 256 + threadIdx.x;
  if (e < N_EDGES) {
    atomicAdd(&hsrc[src[e]], 1);
    atomicAdd(&hdst[dst[e]], 1);
  }
}

// single-block exclusive scan of both histograms.
__global__ __launch_bounds__(1024) void exscan2(const int* __restrict__ hist_s,
    const int* __restrict__ hist_d, int* __restrict__ cur_s, int* __restrict__ cur_d,
    int* __restrict__ seg_s, int* __restrict__ seg_d, float* __restrict__ inv_deg) {
  __shared__ int wsum[16];
  __shared__ int carry;
  int lid = threadIdx.x & 63, wid = threadIdx.x >> 6;
  for (int pass = 0; pass < 2; pass++) {
    if (threadIdx.x == 0) carry = 0;
    __syncthreads();
    const int* __restrict__ hh = pass ? hist_d : hist_s;
    for (int start = 0; start < N_NODES; start += 1024) {
      int i = start + threadIdx.x;
      int v = (i < N_NODES) ? hh[i] : 0;
      int incl = v;
#pragma unroll
      for (int off = 1; off < 64; off <<= 1) {
        int t = __shfl_up(incl, off, 64);
        if (lid >= off) incl += t;
      }
      if (lid == 63) wsum[wid] = incl;
      __syncthreads();
      if (threadIdx.x == 0) {
        int run = carry;
#pragma unroll
        for (int w = 0; w < 16; w++) { int t = wsum[w]; wsum[w] = run; run += t; }
        carry = run;
      }
      __syncthreads();
      int ex = wsum[wid] + incl - v;
      if (i < N_NODES) {
        if (pass == 0) {
          cur_s[i] = ex;
          seg_s[i] = ex;
        } else {
          cur_d[i] = ex;
          seg_d[i] = ex;
          inv_deg[i] = 1.0f / fmaxf((float)v, 1.0f);
        }
      }
      __syncthreads();
    }
  }
  if (threadIdx.x == 0) { seg_s[N_NODES] = N_EDGES; seg_d[N_NODES] = N_EDGES; }
}

// scatter: src-sorted position ps gets (src, orig-edge, dst-sorted position)
__global__ void scatter2(const int* __restrict__ src, const int* __restrict__ dst,
    int* __restrict__ cur_s, int* __restrict__ cur_d,
    int* __restrict__ src_s, int* __restrict__ dst_s,
    int* __restrict__ eidx, int* __restrict__ dpos) {
  int e = blockIdx.x * 256 + threadIdx.x;
  if (e >= N_EDGES) return;
  int s = src[e], d = dst[e];
  int ps = atomicAdd(&cur_s[s], 1);
  int pd = atomicAdd(&cur_d[d], 1);
  src_s[ps] = s;
  dst_s[ps] = d;
  eidx[ps] = e;
  dpos[ps] = pd;
}

// ---------------- graph segment bounds via binary search (gid is sorted) -----------
__global__ void graph_bounds(const int* __restrict__ gid, int* __restrict__ gstart) {
  int g = threadIdx.x;            // blockDim.x == NB
  int lo = 0, hi = N_NODES;
  while (lo < hi) { int mid = (lo + hi) >> 1; if (gid[mid] < g) lo = mid + 1; else hi = mid; }
  gstart[g] = lo;
  if (g == 0) gstart[NB] = N_NODES;
}

// ---------------- edge hidden: r = relu((ef@Wb+bb)@We1+be1), src-sorted order ------
__global__ __launch_bounds__(256) void edge_r(const float* __restrict__ ef,
    const float* __restrict__ Wb, const float* __restrict__ bb,
    const float* __restrict__ We1, const float* __restrict__ be1,
    const int* __restrict__ eidx, float* __restrict__ r) {
  __shared__ float Wbs[BF * H];   // 2 KB
  __shared__ float W1s[H * H];    // 4 KB
  __shared__ float efs[32][BF + 1];
  __shared__ float hbs[32][H + 1];
  int tid = threadIdx.x;
  for (int v = tid; v < BF * H; v += 256) Wbs[v] = Wb[v];
  for (int v = tid; v < H * H; v += 256) W1s[v] = We1[v];
  int e0 = blockIdx.x * 32;
  for (int v = tid; v < 32 * BF; v += 256) {
    int el = v >> 4, k = v & 15;
    int ee = eidx[e0 + el];
    efs[el][k] = ef[ee * BF + k];
  }
  __syncthreads();
  int el = tid >> 3, oq = tid & 7, o0 = oq * 4;
  const float4* Wb4 = (const float4*)Wbs;
  const float4* W14 = (const float4*)W1s;
  float4 hb = ((const float4*)bb)[oq];
#pragma unroll
  for (int kk = 0; kk < BF; kk++) {
    float e_ = efs[el][kk];
    float4 w = Wb4[kk * 8 + oq];
    hb.x += e_ * w.x; hb.y += e_ * w.y; hb.z += e_ * w.z; hb.w += e_ * w.w;
  }
  hbs[el][o0 + 0] = hb.x; hbs[el][o0 + 1] = hb.y;
  hbs[el][o0 + 2] = hb.z; hbs[el][o0 + 3] = hb.w;
  __syncthreads();
  float4 acc = ((const float4*)be1)[oq];
#pragma unroll
  for (int j = 0; j < H; j++) {
    float hj = hbs[el][j];
    float4 w = W14[j * 8 + oq];
    acc.x += hj * w.x; acc.y += hj * w.y; acc.z += hj * w.z; acc.w += hj * w.w;
  }
  acc.x = fmaxf(acc.x, 0.0f); acc.y = fmaxf(acc.y, 0.0f);
  acc.z = fmaxf(acc.z, 0.0f); acc.w = fmaxf(acc.w, 0.0f);
  ((float4*)(r + (size_t)(e0 + el) * H))[oq] = acc;
}

// ---------------- T[n,j,o] = sum_i h[n,i]*We2[j,i*H+o] ----------------
// grid (625, 4): blockIdx.y owns j in [8y, 8y+8); y==3 appends the be2 (hbias) slice.
// All slices preloaded once -> exactly ONE barrier per block; stores stream freely.
__global__ __launch_bounds__(256) void compute_T_fused(const float* __restrict__ h,
    const float* __restrict__ We2, const float* __restrict__ be2,
    float* __restrict__ T, float* __restrict__ hbias) {
  __shared__ float Wall[9 * H * H];   // 36 KB: up to 9 slices of [i][o]
  __shared__ float hs[32][H + 1];
  int tid = threadIdx.x;
  int n0 = blockIdx.x * 32;
  int jb = blockIdx.y;
  int nslice = (jb == 3) ? 9 : 8;
  const float4* Wsrc = (const float4*)(We2 + (size_t)jb * 8 * (H * H));
  for (int v = tid; v < 8 * 256; v += 256) ((float4*)Wall)[v] = Wsrc[v];
  if (jb == 3) ((float4*)(Wall + 8 * H * H))[tid] = ((const float4*)be2)[tid];
  for (int v = tid; v < 32 * H; v += 256) {
    int nl = v >> 5, i = v & 31;
    hs[nl][i] = h[(size_t)(n0 + nl) * H + i];
  }
  __syncthreads();
  int nl = tid >> 3, oq = tid & 7;
  float hreg[H];
#pragma unroll
  for (int i = 0; i < H; i++) hreg[i] = hs[nl][i];
  int n = n0 + nl;
  for (int jj = 0; jj < nslice; jj++) {
    const float4* W4 = (const float4*)(Wall + jj * (H * H));
    float4 acc = make_float4(0.f, 0.f, 0.f, 0.f);
#pragma unroll
    for (int i = 0; i < H; i++) {
      float hi = hreg[i];
      float4 w = W4[i * 8 + oq];
      acc.x += hi * w.x; acc.y += hi * w.y; acc.z += hi * w.z; acc.w += hi * w.w;
    }
    int j = jb * 8 + jj;
    if (j < H) ((float4*)(T + (size_t)n * (H * H) + j * H))[oq] = acc;
    else       ((float4*)(hbias + (size_t)n * H))[oq] = acc;
  }
}

// ---------------- msg: block = 8 src-segments, T rows staged in LDS ----------------
__global__ __launch_bounds__(256) void edge_msg_seg(const float* __restrict__ r,
    const float* __restrict__ T, const float* __restrict__ hbias,
    const int* __restrict__ seg_s, const int* __restrict__ src_s,
    const int* __restrict__ dpos, float* __restrict__ msg_d) {
  __shared__ float Ts[8 * TSTR];  // 32.9 KB, padded stride rotates banks per node
  __shared__ float hb[8 * H];     // 1 KB
  int tid = threadIdx.x;
  int n0 = blockIdx.x * 8;        // 2500 * 8 == 20000
  const float4* Tg = (const float4*)(T + (size_t)n0 * (H * H));
#pragma unroll
  for (int rr = 0; rr < 8; rr++) {
    ((float4*)(Ts + rr * TSTR))[tid] = Tg[rr * 256 + tid];
  }
  if (tid < 8 * H) hb[tid] = hbias[(size_t)n0 * H + tid];
  __syncthreads();
  int estart = seg_s[n0], eend = seg_s[n0 + 8];
  int t = tid & 7;
  for (int e = estart + (tid >> 3); e < eend; e += 32) {
    int s = src_s[e] - n0;        // 0..7
    int pd = dpos[e];
    float4 rv = ((const float4*)(r + (size_t)e * H))[t];
    float4 acc = ((const float4*)(hb + s * H))[t];
    const float4* Trow = (const float4*)(Ts + s * TSTR);
#pragma unroll
    for (int j = 0; j < H; j++) {
      float mine = ((j & 3) == 0) ? rv.x : ((j & 3) == 1) ? rv.y
                 : ((j & 3) == 2) ? rv.z : rv.w;
      float rj = __shfl(mine, j >> 2, 8);      // broadcast within 8-lane edge group
      float4 w = Trow[j * 8 + t];
      acc.x += rj * w.x; acc.y += rj * w.y; acc.z += rj * w.z; acc.w += rj * w.w;
    }
    ((float4*)(msg_d + (size_t)pd * H))[t] = acc;
  }
}

// ---------------- fallback: atomic scatter-add (if workspace too small) ------------
__global__ __launch_bounds__(256) void edge_msg_atomic(const float* __restrict__ r,
    const float* __restrict__ T, const float* __restrict__ hbias,
    const int* __restrict__ src_s, const int* __restrict__ dst_s,
    float* __restrict__ agg) {
  __shared__ float rs[32][H + 1];
  int tid = threadIdx.x;
  int nchunk = gridDim.x;
  int c = (blockIdx.x & 7) * (nchunk >> 3) + (blockIdx.x >> 3);
  int e0 = c * 32;
  for (int v = tid; v < 32 * H; v += 256) {
    int el = v >> 5, j = v & 31;
    rs[el][j] = r[(size_t)(e0 + el) * H + j];
  }
  __syncthreads();
  int el = tid >> 3;
  int t = tid & 7;
  int e = e0 + el;
  int s = src_s[e], d = dst_s[e];
  const float4* Tp = (const float4*)(T + (size_t)s * (H * H));
  float4 acc = ((const float4*)(hbias + (size_t)s * H))[t];
#pragma unroll 8
  for (int j = 0; j < H; j++) {
    float rj = rs[el][j];
    float4 w = Tp[j * 8 + t];
    acc.x += rj * w.x; acc.y += rj * w.y; acc.z += rj * w.z; acc.w += rj * w.w;
  }
  float* ap = agg + (size_t)d * H + t * 4;
  atomicAdd(ap + 0, acc.x);
  atomicAdd(ap + 1, acc.y);
  atomicAdd(ap + 2, acc.z);
  atomicAdd(ap + 3, acc.w);
}

// ---------------- fused segment-reduce + mean + relu + GRU, 8 nodes/block ----------
// 2500 blocks (vs 625): occupancy was the R5 limiter. 32 lanes/node, coalesced
// 128B-per-row reduce, one barrier total, fast exp-based gates.
__global__ __launch_bounds__(256) void seg_gru(const float* __restrict__ msg_d,
    const int* __restrict__ seg_d, const float* __restrict__ invdeg,
    const float* __restrict__ Wih, const float* __restrict__ Whh,
    const float* __restrict__ bih, const float* __restrict__ bhh,
    float* __restrict__ h) {
  __shared__ float Wis[3 * H][H + 1];   // 12.4 KB
  __shared__ float Whs[3 * H][H + 1];   // 12.4 KB
  __shared__ float xs[8][H + 1];
  __shared__ float hsm[8][H + 1];
  int tid = threadIdx.x;
  for (int v = tid; v < 3 * H * H; v += 256) {
    int k = v / H, i = v % H;
    Wis[k][i] = Wih[v];
    Whs[k][i] = Whh[v];
  }
  int node = tid >> 5, o = tid & 31;
  int n = blockIdx.x * 8 + node;        // 2500*8 == 20000 exactly
  int a = seg_d[n], bseg = seg_d[n + 1];
  float s = 0.0f;
  const float* mp = msg_d + (size_t)a * H + o;
  for (int p = a; p < bseg; p++) { s += *mp; mp += H; }
  xs[node][o] = fmaxf(s * invdeg[n], 0.0f);
  float hval = h[(size_t)n * H + o];
  hsm[node][o] = hval;
  __syncthreads();
  float gi0 = bih[o], gi1 = bih[H + o], gi2 = bih[2 * H + o];
  float gh0 = bhh[o], gh1 = bhh[H + o], gh2 = bhh[2 * H + o];
#pragma unroll
  for (int i = 0; i < H; i++) {
    float xi = xs[node][i], hi = hsm[node][i];
    gi0 += xi * Wis[o][i];
    gh0 += hi * Whs[o][i];
    gi1 += xi * Wis[H + o][i];
    gh1 += hi * Whs[H + o][i];
    gi2 += xi * Wis[2 * H + o][i];
    gh2 += hi * Whs[2 * H + o][i];
  }
  float rg = fast_sigmoid(gi0 + gh0);
  float zg = fast_sigmoid(gi1 + gh1);
  float ng = fast_tanh(gi2 + rg * gh2);
  h[(size_t)n * H + o] = (1.0f - zg) * ng + zg * hval;
}

// ---------------- fallback GRU reading agg (8 nodes/block) ----------------
__global__ __launch_bounds__(256) void gru_update(const float* __restrict__ agg,
    const float* __restrict__ invdeg, const float* __restrict__ Wih,
    const float* __restrict__ Whh, const float* __restrict__ bih,
    const float* __restrict__ bhh, float* __restrict__ h) {
  __shared__ float Wis[3 * H][H + 1];
  __shared__ float Whs[3 * H][H + 1];
  __shared__ float xs[8][H + 1];
  __shared__ float hsm[8][H + 1];
  int tid = threadIdx.x;
  for (int v = tid; v < 3 * H * H; v += 256) {
    int k = v / H, i = v % H;
    Wis[k][i] = Wih[v];
    Whs[k][i] = Whh[v];
  }
  int node = tid >> 5, o = tid & 31;
  int n = blockIdx.x * 8 + node;
  xs[node][o] = fmaxf(agg[(size_t)n * H + o] * invdeg[n], 0.0f);
  float hval = h[(size_t)n * H + o];
  hsm[node][o] = hval;
  __syncthreads();
  float gi0 = bih[o], gi1 = bih[H + o], gi2 = bih[2 * H + o];
  float gh0 = bhh[o], gh1 = bhh[H + o], gh2 = bhh[2 * H + o];
#pragma unroll
  for (int i = 0; i < H; i++) {
    float xi = xs[node][i], hi = hsm[node][i];
    gi0 += xi * Wis[o][i];
    gh0 += hi * Whs[o][i];
    gi1 += xi * Wis[H + o][i];
    gh1 += hi * Whs[H + o][i];
    gi2 += xi * Wis[2 * H + o][i];
    gh2 += hi * Whs[2 * H + o][i];
  }
  float rg = fast_sigmoid(gi0 + gh0);
  float zg = fast_sigmoid(gi1 + gh1);
  float ng = fast_tanh(gi2 + rg * gh2);
  h[(size_t)n * H + o] = (1.0f - zg) * ng + zg * hval;
}

// ---------------- graph mean readout: segmented (gid sorted), no atomics -----------
__global__ __launch_bounds__(256) void readout_graph(const float* __restrict__ h,
    const int* __restrict__ gstart, float* __restrict__ out) {
  __shared__ float red[8][H + 1];
  int g = blockIdx.x;
  int a = gstart[g], b = gstart[g + 1];
  int r = threadIdx.x >> 5, o = threadIdx.x & 31;
  float s = 0.0f;
  for (int n = a + r; n < b; n += 8) s += h[(size_t)n * H + o];
  red[r][o] = s;
  __syncthreads();
  if (r == 0) {
    float t = 0.0f;
#pragma unroll
    for (int k = 0; k < 8; k++) t += red[k][o];
    out[g * H + o] = t / fmaxf((float)(b - a), 1.0f);
  }
}

extern "C" void kernel_launch(void* const* d_in, const int* in_sizes, int n_in,
                              void* d_out, int out_size, void* d_ws, size_t ws_size,
                              hipStream_t stream) {
  const float* n_feat = (const float*)d_in[0];
  const float* e_feat = (const float*)d_in[1];
  const int*   src    = (const int*)d_in[2];
  const int*   dst    = (const int*)d_in[3];
  const int*   gid    = (const int*)d_in[4];
  const float* W_atom = (const float*)d_in[5];
  const float* b_atom = (const float*)d_in[6];
  const float* W_bond = (const float*)d_in[7];
  const float* b_bond = (const float*)d_in[8];
  const float* W_e1   = (const float*)d_in[9];
  const float* b_e1   = (const float*)d_in[10];
  const float* W_e2   = (const float*)d_in[11];
  const float* b_e2   = (const float*)d_in[12];
  const float* W_ih   = (const float*)d_in[13];
  const float* W_hh   = (const float*)d_in[14];
  const float* b_ih   = (const float*)d_in[15];
  const float* b_hh   = (const float*)d_in[16];
  float* out = (float*)d_out;

  // workspace carve-up
  char* ws = (char*)d_ws;
  size_t off = 0;
  float* h      = (float*)(ws + off); off += (size_t)N_NODES * H * 4;       // 2.56 MB
  float* rbuf   = (float*)(ws + off); off += (size_t)N_EDGES * H * 4;       // 40.96 MB
  float* T      = (float*)(ws + off); off += (size_t)N_NODES * H * H * 4;   // 81.92 MB
  float* hbias  = (float*)(ws + off); off += (size_t)N_NODES * H * 4;       // 2.56 MB
  int*   hist_s = (int*)(ws + off);   off += (size_t)N_NODES * 4;
  int*   hist_d = (int*)(ws + off);   off += (size_t)N_NODES * 4;
  int*   cur_s  = (int*)(ws + off);   off += (size_t)N_NODES * 4;
  int*   cur_d  = (int*)(ws + off);   off += (size_t)N_NODES * 4;
  int*   seg_s  = (int*)(ws + off);   off += (size_t)(N_NODES + 1) * 4;
  int*   seg_d  = (int*)(ws + off);   off += (size_t)(N_NODES + 1) * 4;
  float* invdeg = (float*)(ws + off); off += (size_t)N_NODES * 4;
  int*   src_s  = (int*)(ws + off);   off += (size_t)N_EDGES * 4;           // 1.28 MB
  int*   dst_s  = (int*)(ws + off);   off += (size_t)N_EDGES * 4;           // 1.28 MB
  int*   dpos   = (int*)(ws + off);   off += (size_t)N_EDGES * 4;           // 1.28 MB
  int*   gstart = (int*)(ws + off);   off += (size_t)(NB + 1) * 4;
  float* agg    = (float*)(ws + off); off += (size_t)N_NODES * H * 4;       // 2.56 MB (fallback)
  float* msg_d  = (float*)(ws + off); off += (size_t)N_EDGES * H * 4;       // 40.96 MB
  int use_msg = (ws_size >= off) ? 1 : 0;
  int* eidx = (int*)T;   // alias: eidx only live before first compute_T

  // node embedding
  embed_nodes<<<N_NODES / 8, 256, 0, stream>>>(n_feat, W_atom, b_atom, h);

  // dual counting sort prep: histograms -> scans (+inv_deg) -> scatter
  hipMemsetAsync(hist_s, 0, (size_t)2 * N_NODES * 4, stream);  // hist_s+hist_d adjacent
  hist2<<<(N_EDGES + 255) / 256, 256, 0, stream>>>(src, dst, hist_s, hist_d);
  exscan2<<<1, 1024, 0, stream>>>(hist_s, hist_d, cur_s, cur_d, seg_s, seg_d, invdeg);
  scatter2<<<(N_EDGES + 255) / 256, 256, 0, stream>>>(src, dst, cur_s, cur_d,
                                                      src_s, dst_s, eidx, dpos);
  graph_bounds<<<1, NB, 0, stream>>>(gid, gstart);

  // edge-net first layer in src-sorted order (layer-invariant)
  edge_r<<<N_EDGES / 32, 256, 0, stream>>>(e_feat, W_bond, b_bond, W_e1, b_e1,
                                           eidx, rbuf);

  for (int layer = 0; layer < 2; layer++) {
    dim3 gT(N_NODES / 32, 4);
    compute_T_fused<<<gT, 256, 0, stream>>>(h, W_e2, b_e2, T, hbias);
    if (use_msg) {
      edge_msg_seg<<<N_NODES / 8, 256, 0, stream>>>(rbuf, T, hbias, seg_s, src_s,
                                                    dpos, msg_d);
      seg_gru<<<N_NODES / 8, 256, 0, stream>>>(msg_d, seg_d, invdeg,
                                               W_ih, W_hh, b_ih, b_hh, h);
    } else {
      hipMemsetAsync(agg, 0, (size_t)N_NODES * H * 4, stream);
      edge_msg_atomic<<<N_EDGES / 32, 256, 0, stream>>>(rbuf, T, hbias, src_s, dst_s,
                                                        agg);
      gru_update<<<N_NODES / 8, 256, 0, stream>>>(agg, invdeg,
                                                  W_ih, W_hh, b_ih, b_hh, h);
    }
  }

  // graph mean readout (segmented, atomic-free)
  readout_graph<<<NB, 256, 0, stream>>>(h, gstart, out);
}

// Round 7
// 419.208 us; speedup vs baseline: 2.2217x; 1.1417x over previous
//
#include <hip/hip_runtime.h>
#include <math.h>

#define N_NODES 20000
#define N_EDGES 320000
#define NB 128
#define H 32
#define AF 64
#define BF 16
#define TSTR 1028        // padded LDS stride (floats) for one T row
#define SCB 79           // scan blocks: ceil(20000/256)
#define SCP 20224        // padded per-pass partial size (79*256)

__device__ __forceinline__ float fast_sigmoid(float x) {
  return 1.0f / (1.0f + __expf(-x));
}
__device__ __forceinline__ float fast_tanh(float x) {
  float e2 = __expf(2.0f * x);
  return 1.0f - 2.0f / (e2 + 1.0f);    // inf-safe
}

// ---------------- node embedding: h = nf @ W_atom + b ----------------
__global__ __launch_bounds__(256) void embed_nodes(const float* __restrict__ nf,
    const float* __restrict__ W, const float* __restrict__ b, float* __restrict__ h) {
  __shared__ float Ws[AF * H];     // 8 KB
  __shared__ float nfs[8][AF];
  int tid = threadIdx.x;
  for (int v = tid; v < AF * H; v += 256) Ws[v] = W[v];
  int n0 = blockIdx.x * 8;
  for (int v = tid; v < 8 * AF; v += 256) {
    int nl = v / AF, k = v % AF;
    int n = n0 + nl;
    nfs[nl][k] = (n < N_NODES) ? nf[n * AF + k] : 0.0f;
  }
  __syncthreads();
  int nl = tid / H, o = tid % H;
  int n = n0 + nl;
  if (n >= N_NODES) return;
  float acc = b[o];
#pragma unroll
  for (int k = 0; k < AF; k++) acc += nfs[nl][k] * Ws[k * H + o];
  h[n * H + o] = acc;
}

// ---------------- histograms over src AND dst ----------------
__global__ void hist2(const int* __restrict__ src, const int* __restrict__ dst,
                      int* __restrict__ hsrc, int* __restrict__ hdst) {
  int e = blockIdx.x * 256 + threadIdx.x;
  if (e < N_EDGES) {
    atomicAdd(&hsrc[src[e]], 1);
    atomicAdd(&hdst[dst[e]], 1);
  }
}

// ---------------- multi-block exclusive scan (replaces single-block exscan2) -------
// pass y=0: hist_s, y=1: hist_d. part[y*SCP+i] = in-block exclusive scan;
// bsum[y*SCB+b] = block total.
__global__ __launch_bounds__(256) void scan_partial(const int* __restrict__ hist_s,
    const int* __restrict__ hist_d, int* __restrict__ part, int* __restrict__ bsum) {
  __shared__ int wsums[4];
  int which = blockIdx.y;
  const int* __restrict__ hh = which ? hist_d : hist_s;
  int i = blockIdx.x * 256 + threadIdx.x;
  int v = (i < N_NODES) ? hh[i] : 0;
  int lane = threadIdx.x & 63, wid = threadIdx.x >> 6;
  int incl = v;
#pragma unroll
  for (int off = 1; off < 64; off <<= 1) {
    int t = __shfl_up(incl, off, 64);
    if (lane >= off) incl += t;
  }
  if (lane == 63) wsums[wid] = incl;
  __syncthreads();
  int woff = 0;
#pragma unroll
  for (int w = 0; w < 4; w++) if (w < wid) woff += wsums[w];
  part[which * SCP + i] = woff + incl - v;
  if (threadIdx.x == 0)
    bsum[which * SCB + blockIdx.x] = wsums[0] + wsums[1] + wsums[2] + wsums[3];
}

// exclusive-scan the 2 x SCB block totals in place (tiny; LDS-serial)
__global__ __launch_bounds__(256) void scan_tops(int* __restrict__ bsum) {
  __shared__ int s[2 * SCB];
  int tid = threadIdx.x;
  if (tid < 2 * SCB) s[tid] = bsum[tid];
  __syncthreads();
  if (tid < 2) {
    int run = 0;
    for (int b = 0; b < SCB; b++) { int t = s[tid * SCB + b]; s[tid * SCB + b] = run; run += t; }
  }
  __syncthreads();
  if (tid < 2 * SCB) bsum[tid] = s[tid];
}

// final: ex = part + block offset; emit cursors, segment starts, inv_deg
__global__ __launch_bounds__(256) void scan_final(const int* __restrict__ part,
    const int* __restrict__ bsum, const int* __restrict__ hist_d,
    int* __restrict__ cur_s, int* __restrict__ cur_d,
    int* __restrict__ seg_s, int* __restrict__ seg_d, float* __restrict__ inv_deg) {
  int which = blockIdx.y;
  int i = blockIdx.x * 256 + threadIdx.x;
  if (i >= N_NODES) return;
  int ex = part[which * SCP + i] + bsum[which * SCB + blockIdx.x];
  if (which == 0) {
    cur_s[i] = ex; seg_s[i] = ex;
    if (i == 0) seg_s[N_NODES] = N_EDGES;
  } else {
    cur_d[i] = ex; seg_d[i] = ex;
    inv_deg[i] = 1.0f / fmaxf((float)hist_d[i], 1.0f);
    if (i == 0) seg_d[N_NODES] = N_EDGES;
  }
}

// scatter: src-sorted position ps gets (src, orig-edge, dst-sorted position)
__global__ void scatter2(const int* __restrict__ src, const int* __restrict__ dst,
    int* __restrict__ cur_s, int* __restrict__ cur_d,
    int* __restrict__ src_s, int* __restrict__ dst_s,
    int* __restrict__ eidx, int* __restrict__ dpos) {
  int e = blockIdx.x * 256 + threadIdx.x;
  if (e >= N_EDGES) return;
  int s = src[e], d = dst[e];
  int ps = atomicAdd(&cur_s[s], 1);
  int pd = atomicAdd(&cur_d[d], 1);
  src_s[ps] = s;
  dst_s[ps] = d;
  eidx[ps] = e;
  dpos[ps] = pd;
}

// ---------------- graph segment bounds via binary search (gid is sorted) -----------
__global__ void graph_bounds(const int* __restrict__ gid, int* __restrict__ gstart) {
  int g = threadIdx.x;            // blockDim.x == NB
  int lo = 0, hi = N_NODES;
  while (lo < hi) { int mid = (lo + hi) >> 1; if (gid[mid] < g) lo = mid + 1; else hi = mid; }
  gstart[g] = lo;
  if (g == 0) gstart[NB] = N_NODES;
}

// ---------------- edge hidden: r = relu((ef@Wb+bb)@We1+be1), src-sorted order ------
__global__ __launch_bounds__(256) void edge_r(const float* __restrict__ ef,
    const float* __restrict__ Wb, const float* __restrict__ bb,
    const float* __restrict__ We1, const float* __restrict__ be1,
    const int* __restrict__ eidx, float* __restrict__ r) {
  __shared__ float Wbs[BF * H];   // 2 KB
  __shared__ float W1s[H * H];    // 4 KB
  __shared__ float efs[32][BF + 1];
  __shared__ float hbs[32][H + 1];
  int tid = threadIdx.x;
  for (int v = tid; v < BF * H; v += 256) Wbs[v] = Wb[v];
  for (int v = tid; v < H * H; v += 256) W1s[v] = We1[v];
  int e0 = blockIdx.x * 32;
  for (int v = tid; v < 32 * BF; v += 256) {
    int el = v >> 4, k = v & 15;
    int ee = eidx[e0 + el];
    efs[el][k] = ef[ee * BF + k];
  }
  __syncthreads();
  int el = tid >> 3, oq = tid & 7, o0 = oq * 4;
  const float4* Wb4 = (const float4*)Wbs;
  const float4* W14 = (const float4*)W1s;
  float4 hb = ((const float4*)bb)[oq];
#pragma unroll
  for (int kk = 0; kk < BF; kk++) {
    float e_ = efs[el][kk];
    float4 w = Wb4[kk * 8 + oq];
    hb.x += e_ * w.x; hb.y += e_ * w.y; hb.z += e_ * w.z; hb.w += e_ * w.w;
  }
  hbs[el][o0 + 0] = hb.x; hbs[el][o0 + 1] = hb.y;
  hbs[el][o0 + 2] = hb.z; hbs[el][o0 + 3] = hb.w;
  __syncthreads();
  float4 acc = ((const float4*)be1)[oq];
#pragma unroll
  for (int j = 0; j < H; j++) {
    float hj = hbs[el][j];
    float4 w = W14[j * 8 + oq];
    acc.x += hj * w.x; acc.y += hj * w.y; acc.z += hj * w.z; acc.w += hj * w.w;
  }
  acc.x = fmaxf(acc.x, 0.0f); acc.y = fmaxf(acc.y, 0.0f);
  acc.z = fmaxf(acc.z, 0.0f); acc.w = fmaxf(acc.w, 0.0f);
  ((float4*)(r + (size_t)(e0 + el) * H))[oq] = acc;
}

// ---------------- T[n,j,o] = sum_i h[n,i]*We2[j,i*H+o] ----------------
// grid (625, 4): one barrier per block; all W slices preloaded.
__global__ __launch_bounds__(256) void compute_T_fused(const float* __restrict__ h,
    const float* __restrict__ We2, const float* __restrict__ be2,
    float* __restrict__ T, float* __restrict__ hbias) {
  __shared__ float Wall[9 * H * H];   // 36 KB
  __shared__ float hs[32][H + 1];
  int tid = threadIdx.x;
  int n0 = blockIdx.x * 32;
  int jb = blockIdx.y;
  int nslice = (jb == 3) ? 9 : 8;
  const float4* Wsrc = (const float4*)(We2 + (size_t)jb * 8 * (H * H));
  for (int v = tid; v < 8 * 256; v += 256) ((float4*)Wall)[v] = Wsrc[v];
  if (jb == 3) ((float4*)(Wall + 8 * H * H))[tid] = ((const float4*)be2)[tid];
  for (int v = tid; v < 32 * H; v += 256) {
    int nl = v >> 5, i = v & 31;
    hs[nl][i] = h[(size_t)(n0 + nl) * H + i];
  }
  __syncthreads();
  int nl = tid >> 3, oq = tid & 7;
  float hreg[H];
#pragma unroll
  for (int i = 0; i < H; i++) hreg[i] = hs[nl][i];
  int n = n0 + nl;
  for (int jj = 0; jj < nslice; jj++) {
    const float4* W4 = (const float4*)(Wall + jj * (H * H));
    float4 acc = make_float4(0.f, 0.f, 0.f, 0.f);
#pragma unroll
    for (int i = 0; i < H; i++) {
      float hi = hreg[i];
      float4 w = W4[i * 8 + oq];
      acc.x += hi * w.x; acc.y += hi * w.y; acc.z += hi * w.z; acc.w += hi * w.w;
    }
    int j = jb * 8 + jj;
    if (j < H) ((float4*)(T + (size_t)n * (H * H) + j * H))[oq] = acc;
    else       ((float4*)(hbias + (size_t)n * H))[oq] = acc;
  }
}

// ---------------- msg: block = 8 src-segments, T rows staged in LDS ----------------
__global__ __launch_bounds__(256) void edge_msg_seg(const float* __restrict__ r,
    const float* __restrict__ T, const float* __restrict__ hbias,
    const int* __restrict__ seg_s, const int* __restrict__ src_s,
    const int* __restrict__ dpos, float* __restrict__ msg_d) {
  __shared__ float Ts[8 * TSTR];  // 32.9 KB
  __shared__ float hb[8 * H];     // 1 KB
  int tid = threadIdx.x;
  int n0 = blockIdx.x * 8;        // 2500 * 8 == 20000
  const float4* Tg = (const float4*)(T + (size_t)n0 * (H * H));
#pragma unroll
  for (int rr = 0; rr < 8; rr++) {
    ((float4*)(Ts + rr * TSTR))[tid] = Tg[rr * 256 + tid];
  }
  if (tid < 8 * H) hb[tid] = hbias[(size_t)n0 * H + tid];
  __syncthreads();
  int estart = seg_s[n0], eend = seg_s[n0 + 8];
  int t = tid & 7;
  for (int e = estart + (tid >> 3); e < eend; e += 32) {
    int s = src_s[e] - n0;        // 0..7
    int pd = dpos[e];
    float4 rv = ((const float4*)(r + (size_t)e * H))[t];
    float4 acc = ((const float4*)(hb + s * H))[t];
    const float4* Trow = (const float4*)(Ts + s * TSTR);
#pragma unroll
    for (int j = 0; j < H; j++) {
      float mine = ((j & 3) == 0) ? rv.x : ((j & 3) == 1) ? rv.y
                 : ((j & 3) == 2) ? rv.z : rv.w;
      float rj = __shfl(mine, j >> 2, 8);      // broadcast within 8-lane edge group
      float4 w = Trow[j * 8 + t];
      acc.x += rj * w.x; acc.y += rj * w.y; acc.z += rj * w.z; acc.w += rj * w.w;
    }
    ((float4*)(msg_d + (size_t)pd * H))[t] = acc;
  }
}

// ---------------- fallback: atomic scatter-add (if workspace too small) ------------
__global__ __launch_bounds__(256) void edge_msg_atomic(const float* __restrict__ r,
    const float* __restrict__ T, const float* __restrict__ hbias,
    const int* __restrict__ src_s, const int* __restrict__ dst_s,
    float* __restrict__ agg) {
  __shared__ float rs[32][H + 1];
  int tid = threadIdx.x;
  int nchunk = gridDim.x;
  int c = (blockIdx.x & 7) * (nchunk >> 3) + (blockIdx.x >> 3);
  int e0 = c * 32;
  for (int v = tid; v < 32 * H; v += 256) {
    int el = v >> 5, j = v & 31;
    rs[el][j] = r[(size_t)(e0 + el) * H + j];
  }
  __syncthreads();
  int el = tid >> 3;
  int t = tid & 7;
  int e = e0 + el;
  int s = src_s[e], d = dst_s[e];
  const float4* Tp = (const float4*)(T + (size_t)s * (H * H));
  float4 acc = ((const float4*)(hbias + (size_t)s * H))[t];
#pragma unroll 8
  for (int j = 0; j < H; j++) {
    float rj = rs[el][j];
    float4 w = Tp[j * 8 + t];
    acc.x += rj * w.x; acc.y += rj * w.y; acc.z += rj * w.z; acc.w += rj * w.w;
  }
  float* ap = agg + (size_t)d * H + t * 4;
  atomicAdd(ap + 0, acc.x);
  atomicAdd(ap + 1, acc.y);
  atomicAdd(ap + 2, acc.z);
  atomicAdd(ap + 3, acc.w);
}

// ---------------- fused segment-reduce + mean + relu + GRU, 8 nodes/block ----------
// Reduce uses 4 independent accumulators -> 4 rows in flight per lane (R6 was
// 1-deep and latency-bound at 46us despite occupancy fix).
__global__ __launch_bounds__(256) void seg_gru(const float* __restrict__ msg_d,
    const int* __restrict__ seg_d, const float* __restrict__ invdeg,
    const float* __restrict__ Wih, const float* __restrict__ Whh,
    const float* __restrict__ bih, const float* __restrict__ bhh,
    float* __restrict__ h) {
  __shared__ float Wis[3 * H][H + 1];   // 12.4 KB
  __shared__ float Whs[3 * H][H + 1];   // 12.4 KB
  __shared__ float xs[8][H + 1];
  __shared__ float hsm[8][H + 1];
  int tid = threadIdx.x;
  for (int v = tid; v < 3 * H * H; v += 256) {
    int k = v / H, i = v % H;
    Wis[k][i] = Wih[v];
    Whs[k][i] = Whh[v];
  }
  int node = tid >> 5, o = tid & 31;
  int n = blockIdx.x * 8 + node;        // 2500*8 == 20000 exactly
  int a = seg_d[n], bseg = seg_d[n + 1];
  const float* mp = msg_d + (size_t)a * H + o;
  float s0 = 0.f, s1 = 0.f, s2 = 0.f, s3 = 0.f;
  int p = a;
  for (; p + 4 <= bseg; p += 4) {
    float m0 = mp[0], m1 = mp[H], m2 = mp[2 * H], m3 = mp[3 * H];
    mp += 4 * H;
    s0 += m0; s1 += m1; s2 += m2; s3 += m3;
  }
  for (; p < bseg; p++) { s0 += *mp; mp += H; }
  float s = (s0 + s1) + (s2 + s3);
  xs[node][o] = fmaxf(s * invdeg[n], 0.0f);
  float hval = h[(size_t)n * H + o];
  hsm[node][o] = hval;
  __syncthreads();
  float gi0 = bih[o], gi1 = bih[H + o], gi2 = bih[2 * H + o];
  float gh0 = bhh[o], gh1 = bhh[H + o], gh2 = bhh[2 * H + o];
#pragma unroll
  for (int i = 0; i < H; i++) {
    float xi = xs[node][i], hi = hsm[node][i];
    gi0 += xi * Wis[o][i];
    gh0 += hi * Whs[o][i];
    gi1 += xi * Wis[H + o][i];
    gh1 += hi * Whs[H + o][i];
    gi2 += xi * Wis[2 * H + o][i];
    gh2 += hi * Whs[2 * H + o][i];
  }
  float rg = fast_sigmoid(gi0 + gh0);
  float zg = fast_sigmoid(gi1 + gh1);
  float ng = fast_tanh(gi2 + rg * gh2);
  h[(size_t)n * H + o] = (1.0f - zg) * ng + zg * hval;
}

// ---------------- fallback GRU reading agg (8 nodes/block) ----------------
__global__ __launch_bounds__(256) void gru_update(const float* __restrict__ agg,
    const float* __restrict__ invdeg, const float* __restrict__ Wih,
    const float* __restrict__ Whh, const float* __restrict__ bih,
    const float* __restrict__ bhh, float* __restrict__ h) {
  __shared__ float Wis[3 * H][H + 1];
  __shared__ float Whs[3 * H][H + 1];
  __shared__ float xs[8][H + 1];
  __shared__ float hsm[8][H + 1];
  int tid = threadIdx.x;
  for (int v = tid; v < 3 * H * H; v += 256) {
    int k = v / H, i = v % H;
    Wis[k][i] = Wih[v];
    Whs[k][i] = Whh[v];
  }
  int node = tid >> 5, o = tid & 31;
  int n = blockIdx.x * 8 + node;
  xs[node][o] = fmaxf(agg[(size_t)n * H + o] * invdeg[n], 0.0f);
  float hval = h[(size_t)n * H + o];
  hsm[node][o] = hval;
  __syncthreads();
  float gi0 = bih[o], gi1 = bih[H + o], gi2 = bih[2 * H + o];
  float gh0 = bhh[o], gh1 = bhh[H + o], gh2 = bhh[2 * H + o];
#pragma unroll
  for (int i = 0; i < H; i++) {
    float xi = xs[node][i], hi = hsm[node][i];
    gi0 += xi * Wis[o][i];
    gh0 += hi * Whs[o][i];
    gi1 += xi * Wis[H + o][i];
    gh1 += hi * Whs[H + o][i];
    gi2 += xi * Wis[2 * H + o][i];
    gh2 += hi * Whs[2 * H + o][i];
  }
  float rg = fast_sigmoid(gi0 + gh0);
  float zg = fast_sigmoid(gi1 + gh1);
  float ng = fast_tanh(gi2 + rg * gh2);
  h[(size_t)n * H + o] = (1.0f - zg) * ng + zg * hval;
}

// ---------------- graph mean readout: segmented (gid sorted), no atomics -----------
__global__ __launch_bounds__(256) void readout_graph(const float* __restrict__ h,
    const int* __restrict__ gstart, float* __restrict__ out) {
  __shared__ float red[8][H + 1];
  int g = blockIdx.x;
  int a = gstart[g], b = gstart[g + 1];
  int r = threadIdx.x >> 5, o = threadIdx.x & 31;
  float s = 0.0f;
  for (int n = a + r; n < b; n += 8) s += h[(size_t)n * H + o];
  red[r][o] = s;
  __syncthreads();
  if (r == 0) {
    float t = 0.0f;
#pragma unroll
    for (int k = 0; k < 8; k++) t += red[k][o];
    out[g * H + o] = t / fmaxf((float)(b - a), 1.0f);
  }
}

extern "C" void kernel_launch(void* const* d_in, const int* in_sizes, int n_in,
                              void* d_out, int out_size, void* d_ws, size_t ws_size,
                              hipStream_t stream) {
  const float* n_feat = (const float*)d_in[0];
  const float* e_feat = (const float*)d_in[1];
  const int*   src    = (const int*)d_in[2];
  const int*   dst    = (const int*)d_in[3];
  const int*   gid    = (const int*)d_in[4];
  const float* W_atom = (const float*)d_in[5];
  const float* b_atom = (const float*)d_in[6];
  const float* W_bond = (const float*)d_in[7];
  const float* b_bond = (const float*)d_in[8];
  const float* W_e1   = (const float*)d_in[9];
  const float* b_e1   = (const float*)d_in[10];
  const float* W_e2   = (const float*)d_in[11];
  const float* b_e2   = (const float*)d_in[12];
  const float* W_ih   = (const float*)d_in[13];
  const float* W_hh   = (const float*)d_in[14];
  const float* b_ih   = (const float*)d_in[15];
  const float* b_hh   = (const float*)d_in[16];
  float* out = (float*)d_out;

  // workspace carve-up
  char* ws = (char*)d_ws;
  size_t off = 0;
  float* h      = (float*)(ws + off); off += (size_t)N_NODES * H * 4;       // 2.56 MB
  float* rbuf   = (float*)(ws + off); off += (size_t)N_EDGES * H * 4;       // 40.96 MB
  float* T      = (float*)(ws + off); off += (size_t)N_NODES * H * H * 4;   // 81.92 MB
  float* hbias  = (float*)(ws + off); off += (size_t)N_NODES * H * 4;       // 2.56 MB
  int*   hist_s = (int*)(ws + off);   off += (size_t)N_NODES * 4;
  int*   hist_d = (int*)(ws + off);   off += (size_t)N_NODES * 4;
  int*   cur_s  = (int*)(ws + off);   off += (size_t)N_NODES * 4;
  int*   cur_d  = (int*)(ws + off);   off += (size_t)N_NODES * 4;
  int*   seg_s  = (int*)(ws + off);   off += (size_t)(N_NODES + 1) * 4;
  int*   seg_d  = (int*)(ws + off);   off += (size_t)(N_NODES + 1) * 4;
  float* invdeg = (float*)(ws + off); off += (size_t)N_NODES * 4;
  int*   part   = (int*)(ws + off);   off += (size_t)2 * SCP * 4;           // 162 KB
  int*   bsum   = (int*)(ws + off);   off += (size_t)2 * SCB * 4;
  int*   src_s  = (int*)(ws + off);   off += (size_t)N_EDGES * 4;           // 1.28 MB
  int*   dst_s  = (int*)(ws + off);   off += (size_t)N_EDGES * 4;           // 1.28 MB
  int*   dpos   = (int*)(ws + off);   off += (size_t)N_EDGES * 4;           // 1.28 MB
  int*   gstart = (int*)(ws + off);   off += (size_t)(NB + 1) * 4;
  float* agg    = (float*)(ws + off); off += (size_t)N_NODES * H * 4;       // 2.56 MB (fallback)
  float* msg_d  = (float*)(ws + off); off += (size_t)N_EDGES * H * 4;       // 40.96 MB
  int use_msg = (ws_size >= off) ? 1 : 0;
  int* eidx = (int*)T;   // alias: eidx only live before first compute_T

  // node embedding
  embed_nodes<<<N_NODES / 8, 256, 0, stream>>>(n_feat, W_atom, b_atom, h);

  // dual counting sort prep: histograms -> multi-block scans -> scatter
  hipMemsetAsync(hist_s, 0, (size_t)2 * N_NODES * 4, stream);  // hist_s+hist_d adjacent
  hist2<<<(N_EDGES + 255) / 256, 256, 0, stream>>>(src, dst, hist_s, hist_d);
  {
    dim3 gs(SCB, 2);
    scan_partial<<<gs, 256, 0, stream>>>(hist_s, hist_d, part, bsum);
    scan_tops<<<1, 256, 0, stream>>>(bsum);
    scan_final<<<gs, 256, 0, stream>>>(part, bsum, hist_d, cur_s, cur_d,
                                       seg_s, seg_d, invdeg);
  }
  scatter2<<<(N_EDGES + 255) / 256, 256, 0, stream>>>(src, dst, cur_s, cur_d,
                                                      src_s, dst_s, eidx, dpos);
  graph_bounds<<<1, NB, 0, stream>>>(gid, gstart);

  // edge-net first layer in src-sorted order (layer-invariant)
  edge_r<<<N_EDGES / 32, 256, 0, stream>>>(e_feat, W_bond, b_bond, W_e1, b_e1,
                                           eidx, rbuf);

  for (int layer = 0; layer < 2; layer++) {
    dim3 gT(N_NODES / 32, 4);
    compute_T_fused<<<gT, 256, 0, stream>>>(h, W_e2, b_e2, T, hbias);
    if (use_msg) {
      edge_msg_seg<<<N_NODES / 8, 256, 0, stream>>>(rbuf, T, hbias, seg_s, src_s,
                                                    dpos, msg_d);
      seg_gru<<<N_NODES / 8, 256, 0, stream>>>(msg_d, seg_d, invdeg,
                                               W_ih, W_hh, b_ih, b_hh, h);
    } else {
      hipMemsetAsync(agg, 0, (size_t)N_NODES * H * 4, stream);
      edge_msg_atomic<<<N_EDGES / 32, 256, 0, stream>>>(rbuf, T, hbias, src_s, dst_s,
                                                        agg);
      gru_update<<<N_NODES / 8, 256, 0, stream>>>(agg, invdeg,
                                                  W_ih, W_hh, b_ih, b_hh, h);
    }
  }

  // graph mean readout (segmented, atomic-free)
  readout_graph<<<NB, 256, 0, stream>>>(h, gstart, out);
}

// Round 9
// 396.620 us; speedup vs baseline: 2.3483x; 1.0570x over previous
//
#include <hip/hip_runtime.h>
#include <hip/hip_fp16.h>
#include <math.h>

#define N_NODES 20000
#define N_EDGES 320000
#define NB 128
#define H 32
#define AF 64
#define BF 16
#define SCB 79           // scan blocks: ceil(20000/256)
#define SCP 20224        // padded per-pass partial size (79*256)

typedef _Float16 f16x2 __attribute__((ext_vector_type(2)));

__device__ __forceinline__ float fast_sigmoid(float x) {
  return 1.0f / (1.0f + __expf(-x));
}
__device__ __forceinline__ float fast_tanh(float x) {
  float e2 = __expf(2.0f * x);
  return 1.0f - 2.0f / (e2 + 1.0f);    // inf-safe
}
// pack two floats as fp16 pair (RNE cast, low = a)
__device__ __forceinline__ unsigned int pk2(float a, float b) {
  union { f16x2 h; unsigned int u; } p;
  p.h[0] = (_Float16)a;
  p.h[1] = (_Float16)b;
  return p.u;
}
// fp16x2 dot with fp32 accumulate: c + a.x*b.x + a.y*b.y
__device__ __forceinline__ float dot2(unsigned int a, unsigned int b, float c) {
  union { unsigned int u; f16x2 h; } ua, ub;
  ua.u = a; ub.u = b;
#if __has_builtin(__builtin_amdgcn_fdot2)
  return __builtin_amdgcn_fdot2(ua.h, ub.h, c, false);
#else
  return c + (float)ua.h[0] * (float)ub.h[0] + (float)ua.h[1] * (float)ub.h[1];
#endif
}

// ---------------- node embedding: h = nf @ W_atom + b ----------------
__global__ __launch_bounds__(256) void embed_nodes(const float* __restrict__ nf,
    const float* __restrict__ W, const float* __restrict__ b, float* __restrict__ h) {
  __shared__ float Ws[AF * H];     // 8 KB
  __shared__ float nfs[8][AF];
  int tid = threadIdx.x;
  for (int v = tid; v < AF * H; v += 256) Ws[v] = W[v];
  int n0 = blockIdx.x * 8;
  for (int v = tid; v < 8 * AF; v += 256) {
    int nl = v / AF, k = v % AF;
    int n = n0 + nl;
    nfs[nl][k] = (n < N_NODES) ? nf[n * AF + k] : 0.0f;
  }
  __syncthreads();
  int nl = tid / H, o = tid % H;
  int n = n0 + nl;
  if (n >= N_NODES) return;
  float acc = b[o];
#pragma unroll
  for (int k = 0; k < AF; k++) acc += nfs[nl][k] * Ws[k * H + o];
  h[n * H + o] = acc;
}

// ---------------- histograms over src AND dst ----------------
__global__ void hist2(const int* __restrict__ src, const int* __restrict__ dst,
                      int* __restrict__ hsrc, int* __restrict__ hdst) {
  int e = blockIdx.x * 256 + threadIdx.x;
  if (e < N_EDGES) {
    atomicAdd(&hsrc[src[e]], 1);
    atomicAdd(&hdst[dst[e]], 1);
  }
}

// ---------------- multi-block exclusive scan ----------------
__global__ __launch_bounds__(256) void scan_partial(const int* __restrict__ hist_s,
    const int* __restrict__ hist_d, int* __restrict__ part, int* __restrict__ bsum) {
  __shared__ int wsums[4];
  int which = blockIdx.y;
  const int* __restrict__ hh = which ? hist_d : hist_s;
  int i = blockIdx.x * 256 + threadIdx.x;
  int v = (i < N_NODES) ? hh[i] : 0;
  int lane = threadIdx.x & 63, wid = threadIdx.x >> 6;
  int incl = v;
#pragma unroll
  for (int off = 1; off < 64; off <<= 1) {
    int t = __shfl_up(incl, off, 64);
    if (lane >= off) incl += t;
  }
  if (lane == 63) wsums[wid] = incl;
  __syncthreads();
  int woff = 0;
#pragma unroll
  for (int w = 0; w < 4; w++) if (w < wid) woff += wsums[w];
  part[which * SCP + i] = woff + incl - v;
  if (threadIdx.x == 0)
    bsum[which * SCB + blockIdx.x] = wsums[0] + wsums[1] + wsums[2] + wsums[3];
}

__global__ __launch_bounds__(256) void scan_tops(int* __restrict__ bsum) {
  __shared__ int s[2 * SCB];
  int tid = threadIdx.x;
  if (tid < 2 * SCB) s[tid] = bsum[tid];
  __syncthreads();
  if (tid < 2) {
    int run = 0;
    for (int b = 0; b < SCB; b++) { int t = s[tid * SCB + b]; s[tid * SCB + b] = run; run += t; }
  }
  __syncthreads();
  if (tid < 2 * SCB) bsum[tid] = s[tid];
}

__global__ __launch_bounds__(256) void scan_final(const int* __restrict__ part,
    const int* __restrict__ bsum, const int* __restrict__ hist_d,
    int* __restrict__ cur_s, int* __restrict__ cur_d,
    int* __restrict__ seg_s, int* __restrict__ seg_d, float* __restrict__ inv_deg) {
  int which = blockIdx.y;
  int i = blockIdx.x * 256 + threadIdx.x;
  if (i >= N_NODES) return;
  int ex = part[which * SCP + i] + bsum[which * SCB + blockIdx.x];
  if (which == 0) {
    cur_s[i] = ex; seg_s[i] = ex;
    if (i == 0) seg_s[N_NODES] = N_EDGES;
  } else {
    cur_d[i] = ex; seg_d[i] = ex;
    inv_deg[i] = 1.0f / fmaxf((float)hist_d[i], 1.0f);
    if (i == 0) seg_d[N_NODES] = N_EDGES;
  }
}

// scatter: src-sorted position ps gets (src, orig-edge, dst-sorted position)
__global__ void scatter2(const int* __restrict__ src, const int* __restrict__ dst,
    int* __restrict__ cur_s, int* __restrict__ cur_d,
    int* __restrict__ src_s, int* __restrict__ dst_s,
    int* __restrict__ eidx, int* __restrict__ dpos) {
  int e = blockIdx.x * 256 + threadIdx.x;
  if (e >= N_EDGES) return;
  int s = src[e], d = dst[e];
  int ps = atomicAdd(&cur_s[s], 1);
  int pd = atomicAdd(&cur_d[d], 1);
  src_s[ps] = s;
  dst_s[ps] = d;
  eidx[ps] = e;
  dpos[ps] = pd;
}

// ---------------- graph segment bounds via binary search (gid is sorted) -----------
__global__ void graph_bounds(const int* __restrict__ gid, int* __restrict__ gstart) {
  int g = threadIdx.x;            // blockDim.x == NB
  int lo = 0, hi = N_NODES;
  while (lo < hi) { int mid = (lo + hi) >> 1; if (gid[mid] < g) lo = mid + 1; else hi = mid; }
  gstart[g] = lo;
  if (g == 0) gstart[NB] = N_NODES;
}

// ---------------- edge hidden: rh = f16-packed relu((ef@Wb+bb)@We1+be1) ------------
// rh[e] = 16 uints; uint jp holds (r[2jp], r[2jp+1]) as fp16 pair.
__global__ __launch_bounds__(256) void edge_r(const float* __restrict__ ef,
    const float* __restrict__ Wb, const float* __restrict__ bb,
    const float* __restrict__ We1, const float* __restrict__ be1,
    const int* __restrict__ eidx, unsigned int* __restrict__ rh) {
  __shared__ float Wbs[BF * H];   // 2 KB
  __shared__ float W1s[H * H];    // 4 KB
  __shared__ float efs[32][BF + 1];
  __shared__ float hbs[32][H + 1];
  int tid = threadIdx.x;
  for (int v = tid; v < BF * H; v += 256) Wbs[v] = Wb[v];
  for (int v = tid; v < H * H; v += 256) W1s[v] = We1[v];
  int e0 = blockIdx.x * 32;
  for (int v = tid; v < 32 * BF; v += 256) {
    int el = v >> 4, k = v & 15;
    int ee = eidx[e0 + el];
    efs[el][k] = ef[ee * BF + k];
  }
  __syncthreads();
  int el = tid >> 3, oq = tid & 7, o0 = oq * 4;
  const float4* Wb4 = (const float4*)Wbs;
  const float4* W14 = (const float4*)W1s;
  float4 hb = ((const float4*)bb)[oq];
#pragma unroll
  for (int kk = 0; kk < BF; kk++) {
    float e_ = efs[el][kk];
    float4 w = Wb4[kk * 8 + oq];
    hb.x += e_ * w.x; hb.y += e_ * w.y; hb.z += e_ * w.z; hb.w += e_ * w.w;
  }
  hbs[el][o0 + 0] = hb.x; hbs[el][o0 + 1] = hb.y;
  hbs[el][o0 + 2] = hb.z; hbs[el][o0 + 3] = hb.w;
  __syncthreads();
  float4 acc = ((const float4*)be1)[oq];
#pragma unroll
  for (int j = 0; j < H; j++) {
    float hj = hbs[el][j];
    float4 w = W14[j * 8 + oq];
    acc.x += hj * w.x; acc.y += hj * w.y; acc.z += hj * w.z; acc.w += hj * w.w;
  }
  acc.x = fmaxf(acc.x, 0.0f); acc.y = fmaxf(acc.y, 0.0f);
  acc.z = fmaxf(acc.z, 0.0f); acc.w = fmaxf(acc.w, 0.0f);
  uint2 st;
  st.x = pk2(acc.x, acc.y);     // jp = 2*oq
  st.y = pk2(acc.z, acc.w);     // jp = 2*oq+1
  ((uint2*)(rh + (size_t)(e0 + el) * 16))[oq] = st;
}

// ---------------- Th[n][jp][o] fp16 pairs over j; hbias fp32 ----------------
// grid (625, 4): one barrier per block; all W slices preloaded.
__global__ __launch_bounds__(256) void compute_T_fused(const float* __restrict__ h,
    const float* __restrict__ We2, const float* __restrict__ be2,
    unsigned int* __restrict__ Th, float* __restrict__ hbias) {
  __shared__ float Wall[9 * H * H];   // 36 KB
  __shared__ float hs[32][H + 1];
  int tid = threadIdx.x;
  int n0 = blockIdx.x * 32;
  int jb = blockIdx.y;
  int nslice = (jb == 3) ? 9 : 8;
  const float4* Wsrc = (const float4*)(We2 + (size_t)jb * 8 * (H * H));
  for (int v = tid; v < 8 * 256; v += 256) ((float4*)Wall)[v] = Wsrc[v];
  if (jb == 3) ((float4*)(Wall + 8 * H * H))[tid] = ((const float4*)be2)[tid];
  for (int v = tid; v < 32 * H; v += 256) {
    int nl = v >> 5, i = v & 31;
    hs[nl][i] = h[(size_t)(n0 + nl) * H + i];
  }
  __syncthreads();
  int nl = tid >> 3, oq = tid & 7;
  float hreg[H];
#pragma unroll
  for (int i = 0; i < H; i++) hreg[i] = hs[nl][i];
  int n = n0 + nl;
  float4 pacc = make_float4(0.f, 0.f, 0.f, 0.f);
  for (int jj = 0; jj < nslice; jj++) {
    const float4* W4 = (const float4*)(Wall + jj * (H * H));
    float4 acc = make_float4(0.f, 0.f, 0.f, 0.f);
#pragma unroll
    for (int i = 0; i < H; i++) {
      float hi = hreg[i];
      float4 w = W4[i * 8 + oq];
      acc.x += hi * w.x; acc.y += hi * w.y; acc.z += hi * w.z; acc.w += hi * w.w;
    }
    int j = jb * 8 + jj;
    if (j < H) {
      if (jj & 1) {                       // j parity == jj parity (jb*8 even)
        uint4 st;
        st.x = pk2(pacc.x, acc.x);
        st.y = pk2(pacc.y, acc.y);
        st.z = pk2(pacc.z, acc.z);
        st.w = pk2(pacc.w, acc.w);
        ((uint4*)(Th + (size_t)n * 512 + (j >> 1) * 32))[oq] = st;
      } else {
        pacc = acc;
      }
    } else {
      ((float4*)(hbias + (size_t)n * H))[oq] = acc;
    }
  }
}

// ---------------- msg: block = 8 src-segments, fp16 T in LDS, dot2 inner loop ------
// Waves iterate segment-by-segment (wave-uniform s) -> LDS reads are 8-address
// broadcasts spanning all 32 banks: zero conflicts. Wave rotation balances load.
__global__ __launch_bounds__(256) void edge_msg_seg(const unsigned int* __restrict__ rh,
    const unsigned int* __restrict__ Th, const float* __restrict__ hbias,
    const int* __restrict__ seg_s, const int* __restrict__ dpos,
    float* __restrict__ msg_d) {
  __shared__ unsigned int Ts[8 * 512];  // 16 KB
  __shared__ float hb[8 * H];           // 1 KB
  __shared__ int sseg[9];
  int tid = threadIdx.x;
  int n0 = blockIdx.x * 8;              // 2500 * 8 == 20000
  const uint4* Tg = (const uint4*)(Th + (size_t)n0 * 512);
#pragma unroll
  for (int v = 0; v < 4; v++) ((uint4*)Ts)[tid + v * 256] = Tg[tid + v * 256];
  hb[tid] = hbias[(size_t)n0 * H + tid];
  if (tid < 9) sseg[tid] = seg_s[n0 + tid];
  __syncthreads();
  int lane = tid & 63, wid = tid >> 6;
  int el = lane >> 3, t = lane & 7;
  for (int s = 0; s < 8; s++) {
    int a = sseg[s], bnd = sseg[s + 1];
    const unsigned int* Trow = Ts + s * 512;
    float4 hbv = ((const float4*)(hb + s * H))[t];
    int ww = (wid + s) & 3;             // rotate wave->chunk mapping per segment
    for (int base = a + ww * 8; base < bnd; base += 32) {
      int e = base + el;
      bool valid = (e < bnd);
      int pd = 0;
      uint2 ru2 = make_uint2(0u, 0u);
      if (valid) {
        pd = dpos[e];
        ru2 = ((const uint2*)(rh + (size_t)e * 16))[t];
      }
      float4 acc = hbv;
#pragma unroll
      for (int jp = 0; jp < 16; jp++) {
        unsigned int mine = (jp & 1) ? ru2.y : ru2.x;
        unsigned int rj = (unsigned int)__shfl((int)mine, jp >> 1, 8);
        uint4 tw = ((const uint4*)(Trow + jp * 32))[t];
        acc.x = dot2(rj, tw.x, acc.x);
        acc.y = dot2(rj, tw.y, acc.y);
        acc.z = dot2(rj, tw.z, acc.z);
        acc.w = dot2(rj, tw.w, acc.w);
      }
      if (valid) ((float4*)(msg_d + (size_t)pd * H))[t] = acc;
    }
  }
}

// ---------------- fallback: atomic scatter-add (if workspace too small) ------------
__global__ __launch_bounds__(256) void edge_msg_atomic(const unsigned int* __restrict__ rh,
    const unsigned int* __restrict__ Th, const float* __restrict__ hbias,
    const int* __restrict__ src_s, const int* __restrict__ dst_s,
    float* __restrict__ agg) {
  int tid = threadIdx.x;
  int e0 = blockIdx.x * 32;
  int el = tid >> 3, t = tid & 7;
  int e = e0 + el;
  int s = src_s[e], d = dst_s[e];
  uint2 ru2 = ((const uint2*)(rh + (size_t)e * 16))[t];
  float4 acc = ((const float4*)(hbias + (size_t)s * H))[t];
  const unsigned int* Trow = Th + (size_t)s * 512;
#pragma unroll
  for (int jp = 0; jp < 16; jp++) {
    unsigned int mine = (jp & 1) ? ru2.y : ru2.x;
    unsigned int rj = (unsigned int)__shfl((int)mine, jp >> 1, 8);
    uint4 tw = ((const uint4*)(Trow + jp * 32))[t];
    acc.x = dot2(rj, tw.x, acc.x);
    acc.y = dot2(rj, tw.y, acc.y);
    acc.z = dot2(rj, tw.z, acc.z);
    acc.w = dot2(rj, tw.w, acc.w);
  }
  float* ap = agg + (size_t)d * H + t * 4;
  atomicAdd(ap + 0, acc.x);
  atomicAdd(ap + 1, acc.y);
  atomicAdd(ap + 2, acc.z);
  atomicAdd(ap + 3, acc.w);
}

// ---------------- fused segment-reduce + mean + relu + GRU, 8 nodes/block ----------
__global__ __launch_bounds__(256) void seg_gru(const float* __restrict__ msg_d,
    const int* __restrict__ seg_d, const float* __restrict__ invdeg,
    const float* __restrict__ Wih, const float* __restrict__ Whh,
    const float* __restrict__ bih, const float* __restrict__ bhh,
    float* __restrict__ h) {
  __shared__ float Wis[3 * H][H + 1];   // 12.4 KB
  __shared__ float Whs[3 * H][H + 1];   // 12.4 KB
  __shared__ float xs[8][H + 1];
  __shared__ float hsm[8][H + 1];
  int tid = threadIdx.x;
  for (int v = tid; v < 3 * H * H; v += 256) {
    int k = v / H, i = v % H;
    Wis[k][i] = Wih[v];
    Whs[k][i] = Whh[v];
  }
  int node = tid >> 5, o = tid & 31;
  int n = blockIdx.x * 8 + node;        // 2500*8 == 20000 exactly
  int a = seg_d[n], bseg = seg_d[n + 1];
  const float* mp = msg_d + (size_t)a * H + o;
  float s0 = 0.f, s1 = 0.f, s2 = 0.f, s3 = 0.f;
  int p = a;
  for (; p + 4 <= bseg; p += 4) {
    float m0 = mp[0], m1 = mp[H], m2 = mp[2 * H], m3 = mp[3 * H];
    mp += 4 * H;
    s0 += m0; s1 += m1; s2 += m2; s3 += m3;
  }
  for (; p < bseg; p++) { s0 += *mp; mp += H; }
  float s = (s0 + s1) + (s2 + s3);
  xs[node][o] = fmaxf(s * invdeg[n], 0.0f);
  float hval = h[(size_t)n * H + o];
  hsm[node][o] = hval;
  __syncthreads();
  float gi0 = bih[o], gi1 = bih[H + o], gi2 = bih[2 * H + o];
  float gh0 = bhh[o], gh1 = bhh[H + o], gh2 = bhh[2 * H + o];
#pragma unroll
  for (int i = 0; i < H; i++) {
    float xi = xs[node][i], hi = hsm[node][i];
    gi0 += xi * Wis[o][i];
    gh0 += hi * Whs[o][i];
    gi1 += xi * Wis[H + o][i];
    gh1 += hi * Whs[H + o][i];
    gi2 += xi * Wis[2 * H + o][i];
    gh2 += hi * Whs[2 * H + o][i];
  }
  float rg = fast_sigmoid(gi0 + gh0);
  float zg = fast_sigmoid(gi1 + gh1);
  float ng = fast_tanh(gi2 + rg * gh2);
  h[(size_t)n * H + o] = (1.0f - zg) * ng + zg * hval;
}

// ---------------- fallback GRU reading agg (8 nodes/block) ----------------
__global__ __launch_bounds__(256) void gru_update(const float* __restrict__ agg,
    const float* __restrict__ invdeg, const float* __restrict__ Wih,
    const float* __restrict__ Whh, const float* __restrict__ bih,
    const float* __restrict__ bhh, float* __restrict__ h) {
  __shared__ float Wis[3 * H][H + 1];
  __shared__ float Whs[3 * H][H + 1];
  __shared__ float xs[8][H + 1];
  __shared__ float hsm[8][H + 1];
  int tid = threadIdx.x;
  for (int v = tid; v < 3 * H * H; v += 256) {
    int k = v / H, i = v % H;
    Wis[k][i] = Wih[v];
    Whs[k][i] = Whh[v];
  }
  int node = tid >> 5, o = tid & 31;
  int n = blockIdx.x * 8 + node;
  xs[node][o] = fmaxf(agg[(size_t)n * H + o] * invdeg[n], 0.0f);
  float hval = h[(size_t)n * H + o];
  hsm[node][o] = hval;
  __syncthreads();
  float gi0 = bih[o], gi1 = bih[H + o], gi2 = bih[2 * H + o];
  float gh0 = bhh[o], gh1 = bhh[H + o], gh2 = bhh[2 * H + o];
#pragma unroll
  for (int i = 0; i < H; i++) {
    float xi = xs[node][i], hi = hsm[node][i];
    gi0 += xi * Wis[o][i];
    gh0 += hi * Whs[o][i];
    gi1 += xi * Wis[H + o][i];
    gh1 += hi * Whs[H + o][i];
    gi2 += xi * Wis[2 * H + o][i];
    gh2 += hi * Whs[2 * H + o][i];
  }
  float rg = fast_sigmoid(gi0 + gh0);
  float zg = fast_sigmoid(gi1 + gh1);
  float ng = fast_tanh(gi2 + rg * gh2);
  h[(size_t)n * H + o] = (1.0f - zg) * ng + zg * hval;
}

// ---------------- graph mean readout: segmented (gid sorted), no atomics -----------
__global__ __launch_bounds__(256) void readout_graph(const float* __restrict__ h,
    const int* __restrict__ gstart, float* __restrict__ out) {
  __shared__ float red[8][H + 1];
  int g = blockIdx.x;
  int a = gstart[g], b = gstart[g + 1];
  int r = threadIdx.x >> 5, o = threadIdx.x & 31;
  float s = 0.0f;
  for (int n = a + r; n < b; n += 8) s += h[(size_t)n * H + o];
  red[r][o] = s;
  __syncthreads();
  if (r == 0) {
    float t = 0.0f;
#pragma unroll
    for (int k = 0; k < 8; k++) t += red[k][o];
    out[g * H + o] = t / fmaxf((float)(b - a), 1.0f);
  }
}

extern "C" void kernel_launch(void* const* d_in, const int* in_sizes, int n_in,
                              void* d_out, int out_size, void* d_ws, size_t ws_size,
                              hipStream_t stream) {
  const float* n_feat = (const float*)d_in[0];
  const float* e_feat = (const float*)d_in[1];
  const int*   src    = (const int*)d_in[2];
  const int*   dst    = (const int*)d_in[3];
  const int*   gid    = (const int*)d_in[4];
  const float* W_atom = (const float*)d_in[5];
  const float* b_atom = (const float*)d_in[6];
  const float* W_bond = (const float*)d_in[7];
  const float* b_bond = (const float*)d_in[8];
  const float* W_e1   = (const float*)d_in[9];
  const float* b_e1   = (const float*)d_in[10];
  const float* W_e2   = (const float*)d_in[11];
  const float* b_e2   = (const float*)d_in[12];
  const float* W_ih   = (const float*)d_in[13];
  const float* W_hh   = (const float*)d_in[14];
  const float* b_ih   = (const float*)d_in[15];
  const float* b_hh   = (const float*)d_in[16];
  float* out = (float*)d_out;

  // workspace carve-up
  char* ws = (char*)d_ws;
  size_t off = 0;
  float*        h      = (float*)(ws + off); off += (size_t)N_NODES * H * 4;     // 2.56 MB
  unsigned int* rh     = (unsigned int*)(ws + off); off += (size_t)N_EDGES * 16 * 4;  // 20.48 MB
  unsigned int* Th     = (unsigned int*)(ws + off); off += (size_t)N_NODES * 512 * 4; // 40.96 MB
  float*        hbias  = (float*)(ws + off); off += (size_t)N_NODES * H * 4;     // 2.56 MB
  int*   hist_s = (int*)(ws + off);   off += (size_t)N_NODES * 4;
  int*   hist_d = (int*)(ws + off);   off += (size_t)N_NODES * 4;
  int*   cur_s  = (int*)(ws + off);   off += (size_t)N_NODES * 4;
  int*   cur_d  = (int*)(ws + off);   off += (size_t)N_NODES * 4;
  int*   seg_s  = (int*)(ws + off);   off += (size_t)(N_NODES + 1) * 4;
  int*   seg_d  = (int*)(ws + off);   off += (size_t)(N_NODES + 1) * 4;
  float* invdeg = (float*)(ws + off); off += (size_t)N_NODES * 4;
  int*   part   = (int*)(ws + off);   off += (size_t)2 * SCP * 4;                // 162 KB
  int*   bsum   = (int*)(ws + off);   off += (size_t)2 * SCB * 4;
  int*   src_s  = (int*)(ws + off);   off += (size_t)N_EDGES * 4;                // 1.28 MB
  int*   dst_s  = (int*)(ws + off);   off += (size_t)N_EDGES * 4;                // 1.28 MB
  int*   dpos   = (int*)(ws + off);   off += (size_t)N_EDGES * 4;                // 1.28 MB
  int*   gstart = (int*)(ws + off);   off += (size_t)(NB + 1) * 4;
  float* agg    = (float*)(ws + off); off += (size_t)N_NODES * H * 4;            // 2.56 MB (fallback)
  float* msg_d  = (float*)(ws + off); off += (size_t)N_EDGES * H * 4;            // 40.96 MB
  int use_msg = (ws_size >= off) ? 1 : 0;
  int* eidx = (int*)Th;   // alias: eidx only live before first compute_T

  // node embedding
  embed_nodes<<<N_NODES / 8, 256, 0, stream>>>(n_feat, W_atom, b_atom, h);

  // dual counting sort prep: histograms -> multi-block scans -> scatter
  hipMemsetAsync(hist_s, 0, (size_t)2 * N_NODES * 4, stream);  // hist_s+hist_d adjacent
  hist2<<<(N_EDGES + 255) / 256, 256, 0, stream>>>(src, dst, hist_s, hist_d);
  {
    dim3 gs(SCB, 2);
    scan_partial<<<gs, 256, 0, stream>>>(hist_s, hist_d, part, bsum);
    scan_tops<<<1, 256, 0, stream>>>(bsum);
    scan_final<<<gs, 256, 0, stream>>>(part, bsum, hist_d, cur_s, cur_d,
                                       seg_s, seg_d, invdeg);
  }
  scatter2<<<(N_EDGES + 255) / 256, 256, 0, stream>>>(src, dst, cur_s, cur_d,
                                                      src_s, dst_s, eidx, dpos);
  graph_bounds<<<1, NB, 0, stream>>>(gid, gstart);

  // edge-net first layer in src-sorted order (layer-invariant), fp16-packed output
  edge_r<<<N_EDGES / 32, 256, 0, stream>>>(e_feat, W_bond, b_bond, W_e1, b_e1,
                                           eidx, rh);

  for (int layer = 0; layer < 2; layer++) {
    dim3 gT(N_NODES / 32, 4);
    compute_T_fused<<<gT, 256, 0, stream>>>(h, W_e2, b_e2, Th, hbias);
    if (use_msg) {
      edge_msg_seg<<<N_NODES / 8, 256, 0, stream>>>(rh, Th, hbias, seg_s,
                                                    dpos, msg_d);
      seg_gru<<<N_NODES / 8, 256, 0, stream>>>(msg_d, seg_d, invdeg,
                                               W_ih, W_hh, b_ih, b_hh, h);
    } else {
      hipMemsetAsync(agg, 0, (size_t)N_NODES * H * 4, stream);
      edge_msg_atomic<<<N_EDGES / 32, 256, 0, stream>>>(rh, Th, hbias, src_s, dst_s,
                                                        agg);
      gru_update<<<N_NODES / 8, 256, 0, stream>>>(agg, invdeg,
                                                  W_ih, W_hh, b_ih, b_hh, h);
    }
  }

  // graph mean readout (segmented, atomic-free)
  readout_graph<<<NB, 256, 0, stream>>>(h, gstart, out);
}

// Round 10
// 389.021 us; speedup vs baseline: 2.3941x; 1.0195x over previous
//
#include <hip/hip_runtime.h>
#include <hip/hip_fp16.h>
#include <math.h>

#define N_NODES 20000
#define N_EDGES 320000
#define NB 128
#define H 32
#define AF 64
#define BF 16
#define SCB 79           // scan blocks: ceil(20000/256)
#define SCP 20224        // padded per-pass partial size (79*256)

typedef _Float16 f16x2 __attribute__((ext_vector_type(2)));

__device__ __forceinline__ float fast_sigmoid(float x) {
  return 1.0f / (1.0f + __expf(-x));
}
__device__ __forceinline__ float fast_tanh(float x) {
  float e2 = __expf(2.0f * x);
  return 1.0f - 2.0f / (e2 + 1.0f);    // inf-safe
}
// pack two floats as fp16 pair (RNE cast, low = a)
__device__ __forceinline__ unsigned int pk2(float a, float b) {
  union { f16x2 h; unsigned int u; } p;
  p.h[0] = (_Float16)a;
  p.h[1] = (_Float16)b;
  return p.u;
}
// extract half 0/1 of an fp16 pair as float
__device__ __forceinline__ float uph(unsigned int u, int hi) {
  union { unsigned int u; f16x2 h; } x; x.u = u;
  return hi ? (float)x.h[1] : (float)x.h[0];
}
// fp16x2 dot with fp32 accumulate: c + a.x*b.x + a.y*b.y
__device__ __forceinline__ float dot2(unsigned int a, unsigned int b, float c) {
  union { unsigned int u; f16x2 h; } ua, ub;
  ua.u = a; ub.u = b;
#if __has_builtin(__builtin_amdgcn_fdot2)
  return __builtin_amdgcn_fdot2(ua.h, ub.h, c, false);
#else
  return c + (float)ua.h[0] * (float)ub.h[0] + (float)ua.h[1] * (float)ub.h[1];
#endif
}

// ---------------- node embedding: h = nf @ W_atom + b ----------------
__global__ __launch_bounds__(256) void embed_nodes(const float* __restrict__ nf,
    const float* __restrict__ W, const float* __restrict__ b, float* __restrict__ h) {
  __shared__ float Ws[AF * H];     // 8 KB
  __shared__ float nfs[8][AF];
  int tid = threadIdx.x;
  for (int v = tid; v < AF * H; v += 256) Ws[v] = W[v];
  int n0 = blockIdx.x * 8;
  for (int v = tid; v < 8 * AF; v += 256) {
    int nl = v / AF, k = v % AF;
    int n = n0 + nl;
    nfs[nl][k] = (n < N_NODES) ? nf[n * AF + k] : 0.0f;
  }
  __syncthreads();
  int nl = tid / H, o = tid % H;
  int n = n0 + nl;
  if (n >= N_NODES) return;
  float acc = b[o];
#pragma unroll
  for (int k = 0; k < AF; k++) acc += nfs[nl][k] * Ws[k * H + o];
  h[n * H + o] = acc;
}

// ---------------- histograms over src AND dst ----------------
__global__ void hist2(const int* __restrict__ src, const int* __restrict__ dst,
                      int* __restrict__ hsrc, int* __restrict__ hdst) {
  int e = blockIdx.x * 256 + threadIdx.x;
  if (e < N_EDGES) {
    atomicAdd(&hsrc[src[e]], 1);
    atomicAdd(&hdst[dst[e]], 1);
  }
}

// ---------------- multi-block exclusive scan ----------------
__global__ __launch_bounds__(256) void scan_partial(const int* __restrict__ hist_s,
    const int* __restrict__ hist_d, int* __restrict__ part, int* __restrict__ bsum) {
  __shared__ int wsums[4];
  int which = blockIdx.y;
  const int* __restrict__ hh = which ? hist_d : hist_s;
  int i = blockIdx.x * 256 + threadIdx.x;
  int v = (i < N_NODES) ? hh[i] : 0;
  int lane = threadIdx.x & 63, wid = threadIdx.x >> 6;
  int incl = v;
#pragma unroll
  for (int off = 1; off < 64; off <<= 1) {
    int t = __shfl_up(incl, off, 64);
    if (lane >= off) incl += t;
  }
  if (lane == 63) wsums[wid] = incl;
  __syncthreads();
  int woff = 0;
#pragma unroll
  for (int w = 0; w < 4; w++) if (w < wid) woff += wsums[w];
  part[which * SCP + i] = woff + incl - v;
  if (threadIdx.x == 0)
    bsum[which * SCB + blockIdx.x] = wsums[0] + wsums[1] + wsums[2] + wsums[3];
}

__global__ __launch_bounds__(256) void scan_tops(int* __restrict__ bsum) {
  __shared__ int s[2 * SCB];
  int tid = threadIdx.x;
  if (tid < 2 * SCB) s[tid] = bsum[tid];
  __syncthreads();
  if (tid < 2) {
    int run = 0;
    for (int b = 0; b < SCB; b++) { int t = s[tid * SCB + b]; s[tid * SCB + b] = run; run += t; }
  }
  __syncthreads();
  if (tid < 2 * SCB) bsum[tid] = s[tid];
}

__global__ __launch_bounds__(256) void scan_final(const int* __restrict__ part,
    const int* __restrict__ bsum, const int* __restrict__ hist_d,
    int* __restrict__ cur_s, int* __restrict__ cur_d,
    int* __restrict__ seg_s, int* __restrict__ seg_d, float* __restrict__ inv_deg) {
  int which = blockIdx.y;
  int i = blockIdx.x * 256 + threadIdx.x;
  if (i >= N_NODES) return;
  int ex = part[which * SCP + i] + bsum[which * SCB + blockIdx.x];
  if (which == 0) {
    cur_s[i] = ex; seg_s[i] = ex;
    if (i == 0) seg_s[N_NODES] = N_EDGES;
  } else {
    cur_d[i] = ex; seg_d[i] = ex;
    inv_deg[i] = 1.0f / fmaxf((float)hist_d[i], 1.0f);
    if (i == 0) seg_d[N_NODES] = N_EDGES;
  }
}

// scatter: edge e gets src-sorted slot ps and dst-sorted slot pd.
// pos_s[e]=ps (coalesced) lets edge_r scatter its OUTPUT instead of gathering input.
__global__ void scatter2(const int* __restrict__ src, const int* __restrict__ dst,
    int* __restrict__ cur_s, int* __restrict__ cur_d,
    int* __restrict__ src_s, int* __restrict__ dst_s,
    int* __restrict__ pos_s, int* __restrict__ dpos) {
  int e = blockIdx.x * 256 + threadIdx.x;
  if (e >= N_EDGES) return;
  int s = src[e], d = dst[e];
  int ps = atomicAdd(&cur_s[s], 1);
  int pd = atomicAdd(&cur_d[d], 1);
  src_s[ps] = s;
  dst_s[ps] = d;
  dpos[ps] = pd;
  pos_s[e] = ps;
}

// ---------------- graph segment bounds via binary search (gid is sorted) -----------
__global__ void graph_bounds(const int* __restrict__ gid, int* __restrict__ gstart) {
  int g = threadIdx.x;            // blockDim.x == NB
  int lo = 0, hi = N_NODES;
  while (lo < hi) { int mid = (lo + hi) >> 1; if (gid[mid] < g) lo = mid + 1; else hi = mid; }
  gstart[g] = lo;
  if (g == 0) gstart[NB] = N_NODES;
}

// ---------------- edge hidden: rh = f16-packed relu((ef@Wb+bb)@We1+be1) ------------
// ORIGINAL edge order (coalesced ef reads); result scatter-written to src-sorted
// slot pos_s[e]. rh[ps] = 16 uints; uint jp holds (r[2jp], r[2jp+1]).
__global__ __launch_bounds__(256) void edge_r(const float* __restrict__ ef,
    const float* __restrict__ Wb, const float* __restrict__ bb,
    const float* __restrict__ We1, const float* __restrict__ be1,
    const int* __restrict__ pos_s, unsigned int* __restrict__ rh) {
  __shared__ float Wbs[BF * H];   // 2 KB
  __shared__ float W1s[H * H];    // 4 KB
  __shared__ float efs[32][BF + 1];
  __shared__ float hbs[32][H + 1];
  int tid = threadIdx.x;
  for (int v = tid; v < BF * H; v += 256) Wbs[v] = Wb[v];
  for (int v = tid; v < H * H; v += 256) W1s[v] = We1[v];
  int e0 = blockIdx.x * 32;
  for (int v = tid; v < 32 * BF; v += 256) {
    int el = v >> 4, k = v & 15;
    efs[el][k] = ef[(size_t)(e0 + el) * BF + k];   // coalesced: 2 KB contiguous
  }
  __syncthreads();
  int el = tid >> 3, oq = tid & 7, o0 = oq * 4;
  const float4* Wb4 = (const float4*)Wbs;
  const float4* W14 = (const float4*)W1s;
  float4 hb = ((const float4*)bb)[oq];
#pragma unroll
  for (int kk = 0; kk < BF; kk++) {
    float e_ = efs[el][kk];
    float4 w = Wb4[kk * 8 + oq];
    hb.x += e_ * w.x; hb.y += e_ * w.y; hb.z += e_ * w.z; hb.w += e_ * w.w;
  }
  hbs[el][o0 + 0] = hb.x; hbs[el][o0 + 1] = hb.y;
  hbs[el][o0 + 2] = hb.z; hbs[el][o0 + 3] = hb.w;
  __syncthreads();
  float4 acc = ((const float4*)be1)[oq];
#pragma unroll
  for (int j = 0; j < H; j++) {
    float hj = hbs[el][j];
    float4 w = W14[j * 8 + oq];
    acc.x += hj * w.x; acc.y += hj * w.y; acc.z += hj * w.z; acc.w += hj * w.w;
  }
  acc.x = fmaxf(acc.x, 0.0f); acc.y = fmaxf(acc.y, 0.0f);
  acc.z = fmaxf(acc.z, 0.0f); acc.w = fmaxf(acc.w, 0.0f);
  int ps = pos_s[e0 + el];
  uint2 st;
  st.x = pk2(acc.x, acc.y);     // jp = 2*oq
  st.y = pk2(acc.z, acc.w);     // jp = 2*oq+1
  ((uint2*)(rh + (size_t)ps * 16))[oq] = st;     // scattered 8B write: no latency stall
}

// ---------------- Th[n][jp][o] fp16 pairs over j; hbias fp32 ----------------
// grid (625, 4): one barrier per block; all W slices preloaded.
__global__ __launch_bounds__(256) void compute_T_fused(const float* __restrict__ h,
    const float* __restrict__ We2, const float* __restrict__ be2,
    unsigned int* __restrict__ Th, float* __restrict__ hbias) {
  __shared__ float Wall[9 * H * H];   // 36 KB
  __shared__ float hs[32][H + 1];
  int tid = threadIdx.x;
  int n0 = blockIdx.x * 32;
  int jb = blockIdx.y;
  int nslice = (jb == 3) ? 9 : 8;
  const float4* Wsrc = (const float4*)(We2 + (size_t)jb * 8 * (H * H));
  for (int v = tid; v < 8 * 256; v += 256) ((float4*)Wall)[v] = Wsrc[v];
  if (jb == 3) ((float4*)(Wall + 8 * H * H))[tid] = ((const float4*)be2)[tid];
  for (int v = tid; v < 32 * H; v += 256) {
    int nl = v >> 5, i = v & 31;
    hs[nl][i] = h[(size_t)(n0 + nl) * H + i];
  }
  __syncthreads();
  int nl = tid >> 3, oq = tid & 7;
  float hreg[H];
#pragma unroll
  for (int i = 0; i < H; i++) hreg[i] = hs[nl][i];
  int n = n0 + nl;
  float4 pacc = make_float4(0.f, 0.f, 0.f, 0.f);
  for (int jj = 0; jj < nslice; jj++) {
    const float4* W4 = (const float4*)(Wall + jj * (H * H));
    float4 acc = make_float4(0.f, 0.f, 0.f, 0.f);
#pragma unroll
    for (int i = 0; i < H; i++) {
      float hi = hreg[i];
      float4 w = W4[i * 8 + oq];
      acc.x += hi * w.x; acc.y += hi * w.y; acc.z += hi * w.z; acc.w += hi * w.w;
    }
    int j = jb * 8 + jj;
    if (j < H) {
      if (jj & 1) {                       // j parity == jj parity (jb*8 even)
        uint4 st;
        st.x = pk2(pacc.x, acc.x);
        st.y = pk2(pacc.y, acc.y);
        st.z = pk2(pacc.z, acc.z);
        st.w = pk2(pacc.w, acc.w);
        ((uint4*)(Th + (size_t)n * 512 + (j >> 1) * 32))[oq] = st;
      } else {
        pacc = acc;
      }
    } else {
      ((float4*)(hbias + (size_t)n * H))[oq] = acc;
    }
  }
}

// ---------------- msg: block = 8 src-segments, fp16 T in LDS, dot2 inner loop ------
// Output msg packed fp16 (uint2 per lane). Wave-uniform segment -> conflict-free LDS.
__global__ __launch_bounds__(256) void edge_msg_seg(const unsigned int* __restrict__ rh,
    const unsigned int* __restrict__ Th, const float* __restrict__ hbias,
    const int* __restrict__ seg_s, const int* __restrict__ dpos,
    unsigned int* __restrict__ msg_h) {
  __shared__ unsigned int Ts[8 * 512];  // 16 KB
  __shared__ float hb[8 * H];           // 1 KB
  __shared__ int sseg[9];
  int tid = threadIdx.x;
  int n0 = blockIdx.x * 8;              // 2500 * 8 == 20000
  const uint4* Tg = (const uint4*)(Th + (size_t)n0 * 512);
#pragma unroll
  for (int v = 0; v < 4; v++) ((uint4*)Ts)[tid + v * 256] = Tg[tid + v * 256];
  hb[tid] = hbias[(size_t)n0 * H + tid];
  if (tid < 9) sseg[tid] = seg_s[n0 + tid];
  __syncthreads();
  int lane = tid & 63, wid = tid >> 6;
  int el = lane >> 3, t = lane & 7;
  for (int s = 0; s < 8; s++) {
    int a = sseg[s], bnd = sseg[s + 1];
    const unsigned int* Trow = Ts + s * 512;
    float4 hbv = ((const float4*)(hb + s * H))[t];
    int ww = (wid + s) & 3;             // rotate wave->chunk mapping per segment
    for (int base = a + ww * 8; base < bnd; base += 32) {
      int e = base + el;
      bool valid = (e < bnd);
      int pd = 0;
      uint2 ru2 = make_uint2(0u, 0u);
      if (valid) {
        pd = dpos[e];
        ru2 = ((const uint2*)(rh + (size_t)e * 16))[t];
      }
      float4 acc = hbv;
#pragma unroll
      for (int jp = 0; jp < 16; jp++) {
        unsigned int mine = (jp & 1) ? ru2.y : ru2.x;
        unsigned int rj = (unsigned int)__shfl((int)mine, jp >> 1, 8);
        uint4 tw = ((const uint4*)(Trow + jp * 32))[t];
        acc.x = dot2(rj, tw.x, acc.x);
        acc.y = dot2(rj, tw.y, acc.y);
        acc.z = dot2(rj, tw.z, acc.z);
        acc.w = dot2(rj, tw.w, acc.w);
      }
      if (valid) {
        uint2 st;
        st.x = pk2(acc.x, acc.y);
        st.y = pk2(acc.z, acc.w);
        ((uint2*)(msg_h + (size_t)pd * 16))[t] = st;
      }
    }
  }
}

// ---------------- fallback: atomic scatter-add (if workspace too small) ------------
__global__ __launch_bounds__(256) void edge_msg_atomic(const unsigned int* __restrict__ rh,
    const unsigned int* __restrict__ Th, const float* __restrict__ hbias,
    const int* __restrict__ src_s, const int* __restrict__ dst_s,
    float* __restrict__ agg) {
  int tid = threadIdx.x;
  int e0 = blockIdx.x * 32;
  int el = tid >> 3, t = tid & 7;
  int e = e0 + el;
  int s = src_s[e], d = dst_s[e];
  uint2 ru2 = ((const uint2*)(rh + (size_t)e * 16))[t];
  float4 acc = ((const float4*)(hbias + (size_t)s * H))[t];
  const unsigned int* Trow = Th + (size_t)s * 512;
#pragma unroll
  for (int jp = 0; jp < 16; jp++) {
    unsigned int mine = (jp & 1) ? ru2.y : ru2.x;
    unsigned int rj = (unsigned int)__shfl((int)mine, jp >> 1, 8);
    uint4 tw = ((const uint4*)(Trow + jp * 32))[t];
    acc.x = dot2(rj, tw.x, acc.x);
    acc.y = dot2(rj, tw.y, acc.y);
    acc.z = dot2(rj, tw.z, acc.z);
    acc.w = dot2(rj, tw.w, acc.w);
  }
  float* ap = agg + (size_t)d * H + t * 4;
  atomicAdd(ap + 0, acc.x);
  atomicAdd(ap + 1, acc.y);
  atomicAdd(ap + 2, acc.z);
  atomicAdd(ap + 3, acc.w);
}

// ---------------- fused segment-reduce + mean + relu + GRU, 8 nodes/block ----------
// msg rows are fp16-packed (16 uints): lane o reads uint o>>1, extracts half o&1.
__global__ __launch_bounds__(256) void seg_gru(const unsigned int* __restrict__ msg_h,
    const int* __restrict__ seg_d, const float* __restrict__ invdeg,
    const float* __restrict__ Wih, const float* __restrict__ Whh,
    const float* __restrict__ bih, const float* __restrict__ bhh,
    float* __restrict__ h) {
  __shared__ float Wis[3 * H][H + 1];   // 12.4 KB
  __shared__ float Whs[3 * H][H + 1];   // 12.4 KB
  __shared__ float xs[8][H + 1];
  __shared__ float hsm[8][H + 1];
  int tid = threadIdx.x;
  for (int v = tid; v < 3 * H * H; v += 256) {
    int k = v / H, i = v % H;
    Wis[k][i] = Wih[v];
    Whs[k][i] = Whh[v];
  }
  int node = tid >> 5, o = tid & 31;
  int n = blockIdx.x * 8 + node;        // 2500*8 == 20000 exactly
  int a = seg_d[n], bseg = seg_d[n + 1];
  int hi = o & 1;
  const unsigned int* mp = msg_h + (size_t)a * 16 + (o >> 1);
  float s0 = 0.f, s1 = 0.f, s2 = 0.f, s3 = 0.f;
  int p = a;
  for (; p + 4 <= bseg; p += 4) {
    unsigned int u0 = mp[0], u1 = mp[16], u2 = mp[32], u3 = mp[48];
    mp += 64;
    s0 += uph(u0, hi); s1 += uph(u1, hi); s2 += uph(u2, hi); s3 += uph(u3, hi);
  }
  for (; p < bseg; p++) { s0 += uph(mp[0], hi); mp += 16; }
  float s = (s0 + s1) + (s2 + s3);
  xs[node][o] = fmaxf(s * invdeg[n], 0.0f);
  float hval = h[(size_t)n * H + o];
  hsm[node][o] = hval;
  __syncthreads();
  float gi0 = bih[o], gi1 = bih[H + o], gi2 = bih[2 * H + o];
  float gh0 = bhh[o], gh1 = bhh[H + o], gh2 = bhh[2 * H + o];
#pragma unroll
  for (int i = 0; i < H; i++) {
    float xi = xs[node][i], hi_ = hsm[node][i];
    gi0 += xi * Wis[o][i];
    gh0 += hi_ * Whs[o][i];
    gi1 += xi * Wis[H + o][i];
    gh1 += hi_ * Whs[H + o][i];
    gi2 += xi * Wis[2 * H + o][i];
    gh2 += hi_ * Whs[2 * H + o][i];
  }
  float rg = fast_sigmoid(gi0 + gh0);
  float zg = fast_sigmoid(gi1 + gh1);
  float ng = fast_tanh(gi2 + rg * gh2);
  h[(size_t)n * H + o] = (1.0f - zg) * ng + zg * hval;
}

// ---------------- fallback GRU reading agg (8 nodes/block) ----------------
__global__ __launch_bounds__(256) void gru_update(const float* __restrict__ agg,
    const float* __restrict__ invdeg, const float* __restrict__ Wih,
    const float* __restrict__ Whh, const float* __restrict__ bih,
    const float* __restrict__ bhh, float* __restrict__ h) {
  __shared__ float Wis[3 * H][H + 1];
  __shared__ float Whs[3 * H][H + 1];
  __shared__ float xs[8][H + 1];
  __shared__ float hsm[8][H + 1];
  int tid = threadIdx.x;
  for (int v = tid; v < 3 * H * H; v += 256) {
    int k = v / H, i = v % H;
    Wis[k][i] = Wih[v];
    Whs[k][i] = Whh[v];
  }
  int node = tid >> 5, o = tid & 31;
  int n = blockIdx.x * 8 + node;
  xs[node][o] = fmaxf(agg[(size_t)n * H + o] * invdeg[n], 0.0f);
  float hval = h[(size_t)n * H + o];
  hsm[node][o] = hval;
  __syncthreads();
  float gi0 = bih[o], gi1 = bih[H + o], gi2 = bih[2 * H + o];
  float gh0 = bhh[o], gh1 = bhh[H + o], gh2 = bhh[2 * H + o];
#pragma unroll
  for (int i = 0; i < H; i++) {
    float xi = xs[node][i], hi_ = hsm[node][i];
    gi0 += xi * Wis[o][i];
    gh0 += hi_ * Whs[o][i];
    gi1 += xi * Wis[H + o][i];
    gh1 += hi_ * Whs[H + o][i];
    gi2 += xi * Wis[2 * H + o][i];
    gh2 += hi_ * Whs[2 * H + o][i];
  }
  float rg = fast_sigmoid(gi0 + gh0);
  float zg = fast_sigmoid(gi1 + gh1);
  float ng = fast_tanh(gi2 + rg * gh2);
  h[(size_t)n * H + o] = (1.0f - zg) * ng + zg * hval;
}

// ---------------- graph mean readout: segmented (gid sorted), no atomics -----------
__global__ __launch_bounds__(256) void readout_graph(const float* __restrict__ h,
    const int* __restrict__ gstart, float* __restrict__ out) {
  __shared__ float red[8][H + 1];
  int g = blockIdx.x;
  int a = gstart[g], b = gstart[g + 1];
  int r = threadIdx.x >> 5, o = threadIdx.x & 31;
  float s = 0.0f;
  for (int n = a + r; n < b; n += 8) s += h[(size_t)n * H + o];
  red[r][o] = s;
  __syncthreads();
  if (r == 0) {
    float t = 0.0f;
#pragma unroll
    for (int k = 0; k < 8; k++) t += red[k][o];
    out[g * H + o] = t / fmaxf((float)(b - a), 1.0f);
  }
}

extern "C" void kernel_launch(void* const* d_in, const int* in_sizes, int n_in,
                              void* d_out, int out_size, void* d_ws, size_t ws_size,
                              hipStream_t stream) {
  const float* n_feat = (const float*)d_in[0];
  const float* e_feat = (const float*)d_in[1];
  const int*   src    = (const int*)d_in[2];
  const int*   dst    = (const int*)d_in[3];
  const int*   gid    = (const int*)d_in[4];
  const float* W_atom = (const float*)d_in[5];
  const float* b_atom = (const float*)d_in[6];
  const float* W_bond = (const float*)d_in[7];
  const float* b_bond = (const float*)d_in[8];
  const float* W_e1   = (const float*)d_in[9];
  const float* b_e1   = (const float*)d_in[10];
  const float* W_e2   = (const float*)d_in[11];
  const float* b_e2   = (const float*)d_in[12];
  const float* W_ih   = (const float*)d_in[13];
  const float* W_hh   = (const float*)d_in[14];
  const float* b_ih   = (const float*)d_in[15];
  const float* b_hh   = (const float*)d_in[16];
  float* out = (float*)d_out;

  // workspace carve-up
  char* ws = (char*)d_ws;
  size_t off = 0;
  float*        h      = (float*)(ws + off); off += (size_t)N_NODES * H * 4;     // 2.56 MB
  unsigned int* rh     = (unsigned int*)(ws + off); off += (size_t)N_EDGES * 16 * 4;  // 20.48 MB
  unsigned int* Th     = (unsigned int*)(ws + off); off += (size_t)N_NODES * 512 * 4; // 40.96 MB
  float*        hbias  = (float*)(ws + off); off += (size_t)N_NODES * H * 4;     // 2.56 MB
  int*   hist_s = (int*)(ws + off);   off += (size_t)N_NODES * 4;
  int*   hist_d = (int*)(ws + off);   off += (size_t)N_NODES * 4;
  int*   cur_s  = (int*)(ws + off);   off += (size_t)N_NODES * 4;
  int*   cur_d  = (int*)(ws + off);   off += (size_t)N_NODES * 4;
  int*   seg_s  = (int*)(ws + off);   off += (size_t)(N_NODES + 1) * 4;
  int*   seg_d  = (int*)(ws + off);   off += (size_t)(N_NODES + 1) * 4;
  float* invdeg = (float*)(ws + off); off += (size_t)N_NODES * 4;
  int*   part   = (int*)(ws + off);   off += (size_t)2 * SCP * 4;                // 162 KB
  int*   bsum   = (int*)(ws + off);   off += (size_t)2 * SCB * 4;
  int*   src_s  = (int*)(ws + off);   off += (size_t)N_EDGES * 4;                // 1.28 MB
  int*   dst_s  = (int*)(ws + off);   off += (size_t)N_EDGES * 4;                // 1.28 MB
  int*   dpos   = (int*)(ws + off);   off += (size_t)N_EDGES * 4;                // 1.28 MB
  int*   gstart = (int*)(ws + off);   off += (size_t)(NB + 1) * 4;
  float* agg    = (float*)(ws + off); off += (size_t)N_NODES * H * 4;            // 2.56 MB (fallback)
  unsigned int* msg_h = (unsigned int*)(ws + off); off += (size_t)N_EDGES * 16 * 4;   // 20.48 MB
  int use_msg = (ws_size >= off) ? 1 : 0;
  int* pos_s = (int*)Th;   // alias: pos_s only live before first compute_T

  // node embedding
  embed_nodes<<<N_NODES / 8, 256, 0, stream>>>(n_feat, W_atom, b_atom, h);

  // dual counting sort prep: histograms -> multi-block scans -> scatter
  hipMemsetAsync(hist_s, 0, (size_t)2 * N_NODES * 4, stream);  // hist_s+hist_d adjacent
  hist2<<<(N_EDGES + 255) / 256, 256, 0, stream>>>(src, dst, hist_s, hist_d);
  {
    dim3 gs(SCB, 2);
    scan_partial<<<gs, 256, 0, stream>>>(hist_s, hist_d, part, bsum);
    scan_tops<<<1, 256, 0, stream>>>(bsum);
    scan_final<<<gs, 256, 0, stream>>>(part, bsum, hist_d, cur_s, cur_d,
                                       seg_s, seg_d, invdeg);
  }
  scatter2<<<(N_EDGES + 255) / 256, 256, 0, stream>>>(src, dst, cur_s, cur_d,
                                                      src_s, dst_s, pos_s, dpos);
  graph_bounds<<<1, NB, 0, stream>>>(gid, gstart);

  // edge-net first layer, original order in / src-sorted scatter out (layer-invariant)
  edge_r<<<N_EDGES / 32, 256, 0, stream>>>(e_feat, W_bond, b_bond, W_e1, b_e1,
                                           pos_s, rh);

  for (int layer = 0; layer < 2; layer++) {
    dim3 gT(N_NODES / 32, 4);
    compute_T_fused<<<gT, 256, 0, stream>>>(h, W_e2, b_e2, Th, hbias);
    if (use_msg) {
      edge_msg_seg<<<N_NODES / 8, 256, 0, stream>>>(rh, Th, hbias, seg_s,
                                                    dpos, msg_h);
      seg_gru<<<N_NODES / 8, 256, 0, stream>>>(msg_h, seg_d, invdeg,
                                               W_ih, W_hh, b_ih, b_hh, h);
    } else {
      hipMemsetAsync(agg, 0, (size_t)N_NODES * H * 4, stream);
      edge_msg_atomic<<<N_EDGES / 32, 256, 0, stream>>>(rh, Th, hbias, src_s, dst_s,
                                                        agg);
      gru_update<<<N_NODES / 8, 256, 0, stream>>>(agg, invdeg,
                                                  W_ih, W_hh, b_ih, b_hh, h);
    }
  }

  // graph mean readout (segmented, atomic-free)
  readout_graph<<<NB, 256, 0, stream>>>(h, gstart, out);
}

// Round 11
// 371.301 us; speedup vs baseline: 2.5084x; 1.0477x over previous
//
#include <hip/hip_runtime.h>
#include <hip/hip_fp16.h>
#include <math.h>

#define N_NODES 20000
#define N_EDGES 320000
#define NB 128
#define H 32
#define AF 64
#define BF 16
#define SCB 79           // scan blocks: ceil(20000/256)
#define SCP 20224        // padded per-pass partial size (79*256)

typedef _Float16 f16x2 __attribute__((ext_vector_type(2)));

__device__ __forceinline__ float fast_sigmoid(float x) {
  return 1.0f / (1.0f + __expf(-x));
}
__device__ __forceinline__ float fast_tanh(float x) {
  float e2 = __expf(2.0f * x);
  return 1.0f - 2.0f / (e2 + 1.0f);    // inf-safe
}
// pack two floats as fp16 pair (RNE cast, low = a)
__device__ __forceinline__ unsigned int pk2(float a, float b) {
  union { f16x2 h; unsigned int u; } p;
  p.h[0] = (_Float16)a;
  p.h[1] = (_Float16)b;
  return p.u;
}
// extract half 0/1 of an fp16 pair as float
__device__ __forceinline__ float uph(unsigned int u, int hi) {
  union { unsigned int u; f16x2 h; } x; x.u = u;
  return hi ? (float)x.h[1] : (float)x.h[0];
}
// fp16x2 dot with fp32 accumulate: c + a.x*b.x + a.y*b.y
__device__ __forceinline__ float dot2(unsigned int a, unsigned int b, float c) {
  union { unsigned int u; f16x2 h; } ua, ub;
  ua.u = a; ub.u = b;
#if __has_builtin(__builtin_amdgcn_fdot2)
  return __builtin_amdgcn_fdot2(ua.h, ub.h, c, false);
#else
  return c + (float)ua.h[0] * (float)ub.h[0] + (float)ua.h[1] * (float)ub.h[1];
#endif
}

// ---------------- node embedding: h = nf @ W_atom + b ----------------
__global__ __launch_bounds__(256) void embed_nodes(const float* __restrict__ nf,
    const float* __restrict__ W, const float* __restrict__ b, float* __restrict__ h) {
  __shared__ float Ws[AF * H];     // 8 KB
  __shared__ float nfs[8][AF];
  int tid = threadIdx.x;
  for (int v = tid; v < AF * H; v += 256) Ws[v] = W[v];
  int n0 = blockIdx.x * 8;
  for (int v = tid; v < 8 * AF; v += 256) {
    int nl = v / AF, k = v % AF;
    int n = n0 + nl;
    nfs[nl][k] = (n < N_NODES) ? nf[n * AF + k] : 0.0f;
  }
  __syncthreads();
  int nl = tid / H, o = tid % H;
  int n = n0 + nl;
  if (n >= N_NODES) return;
  float acc = b[o];
#pragma unroll
  for (int k = 0; k < AF; k++) acc += nfs[nl][k] * Ws[k * H + o];
  h[n * H + o] = acc;
}

// ---------------- histograms over src AND dst ----------------
__global__ void hist2(const int* __restrict__ src, const int* __restrict__ dst,
                      int* __restrict__ hsrc, int* __restrict__ hdst) {
  int e = blockIdx.x * 256 + threadIdx.x;
  if (e < N_EDGES) {
    atomicAdd(&hsrc[src[e]], 1);
    atomicAdd(&hdst[dst[e]], 1);
  }
}

// ---------------- multi-block exclusive scan ----------------
__global__ __launch_bounds__(256) void scan_partial(const int* __restrict__ hist_s,
    const int* __restrict__ hist_d, int* __restrict__ part, int* __restrict__ bsum) {
  __shared__ int wsums[4];
  int which = blockIdx.y;
  const int* __restrict__ hh = which ? hist_d : hist_s;
  int i = blockIdx.x * 256 + threadIdx.x;
  int v = (i < N_NODES) ? hh[i] : 0;
  int lane = threadIdx.x & 63, wid = threadIdx.x >> 6;
  int incl = v;
#pragma unroll
  for (int off = 1; off < 64; off <<= 1) {
    int t = __shfl_up(incl, off, 64);
    if (lane >= off) incl += t;
  }
  if (lane == 63) wsums[wid] = incl;
  __syncthreads();
  int woff = 0;
#pragma unroll
  for (int w = 0; w < 4; w++) if (w < wid) woff += wsums[w];
  part[which * SCP + i] = woff + incl - v;
  if (threadIdx.x == 0)
    bsum[which * SCB + blockIdx.x] = wsums[0] + wsums[1] + wsums[2] + wsums[3];
}

// tops scan + graph segment bounds (gid sorted) fused in one tiny block
__global__ __launch_bounds__(256) void scan_tops(int* __restrict__ bsum,
    const int* __restrict__ gid, int* __restrict__ gstart) {
  __shared__ int s[2 * SCB];
  int tid = threadIdx.x;
  if (tid < 2 * SCB) s[tid] = bsum[tid];
  if (tid < NB) {
    int g = tid;
    int lo = 0, hi = N_NODES;
    while (lo < hi) { int mid = (lo + hi) >> 1; if (gid[mid] < g) lo = mid + 1; else hi = mid; }
    gstart[g] = lo;
    if (g == 0) gstart[NB] = N_NODES;
  }
  __syncthreads();
  if (tid < 2) {
    int run = 0;
    for (int b = 0; b < SCB; b++) { int t = s[tid * SCB + b]; s[tid * SCB + b] = run; run += t; }
  }
  __syncthreads();
  if (tid < 2 * SCB) bsum[tid] = s[tid];
}

__global__ __launch_bounds__(256) void scan_final(const int* __restrict__ part,
    const int* __restrict__ bsum, const int* __restrict__ hist_d,
    int* __restrict__ cur_s, int* __restrict__ cur_d,
    int* __restrict__ seg_s, int* __restrict__ seg_d, float* __restrict__ inv_deg) {
  int which = blockIdx.y;
  int i = blockIdx.x * 256 + threadIdx.x;
  if (i >= N_NODES) return;
  int ex = part[which * SCP + i] + bsum[which * SCB + blockIdx.x];
  if (which == 0) {
    cur_s[i] = ex; seg_s[i] = ex;
    if (i == 0) seg_s[N_NODES] = N_EDGES;
  } else {
    cur_d[i] = ex; seg_d[i] = ex;
    inv_deg[i] = 1.0f / fmaxf((float)hist_d[i], 1.0f);
    if (i == 0) seg_d[N_NODES] = N_EDGES;
  }
}

// scatter (fast path): only dpos[ps] (scattered) + pos_s[e] (coalesced).
__global__ void scatter2_fast(const int* __restrict__ src, const int* __restrict__ dst,
    int* __restrict__ cur_s, int* __restrict__ cur_d,
    int* __restrict__ pos_s, int* __restrict__ dpos) {
  int e = blockIdx.x * 256 + threadIdx.x;
  if (e >= N_EDGES) return;
  int s = src[e], d = dst[e];
  int ps = atomicAdd(&cur_s[s], 1);
  int pd = atomicAdd(&cur_d[d], 1);
  dpos[ps] = pd;
  pos_s[e] = ps;
}

// scatter (fallback path): also materialize src_s/dst_s for the atomic kernel.
__global__ void scatter2_full(const int* __restrict__ src, const int* __restrict__ dst,
    int* __restrict__ cur_s, int* __restrict__ cur_d,
    int* __restrict__ src_s, int* __restrict__ dst_s,
    int* __restrict__ pos_s, int* __restrict__ dpos) {
  int e = blockIdx.x * 256 + threadIdx.x;
  if (e >= N_EDGES) return;
  int s = src[e], d = dst[e];
  int ps = atomicAdd(&cur_s[s], 1);
  int pd = atomicAdd(&cur_d[d], 1);
  src_s[ps] = s;
  dst_s[ps] = d;
  dpos[ps] = pd;
  pos_s[e] = ps;
}

// ---------------- edge hidden: rh = f16-packed relu((ef@Wb+bb)@We1+be1) ------------
// Original edge order in (coalesced), scatter-write to src-sorted slot pos_s[e].
// Phase 2 runs in packed fp16 (dot2): halves LDS ops vs fp32 (R10 was LDS-bound).
__global__ __launch_bounds__(256) void edge_r(const float* __restrict__ ef,
    const float* __restrict__ Wb, const float* __restrict__ bb,
    const float* __restrict__ We1, const float* __restrict__ be1,
    const int* __restrict__ pos_s, unsigned int* __restrict__ rh) {
  __shared__ float Wbs[BF * H];           // 2 KB [k][o]
  __shared__ unsigned int W1p[16 * H];    // 2 KB [jp][o], fp16 pair over j
  __shared__ float efs[32 * 20];          // row stride 20: bank-rotated
  __shared__ unsigned int hbp[32 * 20];   // row stride 20: bank-rotated
  int tid = threadIdx.x;
  for (int v = tid; v < BF * H; v += 256) Wbs[v] = Wb[v];
  for (int v = tid; v < 16 * H; v += 256) {
    int jp = v >> 5, o = v & 31;
    W1p[v] = pk2(We1[(2 * jp) * H + o], We1[(2 * jp + 1) * H + o]);
  }
  int e0 = blockIdx.x * 32;
  if (tid < 128) {        // 32 edges x 16 floats = 128 float4, coalesced
    float4 d = ((const float4*)(ef + (size_t)e0 * BF))[tid];
    ((float4*)(efs + (tid >> 2) * 20))[tid & 3] = d;
  }
  __syncthreads();
  int el = tid >> 3, oq = tid & 7;
  const float4* Wb4 = (const float4*)Wbs;
  const float4* efv = (const float4*)(efs + el * 20);
  float4 hb = ((const float4*)bb)[oq];
#pragma unroll
  for (int kq = 0; kq < 4; kq++) {
    float4 e4 = efv[kq];
    float4 w;
    w = Wb4[(kq * 4 + 0) * 8 + oq];
    hb.x += e4.x * w.x; hb.y += e4.x * w.y; hb.z += e4.x * w.z; hb.w += e4.x * w.w;
    w = Wb4[(kq * 4 + 1) * 8 + oq];
    hb.x += e4.y * w.x; hb.y += e4.y * w.y; hb.z += e4.y * w.z; hb.w += e4.y * w.w;
    w = Wb4[(kq * 4 + 2) * 8 + oq];
    hb.x += e4.z * w.x; hb.y += e4.z * w.y; hb.z += e4.z * w.z; hb.w += e4.z * w.w;
    w = Wb4[(kq * 4 + 3) * 8 + oq];
    hb.x += e4.w * w.x; hb.y += e4.w * w.y; hb.z += e4.w * w.z; hb.w += e4.w * w.w;
  }
  // thread owns hidden units j = 4oq..4oq+3 -> fp16 pairs jp = 2oq, 2oq+1
  ((uint2*)(hbp + el * 20))[oq] = make_uint2(pk2(hb.x, hb.y), pk2(hb.z, hb.w));
  __syncthreads();
  float4 acc = ((const float4*)be1)[oq];
  const uint4* hb4 = (const uint4*)(hbp + el * 20);
#pragma unroll
  for (int q = 0; q < 4; q++) {
    uint4 hp = hb4[q];                     // jp = 4q..4q+3, 8-lane broadcast
    uint4 w;
    w = ((const uint4*)(W1p + (4 * q + 0) * H))[oq];
    acc.x = dot2(hp.x, w.x, acc.x); acc.y = dot2(hp.x, w.y, acc.y);
    acc.z = dot2(hp.x, w.z, acc.z); acc.w = dot2(hp.x, w.w, acc.w);
    w = ((const uint4*)(W1p + (4 * q + 1) * H))[oq];
    acc.x = dot2(hp.y, w.x, acc.x); acc.y = dot2(hp.y, w.y, acc.y);
    acc.z = dot2(hp.y, w.z, acc.z); acc.w = dot2(hp.y, w.w, acc.w);
    w = ((const uint4*)(W1p + (4 * q + 2) * H))[oq];
    acc.x = dot2(hp.z, w.x, acc.x); acc.y = dot2(hp.z, w.y, acc.y);
    acc.z = dot2(hp.z, w.z, acc.z); acc.w = dot2(hp.z, w.w, acc.w);
    w = ((const uint4*)(W1p + (4 * q + 3) * H))[oq];
    acc.x = dot2(hp.w, w.x, acc.x); acc.y = dot2(hp.w, w.y, acc.y);
    acc.z = dot2(hp.w, w.z, acc.z); acc.w = dot2(hp.w, w.w, acc.w);
  }
  acc.x = fmaxf(acc.x, 0.0f); acc.y = fmaxf(acc.y, 0.0f);
  acc.z = fmaxf(acc.z, 0.0f); acc.w = fmaxf(acc.w, 0.0f);
  int ps = pos_s[e0 + el];
  uint2 st;
  st.x = pk2(acc.x, acc.y);     // jp = 2*oq
  st.y = pk2(acc.z, acc.w);     // jp = 2*oq+1
  ((uint2*)(rh + (size_t)ps * 16))[oq] = st;   // scattered 8B write: no latency stall
}

// ---------------- Th[n][jp][o] fp16 pairs over j; hbias fp32 ----------------
// grid (625, 4): one barrier per block; all W slices preloaded.
__global__ __launch_bounds__(256) void compute_T_fused(const float* __restrict__ h,
    const float* __restrict__ We2, const float* __restrict__ be2,
    unsigned int* __restrict__ Th, float* __restrict__ hbias) {
  __shared__ float Wall[9 * H * H];   // 36 KB
  __shared__ float hs[32][H + 1];
  int tid = threadIdx.x;
  int n0 = blockIdx.x * 32;
  int jb = blockIdx.y;
  int nslice = (jb == 3) ? 9 : 8;
  const float4* Wsrc = (const float4*)(We2 + (size_t)jb * 8 * (H * H));
  for (int v = tid; v < 8 * 256; v += 256) ((float4*)Wall)[v] = Wsrc[v];
  if (jb == 3) ((float4*)(Wall + 8 * H * H))[tid] = ((const float4*)be2)[tid];
  for (int v = tid; v < 32 * H; v += 256) {
    int nl = v >> 5, i = v & 31;
    hs[nl][i] = h[(size_t)(n0 + nl) * H + i];
  }
  __syncthreads();
  int nl = tid >> 3, oq = tid & 7;
  float hreg[H];
#pragma unroll
  for (int i = 0; i < H; i++) hreg[i] = hs[nl][i];
  int n = n0 + nl;
  float4 pacc = make_float4(0.f, 0.f, 0.f, 0.f);
  for (int jj = 0; jj < nslice; jj++) {
    const float4* W4 = (const float4*)(Wall + jj * (H * H));
    float4 acc = make_float4(0.f, 0.f, 0.f, 0.f);
#pragma unroll
    for (int i = 0; i < H; i++) {
      float hi = hreg[i];
      float4 w = W4[i * 8 + oq];
      acc.x += hi * w.x; acc.y += hi * w.y; acc.z += hi * w.z; acc.w += hi * w.w;
    }
    int j = jb * 8 + jj;
    if (j < H) {
      if (jj & 1) {                       // j parity == jj parity (jb*8 even)
        uint4 st;
        st.x = pk2(pacc.x, acc.x);
        st.y = pk2(pacc.y, acc.y);
        st.z = pk2(pacc.z, acc.z);
        st.w = pk2(pacc.w, acc.w);
        ((uint4*)(Th + (size_t)n * 512 + (j >> 1) * 32))[oq] = st;
      } else {
        pacc = acc;
      }
    } else {
      ((float4*)(hbias + (size_t)n * H))[oq] = acc;
    }
  }
}

// ---------------- msg: block = 8 src-segments, fp16 T in LDS, dot2 inner loop ------
// Output msg packed fp16 (uint2 per lane). Wave-uniform segment -> conflict-free LDS.
__global__ __launch_bounds__(256) void edge_msg_seg(const unsigned int* __restrict__ rh,
    const unsigned int* __restrict__ Th, const float* __restrict__ hbias,
    const int* __restrict__ seg_s, const int* __restrict__ dpos,
    unsigned int* __restrict__ msg_h) {
  __shared__ unsigned int Ts[8 * 512];  // 16 KB
  __shared__ float hb[8 * H];           // 1 KB
  __shared__ int sseg[9];
  int tid = threadIdx.x;
  int n0 = blockIdx.x * 8;              // 2500 * 8 == 20000
  const uint4* Tg = (const uint4*)(Th + (size_t)n0 * 512);
#pragma unroll
  for (int v = 0; v < 4; v++) ((uint4*)Ts)[tid + v * 256] = Tg[tid + v * 256];
  hb[tid] = hbias[(size_t)n0 * H + tid];
  if (tid < 9) sseg[tid] = seg_s[n0 + tid];
  __syncthreads();
  int lane = tid & 63, wid = tid >> 6;
  int el = lane >> 3, t = lane & 7;
  for (int s = 0; s < 8; s++) {
    int a = sseg[s], bnd = sseg[s + 1];
    const unsigned int* Trow = Ts + s * 512;
    float4 hbv = ((const float4*)(hb + s * H))[t];
    int ww = (wid + s) & 3;             // rotate wave->chunk mapping per segment
    for (int base = a + ww * 8; base < bnd; base += 32) {
      int e = base + el;
      bool valid = (e < bnd);
      int pd = 0;
      uint2 ru2 = make_uint2(0u, 0u);
      if (valid) {
        pd = dpos[e];
        ru2 = ((const uint2*)(rh + (size_t)e * 16))[t];
      }
      float4 acc = hbv;
#pragma unroll
      for (int jp = 0; jp < 16; jp++) {
        unsigned int mine = (jp & 1) ? ru2.y : ru2.x;
        unsigned int rj = (unsigned int)__shfl((int)mine, jp >> 1, 8);
        uint4 tw = ((const uint4*)(Trow + jp * 32))[t];
        acc.x = dot2(rj, tw.x, acc.x);
        acc.y = dot2(rj, tw.y, acc.y);
        acc.z = dot2(rj, tw.z, acc.z);
        acc.w = dot2(rj, tw.w, acc.w);
      }
      if (valid) {
        uint2 st;
        st.x = pk2(acc.x, acc.y);
        st.y = pk2(acc.z, acc.w);
        ((uint2*)(msg_h + (size_t)pd * 16))[t] = st;
      }
    }
  }
}

// ---------------- fallback: atomic scatter-add (if workspace too small) ------------
__global__ __launch_bounds__(256) void edge_msg_atomic(const unsigned int* __restrict__ rh,
    const unsigned int* __restrict__ Th, const float* __restrict__ hbias,
    const int* __restrict__ src_s, const int* __restrict__ dst_s,
    float* __restrict__ agg) {
  int tid = threadIdx.x;
  int e0 = blockIdx.x * 32;
  int el = tid >> 3, t = tid & 7;
  int e = e0 + el;
  int s = src_s[e], d = dst_s[e];
  uint2 ru2 = ((const uint2*)(rh + (size_t)e * 16))[t];
  float4 acc = ((const float4*)(hbias + (size_t)s * H))[t];
  const unsigned int* Trow = Th + (size_t)s * 512;
#pragma unroll
  for (int jp = 0; jp < 16; jp++) {
    unsigned int mine = (jp & 1) ? ru2.y : ru2.x;
    unsigned int rj = (unsigned int)__shfl((int)mine, jp >> 1, 8);
    uint4 tw = ((const uint4*)(Trow + jp * 32))[t];
    acc.x = dot2(rj, tw.x, acc.x);
    acc.y = dot2(rj, tw.y, acc.y);
    acc.z = dot2(rj, tw.z, acc.z);
    acc.w = dot2(rj, tw.w, acc.w);
  }
  float* ap = agg + (size_t)d * H + t * 4;
  atomicAdd(ap + 0, acc.x);
  atomicAdd(ap + 1, acc.y);
  atomicAdd(ap + 2, acc.z);
  atomicAdd(ap + 3, acc.w);
}

// ---------------- fused segment-reduce + mean + relu + GRU, 8 nodes/block ----------
// msg rows are fp16-packed (16 uints): lane o reads uint o>>1, extracts half o&1.
__global__ __launch_bounds__(256) void seg_gru(const unsigned int* __restrict__ msg_h,
    const int* __restrict__ seg_d, const float* __restrict__ invdeg,
    const float* __restrict__ Wih, const float* __restrict__ Whh,
    const float* __restrict__ bih, const float* __restrict__ bhh,
    float* __restrict__ h) {
  __shared__ float Wis[3 * H][H + 1];   // 12.4 KB
  __shared__ float Whs[3 * H][H + 1];   // 12.4 KB
  __shared__ float xs[8][H + 1];
  __shared__ float hsm[8][H + 1];
  int tid = threadIdx.x;
  for (int v = tid; v < 3 * H * H; v += 256) {
    int k = v / H, i = v % H;
    Wis[k][i] = Wih[v];
    Whs[k][i] = Whh[v];
  }
  int node = tid >> 5, o = tid & 31;
  int n = blockIdx.x * 8 + node;        // 2500*8 == 20000 exactly
  int a = seg_d[n], bseg = seg_d[n + 1];
  int hi = o & 1;
  const unsigned int* mp = msg_h + (size_t)a * 16 + (o >> 1);
  float s0 = 0.f, s1 = 0.f, s2 = 0.f, s3 = 0.f;
  int p = a;
  for (; p + 4 <= bseg; p += 4) {
    unsigned int u0 = mp[0], u1 = mp[16], u2 = mp[32], u3 = mp[48];
    mp += 64;
    s0 += uph(u0, hi); s1 += uph(u1, hi); s2 += uph(u2, hi); s3 += uph(u3, hi);
  }
  for (; p < bseg; p++) { s0 += uph(mp[0], hi); mp += 16; }
  float s = (s0 + s1) + (s2 + s3);
  xs[node][o] = fmaxf(s * invdeg[n], 0.0f);
  float hval = h[(size_t)n * H + o];
  hsm[node][o] = hval;
  __syncthreads();
  float gi0 = bih[o], gi1 = bih[H + o], gi2 = bih[2 * H + o];
  float gh0 = bhh[o], gh1 = bhh[H + o], gh2 = bhh[2 * H + o];
#pragma unroll
  for (int i = 0; i < H; i++) {
    float xi = xs[node][i], hi_ = hsm[node][i];
    gi0 += xi * Wis[o][i];
    gh0 += hi_ * Whs[o][i];
    gi1 += xi * Wis[H + o][i];
    gh1 += hi_ * Whs[H + o][i];
    gi2 += xi * Wis[2 * H + o][i];
    gh2 += hi_ * Whs[2 * H + o][i];
  }
  float rg = fast_sigmoid(gi0 + gh0);
  float zg = fast_sigmoid(gi1 + gh1);
  float ng = fast_tanh(gi2 + rg * gh2);
  h[(size_t)n * H + o] = (1.0f - zg) * ng + zg * hval;
}

// ---------------- fallback GRU reading agg (8 nodes/block) ----------------
__global__ __launch_bounds__(256) void gru_update(const float* __restrict__ agg,
    const float* __restrict__ invdeg, const float* __restrict__ Wih,
    const float* __restrict__ Whh, const float* __restrict__ bih,
    const float* __restrict__ bhh, float* __restrict__ h) {
  __shared__ float Wis[3 * H][H + 1];
  __shared__ float Whs[3 * H][H + 1];
  __shared__ float xs[8][H + 1];
  __shared__ float hsm[8][H + 1];
  int tid = threadIdx.x;
  for (int v = tid; v < 3 * H * H; v += 256) {
    int k = v / H, i = v % H;
    Wis[k][i] = Wih[v];
    Whs[k][i] = Whh[v];
  }
  int node = tid >> 5, o = tid & 31;
  int n = blockIdx.x * 8 + node;
  xs[node][o] = fmaxf(agg[(size_t)n * H + o] * invdeg[n], 0.0f);
  float hval = h[(size_t)n * H + o];
  hsm[node][o] = hval;
  __syncthreads();
  float gi0 = bih[o], gi1 = bih[H + o], gi2 = bih[2 * H + o];
  float gh0 = bhh[o], gh1 = bhh[H + o], gh2 = bhh[2 * H + o];
#pragma unroll
  for (int i = 0; i < H; i++) {
    float xi = xs[node][i], hi_ = hsm[node][i];
    gi0 += xi * Wis[o][i];
    gh0 += hi_ * Whs[o][i];
    gi1 += xi * Wis[H + o][i];
    gh1 += hi_ * Whs[H + o][i];
    gi2 += xi * Wis[2 * H + o][i];
    gh2 += hi_ * Whs[2 * H + o][i];
  }
  float rg = fast_sigmoid(gi0 + gh0);
  float zg = fast_sigmoid(gi1 + gh1);
  float ng = fast_tanh(gi2 + rg * gh2);
  h[(size_t)n * H + o] = (1.0f - zg) * ng + zg * hval;
}

// ---------------- graph mean readout: segmented (gid sorted), no atomics -----------
__global__ __launch_bounds__(256) void readout_graph(const float* __restrict__ h,
    const int* __restrict__ gstart, float* __restrict__ out) {
  __shared__ float red[8][H + 1];
  int g = blockIdx.x;
  int a = gstart[g], b = gstart[g + 1];
  int r = threadIdx.x >> 5, o = threadIdx.x & 31;
  float s = 0.0f;
  for (int n = a + r; n < b; n += 8) s += h[(size_t)n * H + o];
  red[r][o] = s;
  __syncthreads();
  if (r == 0) {
    float t = 0.0f;
#pragma unroll
    for (int k = 0; k < 8; k++) t += red[k][o];
    out[g * H + o] = t / fmaxf((float)(b - a), 1.0f);
  }
}

extern "C" void kernel_launch(void* const* d_in, const int* in_sizes, int n_in,
                              void* d_out, int out_size, void* d_ws, size_t ws_size,
                              hipStream_t stream) {
  const float* n_feat = (const float*)d_in[0];
  const float* e_feat = (const float*)d_in[1];
  const int*   src    = (const int*)d_in[2];
  const int*   dst    = (const int*)d_in[3];
  const int*   gid    = (const int*)d_in[4];
  const float* W_atom = (const float*)d_in[5];
  const float* b_atom = (const float*)d_in[6];
  const float* W_bond = (const float*)d_in[7];
  const float* b_bond = (const float*)d_in[8];
  const float* W_e1   = (const float*)d_in[9];
  const float* b_e1   = (const float*)d_in[10];
  const float* W_e2   = (const float*)d_in[11];
  const float* b_e2   = (const float*)d_in[12];
  const float* W_ih   = (const float*)d_in[13];
  const float* W_hh   = (const float*)d_in[14];
  const float* b_ih   = (const float*)d_in[15];
  const float* b_hh   = (const float*)d_in[16];
  float* out = (float*)d_out;

  // workspace carve-up
  char* ws = (char*)d_ws;
  size_t off = 0;
  float*        h      = (float*)(ws + off); off += (size_t)N_NODES * H * 4;     // 2.56 MB
  unsigned int* rh     = (unsigned int*)(ws + off); off += (size_t)N_EDGES * 16 * 4;  // 20.48 MB
  unsigned int* Th     = (unsigned int*)(ws + off); off += (size_t)N_NODES * 512 * 4; // 40.96 MB
  float*        hbias  = (float*)(ws + off); off += (size_t)N_NODES * H * 4;     // 2.56 MB
  int*   hist_s = (int*)(ws + off);   off += (size_t)N_NODES * 4;
  int*   hist_d = (int*)(ws + off);   off += (size_t)N_NODES * 4;
  int*   cur_s  = (int*)(ws + off);   off += (size_t)N_NODES * 4;
  int*   cur_d  = (int*)(ws + off);   off += (size_t)N_NODES * 4;
  int*   seg_s  = (int*)(ws + off);   off += (size_t)(N_NODES + 1) * 4;
  int*   seg_d  = (int*)(ws + off);   off += (size_t)(N_NODES + 1) * 4;
  float* invdeg = (float*)(ws + off); off += (size_t)N_NODES * 4;
  int*   part   = (int*)(ws + off);   off += (size_t)2 * SCP * 4;                // 162 KB
  int*   bsum   = (int*)(ws + off);   off += (size_t)2 * SCB * 4;
  int*   src_s  = (int*)(ws + off);   off += (size_t)N_EDGES * 4;                // 1.28 MB (fallback)
  int*   dst_s  = (int*)(ws + off);   off += (size_t)N_EDGES * 4;                // 1.28 MB (fallback)
  int*   dpos   = (int*)(ws + off);   off += (size_t)N_EDGES * 4;                // 1.28 MB
  int*   gstart = (int*)(ws + off);   off += (size_t)(NB + 1) * 4;
  float* agg    = (float*)(ws + off); off += (size_t)N_NODES * H * 4;            // 2.56 MB (fallback)
  unsigned int* msg_h = (unsigned int*)(ws + off); off += (size_t)N_EDGES * 16 * 4;   // 20.48 MB
  int use_msg = (ws_size >= off) ? 1 : 0;
  int* pos_s = (int*)Th;   // alias: pos_s only live before first compute_T

  // node embedding
  embed_nodes<<<N_NODES / 8, 256, 0, stream>>>(n_feat, W_atom, b_atom, h);

  // dual counting sort prep: histograms -> multi-block scans -> scatter
  hipMemsetAsync(hist_s, 0, (size_t)2 * N_NODES * 4, stream);  // hist_s+hist_d adjacent
  hist2<<<(N_EDGES + 255) / 256, 256, 0, stream>>>(src, dst, hist_s, hist_d);
  {
    dim3 gs(SCB, 2);
    scan_partial<<<gs, 256, 0, stream>>>(hist_s, hist_d, part, bsum);
    scan_tops<<<1, 256, 0, stream>>>(bsum, gid, gstart);
    scan_final<<<gs, 256, 0, stream>>>(part, bsum, hist_d, cur_s, cur_d,
                                       seg_s, seg_d, invdeg);
  }
  if (use_msg) {
    scatter2_fast<<<(N_EDGES + 255) / 256, 256, 0, stream>>>(src, dst, cur_s, cur_d,
                                                             pos_s, dpos);
  } else {
    scatter2_full<<<(N_EDGES + 255) / 256, 256, 0, stream>>>(src, dst, cur_s, cur_d,
                                                             src_s, dst_s, pos_s, dpos);
  }

  // edge-net first layer, original order in / src-sorted scatter out (layer-invariant)
  edge_r<<<N_EDGES / 32, 256, 0, stream>>>(e_feat, W_bond, b_bond, W_e1, b_e1,
                                           pos_s, rh);

  for (int layer = 0; layer < 2; layer++) {
    dim3 gT(N_NODES / 32, 4);
    compute_T_fused<<<gT, 256, 0, stream>>>(h, W_e2, b_e2, Th, hbias);
    if (use_msg) {
      edge_msg_seg<<<N_NODES / 8, 256, 0, stream>>>(rh, Th, hbias, seg_s,
                                                    dpos, msg_h);
      seg_gru<<<N_NODES / 8, 256, 0, stream>>>(msg_h, seg_d, invdeg,
                                               W_ih, W_hh, b_ih, b_hh, h);
    } else {
      hipMemsetAsync(agg, 0, (size_t)N_NODES * H * 4, stream);
      edge_msg_atomic<<<N_EDGES / 32, 256, 0, stream>>>(rh, Th, hbias, src_s, dst_s,
                                                        agg);
      gru_update<<<N_NODES / 8, 256, 0, stream>>>(agg, invdeg,
                                                  W_ih, W_hh, b_ih, b_hh, h);
    }
  }

  // graph mean readout (segmented, atomic-free)
  readout_graph<<<NB, 256, 0, stream>>>(h, gstart, out);
}

// Round 12
// 337.113 us; speedup vs baseline: 2.7628x; 1.1014x over previous
//
#include <hip/hip_runtime.h>
#include <hip/hip_fp16.h>
#include <math.h>

#define N_NODES 20000
#define N_EDGES 320000
#define NB 128
#define H 32
#define AF 64
#define BF 16
#define SCB 79           // scan blocks: ceil(20000/256)
#define SCP 20224        // padded per-pass partial size (79*256)

typedef _Float16 f16x2 __attribute__((ext_vector_type(2)));

__device__ __forceinline__ float fast_sigmoid(float x) {
  return 1.0f / (1.0f + __expf(-x));
}
__device__ __forceinline__ float fast_tanh(float x) {
  float e2 = __expf(2.0f * x);
  return 1.0f - 2.0f / (e2 + 1.0f);    // inf-safe
}
// pack two floats as fp16 pair (RNE cast, low = a)
__device__ __forceinline__ unsigned int pk2(float a, float b) {
  union { f16x2 h; unsigned int u; } p;
  p.h[0] = (_Float16)a;
  p.h[1] = (_Float16)b;
  return p.u;
}
// extract half 0/1 of an fp16 pair as float
__device__ __forceinline__ float uph(unsigned int u, int hi) {
  union { unsigned int u; f16x2 h; } x; x.u = u;
  return hi ? (float)x.h[1] : (float)x.h[0];
}
// fp16x2 dot with fp32 accumulate: c + a.x*b.x + a.y*b.y
__device__ __forceinline__ float dot2(unsigned int a, unsigned int b, float c) {
  union { unsigned int u; f16x2 h; } ua, ub;
  ua.u = a; ub.u = b;
#if __has_builtin(__builtin_amdgcn_fdot2)
  return __builtin_amdgcn_fdot2(ua.h, ub.h, c, false);
#else
  return c + (float)ua.h[0] * (float)ub.h[0] + (float)ua.h[1] * (float)ub.h[1];
#endif
}

// ---------------- node embedding: h = nf @ W_atom + b ----------------
__global__ __launch_bounds__(256) void embed_nodes(const float* __restrict__ nf,
    const float* __restrict__ W, const float* __restrict__ b, float* __restrict__ h) {
  __shared__ float Ws[AF * H];     // 8 KB
  __shared__ float nfs[8][AF];
  int tid = threadIdx.x;
  for (int v = tid; v < AF * H; v += 256) Ws[v] = W[v];
  int n0 = blockIdx.x * 8;
  for (int v = tid; v < 8 * AF; v += 256) {
    int nl = v / AF, k = v % AF;
    int n = n0 + nl;
    nfs[nl][k] = (n < N_NODES) ? nf[n * AF + k] : 0.0f;
  }
  __syncthreads();
  int nl = tid / H, o = tid % H;
  int n = n0 + nl;
  if (n >= N_NODES) return;
  float acc = b[o];
#pragma unroll
  for (int k = 0; k < AF; k++) acc += nfs[nl][k] * Ws[k * H + o];
  h[n * H + o] = acc;
}

// ---------------- pack We2 (+be2 as pseudo-slice 32) into fp16 i-pairs -------------
// Wp[j*512 + ip*32 + o] = (src[2ip*32+o], src[(2ip+1)*32+o]), src = We2 slice j or be2.
__global__ __launch_bounds__(256) void pack_We2(const float* __restrict__ We2,
    const float* __restrict__ be2, unsigned int* __restrict__ Wp) {
  int idx = blockIdx.x * 256 + threadIdx.x;
  if (idx >= 33 * 512) return;
  int j = idx >> 9, r = idx & 511;
  int ip = r >> 5, o = r & 31;
  const float* src = (j < 32) ? (We2 + (size_t)j * (H * H)) : be2;
  Wp[idx] = pk2(src[(2 * ip) * H + o], src[(2 * ip + 1) * H + o]);
}

// ---------------- histograms over src AND dst ----------------
__global__ void hist2(const int* __restrict__ src, const int* __restrict__ dst,
                      int* __restrict__ hsrc, int* __restrict__ hdst) {
  int e = blockIdx.x * 256 + threadIdx.x;
  if (e < N_EDGES) {
    atomicAdd(&hsrc[src[e]], 1);
    atomicAdd(&hdst[dst[e]], 1);
  }
}

// ---------------- multi-block exclusive scan ----------------
__global__ __launch_bounds__(256) void scan_partial(const int* __restrict__ hist_s,
    const int* __restrict__ hist_d, int* __restrict__ part, int* __restrict__ bsum) {
  __shared__ int wsums[4];
  int which = blockIdx.y;
  const int* __restrict__ hh = which ? hist_d : hist_s;
  int i = blockIdx.x * 256 + threadIdx.x;
  int v = (i < N_NODES) ? hh[i] : 0;
  int lane = threadIdx.x & 63, wid = threadIdx.x >> 6;
  int incl = v;
#pragma unroll
  for (int off = 1; off < 64; off <<= 1) {
    int t = __shfl_up(incl, off, 64);
    if (lane >= off) incl += t;
  }
  if (lane == 63) wsums[wid] = incl;
  __syncthreads();
  int woff = 0;
#pragma unroll
  for (int w = 0; w < 4; w++) if (w < wid) woff += wsums[w];
  part[which * SCP + i] = woff + incl - v;
  if (threadIdx.x == 0)
    bsum[which * SCB + blockIdx.x] = wsums[0] + wsums[1] + wsums[2] + wsums[3];
}

// tops scan + graph segment bounds (gid sorted) fused in one tiny block
__global__ __launch_bounds__(256) void scan_tops(int* __restrict__ bsum,
    const int* __restrict__ gid, int* __restrict__ gstart) {
  __shared__ int s[2 * SCB];
  int tid = threadIdx.x;
  if (tid < 2 * SCB) s[tid] = bsum[tid];
  if (tid < NB) {
    int g = tid;
    int lo = 0, hi = N_NODES;
    while (lo < hi) { int mid = (lo + hi) >> 1; if (gid[mid] < g) lo = mid + 1; else hi = mid; }
    gstart[g] = lo;
    if (g == 0) gstart[NB] = N_NODES;
  }
  __syncthreads();
  if (tid < 2) {
    int run = 0;
    for (int b = 0; b < SCB; b++) { int t = s[tid * SCB + b]; s[tid * SCB + b] = run; run += t; }
  }
  __syncthreads();
  if (tid < 2 * SCB) bsum[tid] = s[tid];
}

__global__ __launch_bounds__(256) void scan_final(const int* __restrict__ part,
    const int* __restrict__ bsum, const int* __restrict__ hist_d,
    int* __restrict__ cur_s, int* __restrict__ cur_d,
    int* __restrict__ seg_s, int* __restrict__ seg_d, float* __restrict__ inv_deg) {
  int which = blockIdx.y;
  int i = blockIdx.x * 256 + threadIdx.x;
  if (i >= N_NODES) return;
  int ex = part[which * SCP + i] + bsum[which * SCB + blockIdx.x];
  if (which == 0) {
    cur_s[i] = ex; seg_s[i] = ex;
    if (i == 0) seg_s[N_NODES] = N_EDGES;
  } else {
    cur_d[i] = ex; seg_d[i] = ex;
    inv_deg[i] = 1.0f / fmaxf((float)hist_d[i], 1.0f);
    if (i == 0) seg_d[N_NODES] = N_EDGES;
  }
}

// scatter (fast path): only dpos[ps] (scattered) + pos_s[e] (coalesced).
__global__ void scatter2_fast(const int* __restrict__ src, const int* __restrict__ dst,
    int* __restrict__ cur_s, int* __restrict__ cur_d,
    int* __restrict__ pos_s, int* __restrict__ dpos) {
  int e = blockIdx.x * 256 + threadIdx.x;
  if (e >= N_EDGES) return;
  int s = src[e], d = dst[e];
  int ps = atomicAdd(&cur_s[s], 1);
  int pd = atomicAdd(&cur_d[d], 1);
  dpos[ps] = pd;
  pos_s[e] = ps;
}

// scatter (fallback path): also materialize src_s/dst_s for the atomic kernel.
__global__ void scatter2_full(const int* __restrict__ src, const int* __restrict__ dst,
    int* __restrict__ cur_s, int* __restrict__ cur_d,
    int* __restrict__ src_s, int* __restrict__ dst_s,
    int* __restrict__ pos_s, int* __restrict__ dpos) {
  int e = blockIdx.x * 256 + threadIdx.x;
  if (e >= N_EDGES) return;
  int s = src[e], d = dst[e];
  int ps = atomicAdd(&cur_s[s], 1);
  int pd = atomicAdd(&cur_d[d], 1);
  src_s[ps] = s;
  dst_s[ps] = d;
  dpos[ps] = pd;
  pos_s[e] = ps;
}

// ---------------- edge hidden: rh = f16-packed relu((ef@Wb+bb)@We1+be1) ------------
// Original edge order in (coalesced), scatter-write to src-sorted slot pos_s[e].
__global__ __launch_bounds__(256) void edge_r(const float* __restrict__ ef,
    const float* __restrict__ Wb, const float* __restrict__ bb,
    const float* __restrict__ We1, const float* __restrict__ be1,
    const int* __restrict__ pos_s, unsigned int* __restrict__ rh) {
  __shared__ float Wbs[BF * H];           // 2 KB [k][o]
  __shared__ unsigned int W1p[16 * H];    // 2 KB [jp][o], fp16 pair over j
  __shared__ float efs[32 * 20];          // row stride 20: bank-rotated
  __shared__ unsigned int hbp[32 * 20];   // row stride 20: bank-rotated
  int tid = threadIdx.x;
  for (int v = tid; v < BF * H; v += 256) Wbs[v] = Wb[v];
  for (int v = tid; v < 16 * H; v += 256) {
    int jp = v >> 5, o = v & 31;
    W1p[v] = pk2(We1[(2 * jp) * H + o], We1[(2 * jp + 1) * H + o]);
  }
  int e0 = blockIdx.x * 32;
  if (tid < 128) {        // 32 edges x 16 floats = 128 float4, coalesced
    float4 d = ((const float4*)(ef + (size_t)e0 * BF))[tid];
    ((float4*)(efs + (tid >> 2) * 20))[tid & 3] = d;
  }
  __syncthreads();
  int el = tid >> 3, oq = tid & 7;
  const float4* Wb4 = (const float4*)Wbs;
  const float4* efv = (const float4*)(efs + el * 20);
  float4 hb = ((const float4*)bb)[oq];
#pragma unroll
  for (int kq = 0; kq < 4; kq++) {
    float4 e4 = efv[kq];
    float4 w;
    w = Wb4[(kq * 4 + 0) * 8 + oq];
    hb.x += e4.x * w.x; hb.y += e4.x * w.y; hb.z += e4.x * w.z; hb.w += e4.x * w.w;
    w = Wb4[(kq * 4 + 1) * 8 + oq];
    hb.x += e4.y * w.x; hb.y += e4.y * w.y; hb.z += e4.y * w.z; hb.w += e4.y * w.w;
    w = Wb4[(kq * 4 + 2) * 8 + oq];
    hb.x += e4.z * w.x; hb.y += e4.z * w.y; hb.z += e4.z * w.z; hb.w += e4.z * w.w;
    w = Wb4[(kq * 4 + 3) * 8 + oq];
    hb.x += e4.w * w.x; hb.y += e4.w * w.y; hb.z += e4.w * w.z; hb.w += e4.w * w.w;
  }
  ((uint2*)(hbp + el * 20))[oq] = make_uint2(pk2(hb.x, hb.y), pk2(hb.z, hb.w));
  __syncthreads();
  float4 acc = ((const float4*)be1)[oq];
  const uint4* hb4 = (const uint4*)(hbp + el * 20);
#pragma unroll
  for (int q = 0; q < 4; q++) {
    uint4 hp = hb4[q];                     // jp = 4q..4q+3, 8-lane broadcast
    uint4 w;
    w = ((const uint4*)(W1p + (4 * q + 0) * H))[oq];
    acc.x = dot2(hp.x, w.x, acc.x); acc.y = dot2(hp.x, w.y, acc.y);
    acc.z = dot2(hp.x, w.z, acc.z); acc.w = dot2(hp.x, w.w, acc.w);
    w = ((const uint4*)(W1p + (4 * q + 1) * H))[oq];
    acc.x = dot2(hp.y, w.x, acc.x); acc.y = dot2(hp.y, w.y, acc.y);
    acc.z = dot2(hp.y, w.z, acc.z); acc.w = dot2(hp.y, w.w, acc.w);
    w = ((const uint4*)(W1p + (4 * q + 2) * H))[oq];
    acc.x = dot2(hp.z, w.x, acc.x); acc.y = dot2(hp.z, w.y, acc.y);
    acc.z = dot2(hp.z, w.z, acc.z); acc.w = dot2(hp.z, w.w, acc.w);
    w = ((const uint4*)(W1p + (4 * q + 3) * H))[oq];
    acc.x = dot2(hp.w, w.x, acc.x); acc.y = dot2(hp.w, w.y, acc.y);
    acc.z = dot2(hp.w, w.z, acc.z); acc.w = dot2(hp.w, w.w, acc.w);
  }
  acc.x = fmaxf(acc.x, 0.0f); acc.y = fmaxf(acc.y, 0.0f);
  acc.z = fmaxf(acc.z, 0.0f); acc.w = fmaxf(acc.w, 0.0f);
  int ps = pos_s[e0 + el];
  uint2 st;
  st.x = pk2(acc.x, acc.y);     // jp = 2*oq
  st.y = pk2(acc.z, acc.w);     // jp = 2*oq+1
  ((uint2*)(rh + (size_t)ps * 16))[oq] = st;   // scattered 8B write: no latency stall
}

// ---------------- Th[n][jp][o] fp16 pairs over j; hbias fp32 ----------------
// grid (625, 4). Packed-Wp inner loop: 16 b128 LDS reads/slice/wave (was 32 fp32) —
// R11's compute_T was LDS-instruction-throughput bound.
__global__ __launch_bounds__(256) void compute_T_fused(const float* __restrict__ h,
    const unsigned int* __restrict__ Wp,
    unsigned int* __restrict__ Th, float* __restrict__ hbias) {
  __shared__ unsigned int Wall[9 * 512];   // 18.4 KB (8 slices + optional bias slice)
  __shared__ unsigned int hp[32 * 17];     // packed h i-pairs, stride 17
  int tid = threadIdx.x;
  int n0 = blockIdx.x * 32;
  int jb = blockIdx.y;
  int nslice = (jb == 3) ? 9 : 8;
  const uint4* Wsrc = (const uint4*)(Wp + (size_t)jb * 8 * 512);
#pragma unroll
  for (int v = 0; v < 4; v++) ((uint4*)Wall)[tid + v * 256] = Wsrc[tid + v * 256];
  if (jb == 3 && tid < 128)
    ((uint4*)(Wall + 8 * 512))[tid] = ((const uint4*)(Wp + 32 * 512))[tid];
  for (int v = tid; v < 512; v += 256) {
    int nl = v >> 4, ip = v & 15;
    float2 hv = ((const float2*)(h + (size_t)(n0 + nl) * H))[ip];
    hp[nl * 17 + ip] = pk2(hv.x, hv.y);
  }
  __syncthreads();
  int nl = tid >> 3, oq = tid & 7;
  unsigned int hreg[16];
#pragma unroll
  for (int ip = 0; ip < 16; ip++) hreg[ip] = hp[nl * 17 + ip];
  int n = n0 + nl;
  float4 pacc = make_float4(0.f, 0.f, 0.f, 0.f);
  for (int jj = 0; jj < nslice; jj++) {
    const uint4* W4 = (const uint4*)(Wall + jj * 512);
    float4 acc = make_float4(0.f, 0.f, 0.f, 0.f);
#pragma unroll
    for (int ip = 0; ip < 16; ip++) {
      unsigned int hpv = hreg[ip];
      uint4 w = W4[ip * 8 + oq];
      acc.x = dot2(hpv, w.x, acc.x);
      acc.y = dot2(hpv, w.y, acc.y);
      acc.z = dot2(hpv, w.z, acc.z);
      acc.w = dot2(hpv, w.w, acc.w);
    }
    int j = jb * 8 + jj;
    if (j < H) {
      if (jj & 1) {                       // j parity == jj parity (jb*8 even)
        uint4 st;
        st.x = pk2(pacc.x, acc.x);
        st.y = pk2(pacc.y, acc.y);
        st.z = pk2(pacc.z, acc.z);
        st.w = pk2(pacc.w, acc.w);
        ((uint4*)(Th + (size_t)n * 512 + (j >> 1) * 32))[oq] = st;
      } else {
        pacc = acc;
      }
    } else {
      ((float4*)(hbias + (size_t)n * H))[oq] = acc;
    }
  }
}

// ---------------- msg: block = 8 src-segments, fp16 T in LDS, dot2 inner loop ------
__global__ __launch_bounds__(256) void edge_msg_seg(const unsigned int* __restrict__ rh,
    const unsigned int* __restrict__ Th, const float* __restrict__ hbias,
    const int* __restrict__ seg_s, const int* __restrict__ dpos,
    unsigned int* __restrict__ msg_h) {
  __shared__ unsigned int Ts[8 * 512];  // 16 KB
  __shared__ float hb[8 * H];           // 1 KB
  __shared__ int sseg[9];
  int tid = threadIdx.x;
  int n0 = blockIdx.x * 8;              // 2500 * 8 == 20000
  const uint4* Tg = (const uint4*)(Th + (size_t)n0 * 512);
#pragma unroll
  for (int v = 0; v < 4; v++) ((uint4*)Ts)[tid + v * 256] = Tg[tid + v * 256];
  hb[tid] = hbias[(size_t)n0 * H + tid];
  if (tid < 9) sseg[tid] = seg_s[n0 + tid];
  __syncthreads();
  int lane = tid & 63, wid = tid >> 6;
  int el = lane >> 3, t = lane & 7;
  for (int s = 0; s < 8; s++) {
    int a = sseg[s], bnd = sseg[s + 1];
    const unsigned int* Trow = Ts + s * 512;
    float4 hbv = ((const float4*)(hb + s * H))[t];
    int ww = (wid + s) & 3;             // rotate wave->chunk mapping per segment
    for (int base = a + ww * 8; base < bnd; base += 32) {
      int e = base + el;
      bool valid = (e < bnd);
      int pd = 0;
      uint2 ru2 = make_uint2(0u, 0u);
      if (valid) {
        pd = dpos[e];
        ru2 = ((const uint2*)(rh + (size_t)e * 16))[t];
      }
      float4 acc = hbv;
#pragma unroll
      for (int jp = 0; jp < 16; jp++) {
        unsigned int mine = (jp & 1) ? ru2.y : ru2.x;
        unsigned int rj = (unsigned int)__shfl((int)mine, jp >> 1, 8);
        uint4 tw = ((const uint4*)(Trow + jp * 32))[t];
        acc.x = dot2(rj, tw.x, acc.x);
        acc.y = dot2(rj, tw.y, acc.y);
        acc.z = dot2(rj, tw.z, acc.z);
        acc.w = dot2(rj, tw.w, acc.w);
      }
      if (valid) {
        uint2 st;
        st.x = pk2(acc.x, acc.y);
        st.y = pk2(acc.z, acc.w);
        ((uint2*)(msg_h + (size_t)pd * 16))[t] = st;
      }
    }
  }
}

// ---------------- fallback: atomic scatter-add (if workspace too small) ------------
__global__ __launch_bounds__(256) void edge_msg_atomic(const unsigned int* __restrict__ rh,
    const unsigned int* __restrict__ Th, const float* __restrict__ hbias,
    const int* __restrict__ src_s, const int* __restrict__ dst_s,
    float* __restrict__ agg) {
  int tid = threadIdx.x;
  int e0 = blockIdx.x * 32;
  int el = tid >> 3, t = tid & 7;
  int e = e0 + el;
  int s = src_s[e], d = dst_s[e];
  uint2 ru2 = ((const uint2*)(rh + (size_t)e * 16))[t];
  float4 acc = ((const float4*)(hbias + (size_t)s * H))[t];
  const unsigned int* Trow = Th + (size_t)s * 512;
#pragma unroll
  for (int jp = 0; jp < 16; jp++) {
    unsigned int mine = (jp & 1) ? ru2.y : ru2.x;
    unsigned int rj = (unsigned int)__shfl((int)mine, jp >> 1, 8);
    uint4 tw = ((const uint4*)(Trow + jp * 32))[t];
    acc.x = dot2(rj, tw.x, acc.x);
    acc.y = dot2(rj, tw.y, acc.y);
    acc.z = dot2(rj, tw.z, acc.z);
    acc.w = dot2(rj, tw.w, acc.w);
  }
  float* ap = agg + (size_t)d * H + t * 4;
  atomicAdd(ap + 0, acc.x);
  atomicAdd(ap + 1, acc.y);
  atomicAdd(ap + 2, acc.z);
  atomicAdd(ap + 3, acc.w);
}

// ---------------- fused segment-reduce + mean + relu + GRU, 8 nodes/block ----------
// Reduce 8-deep (was 4): deg~16 -> 2 exposed latency rounds instead of 4.
__global__ __launch_bounds__(256) void seg_gru(const unsigned int* __restrict__ msg_h,
    const int* __restrict__ seg_d, const float* __restrict__ invdeg,
    const float* __restrict__ Wih, const float* __restrict__ Whh,
    const float* __restrict__ bih, const float* __restrict__ bhh,
    float* __restrict__ h) {
  __shared__ float Wis[3 * H][H + 1];   // 12.4 KB
  __shared__ float Whs[3 * H][H + 1];   // 12.4 KB
  __shared__ float xs[8][H + 1];
  __shared__ float hsm[8][H + 1];
  int tid = threadIdx.x;
  for (int v = tid; v < 3 * H * H; v += 256) {
    int k = v / H, i = v % H;
    Wis[k][i] = Wih[v];
    Whs[k][i] = Whh[v];
  }
  int node = tid >> 5, o = tid & 31;
  int n = blockIdx.x * 8 + node;        // 2500*8 == 20000 exactly
  int a = seg_d[n], bseg = seg_d[n + 1];
  int hi = o & 1;
  const unsigned int* mp = msg_h + (size_t)a * 16 + (o >> 1);
  float s0 = 0.f, s1 = 0.f, s2 = 0.f, s3 = 0.f;
  float s4 = 0.f, s5 = 0.f, s6 = 0.f, s7 = 0.f;
  int p = a;
  for (; p + 8 <= bseg; p += 8) {
    unsigned int u0 = mp[0],  u1 = mp[16], u2 = mp[32], u3 = mp[48];
    unsigned int u4 = mp[64], u5 = mp[80], u6 = mp[96], u7 = mp[112];
    mp += 128;
    s0 += uph(u0, hi); s1 += uph(u1, hi); s2 += uph(u2, hi); s3 += uph(u3, hi);
    s4 += uph(u4, hi); s5 += uph(u5, hi); s6 += uph(u6, hi); s7 += uph(u7, hi);
  }
  for (; p + 2 <= bseg; p += 2) {
    unsigned int u0 = mp[0], u1 = mp[16];
    mp += 32;
    s0 += uph(u0, hi); s1 += uph(u1, hi);
  }
  if (p < bseg) s0 += uph(mp[0], hi);
  float s = ((s0 + s1) + (s2 + s3)) + ((s4 + s5) + (s6 + s7));
  xs[node][o] = fmaxf(s * invdeg[n], 0.0f);
  float hval = h[(size_t)n * H + o];
  hsm[node][o] = hval;
  __syncthreads();
  float gi0 = bih[o], gi1 = bih[H + o], gi2 = bih[2 * H + o];
  float gh0 = bhh[o], gh1 = bhh[H + o], gh2 = bhh[2 * H + o];
#pragma unroll
  for (int i = 0; i < H; i++) {
    float xi = xs[node][i], hi_ = hsm[node][i];
    gi0 += xi * Wis[o][i];
    gh0 += hi_ * Whs[o][i];
    gi1 += xi * Wis[H + o][i];
    gh1 += hi_ * Whs[H + o][i];
    gi2 += xi * Wis[2 * H + o][i];
    gh2 += hi_ * Whs[2 * H + o][i];
  }
  float rg = fast_sigmoid(gi0 + gh0);
  float zg = fast_sigmoid(gi1 + gh1);
  float ng = fast_tanh(gi2 + rg * gh2);
  h[(size_t)n * H + o] = (1.0f - zg) * ng + zg * hval;
}

// ---------------- fallback GRU reading agg (8 nodes/block) ----------------
__global__ __launch_bounds__(256) void gru_update(const float* __restrict__ agg,
    const float* __restrict__ invdeg, const float* __restrict__ Wih,
    const float* __restrict__ Whh, const float* __restrict__ bih,
    const float* __restrict__ bhh, float* __restrict__ h) {
  __shared__ float Wis[3 * H][H + 1];
  __shared__ float Whs[3 * H][H + 1];
  __shared__ float xs[8][H + 1];
  __shared__ float hsm[8][H + 1];
  int tid = threadIdx.x;
  for (int v = tid; v < 3 * H * H; v += 256) {
    int k = v / H, i = v % H;
    Wis[k][i] = Wih[v];
    Whs[k][i] = Whh[v];
  }
  int node = tid >> 5, o = tid & 31;
  int n = blockIdx.x * 8 + node;
  xs[node][o] = fmaxf(agg[(size_t)n * H + o] * invdeg[n], 0.0f);
  float hval = h[(size_t)n * H + o];
  hsm[node][o] = hval;
  __syncthreads();
  float gi0 = bih[o], gi1 = bih[H + o], gi2 = bih[2 * H + o];
  float gh0 = bhh[o], gh1 = bhh[H + o], gh2 = bhh[2 * H + o];
#pragma unroll
  for (int i = 0; i < H; i++) {
    float xi = xs[node][i], hi_ = hsm[node][i];
    gi0 += xi * Wis[o][i];
    gh0 += hi_ * Whs[o][i];
    gi1 += xi * Wis[H + o][i];
    gh1 += hi_ * Whs[H + o][i];
    gi2 += xi * Wis[2 * H + o][i];
    gh2 += hi_ * Whs[2 * H + o][i];
  }
  float rg = fast_sigmoid(gi0 + gh0);
  float zg = fast_sigmoid(gi1 + gh1);
  float ng = fast_tanh(gi2 + rg * gh2);
  h[(size_t)n * H + o] = (1.0f - zg) * ng + zg * hval;
}

// ---------------- graph mean readout: segmented (gid sorted), no atomics -----------
__global__ __launch_bounds__(256) void readout_graph(const float* __restrict__ h,
    const int* __restrict__ gstart, float* __restrict__ out) {
  __shared__ float red[8][H + 1];
  int g = blockIdx.x;
  int a = gstart[g], b = gstart[g + 1];
  int r = threadIdx.x >> 5, o = threadIdx.x & 31;
  float s = 0.0f;
  for (int n = a + r; n < b; n += 8) s += h[(size_t)n * H + o];
  red[r][o] = s;
  __syncthreads();
  if (r == 0) {
    float t = 0.0f;
#pragma unroll
    for (int k = 0; k < 8; k++) t += red[k][o];
    out[g * H + o] = t / fmaxf((float)(b - a), 1.0f);
  }
}

extern "C" void kernel_launch(void* const* d_in, const int* in_sizes, int n_in,
                              void* d_out, int out_size, void* d_ws, size_t ws_size,
                              hipStream_t stream) {
  const float* n_feat = (const float*)d_in[0];
  const float* e_feat = (const float*)d_in[1];
  const int*   src    = (const int*)d_in[2];
  const int*   dst    = (const int*)d_in[3];
  const int*   gid    = (const int*)d_in[4];
  const float* W_atom = (const float*)d_in[5];
  const float* b_atom = (const float*)d_in[6];
  const float* W_bond = (const float*)d_in[7];
  const float* b_bond = (const float*)d_in[8];
  const float* W_e1   = (const float*)d_in[9];
  const float* b_e1   = (const float*)d_in[10];
  const float* W_e2   = (const float*)d_in[11];
  const float* b_e2   = (const float*)d_in[12];
  const float* W_ih   = (const float*)d_in[13];
  const float* W_hh   = (const float*)d_in[14];
  const float* b_ih   = (const float*)d_in[15];
  const float* b_hh   = (const float*)d_in[16];
  float* out = (float*)d_out;

  // workspace carve-up
  char* ws = (char*)d_ws;
  size_t off = 0;
  float*        h      = (float*)(ws + off); off += (size_t)N_NODES * H * 4;     // 2.56 MB
  unsigned int* rh     = (unsigned int*)(ws + off); off += (size_t)N_EDGES * 16 * 4;  // 20.48 MB
  unsigned int* Th     = (unsigned int*)(ws + off); off += (size_t)N_NODES * 512 * 4; // 40.96 MB
  float*        hbias  = (float*)(ws + off); off += (size_t)N_NODES * H * 4;     // 2.56 MB
  unsigned int* Wp     = (unsigned int*)(ws + off); off += (size_t)33 * 512 * 4; // 67.6 KB
  int*   hist_s = (int*)(ws + off);   off += (size_t)N_NODES * 4;
  int*   hist_d = (int*)(ws + off);   off += (size_t)N_NODES * 4;
  int*   cur_s  = (int*)(ws + off);   off += (size_t)N_NODES * 4;
  int*   cur_d  = (int*)(ws + off);   off += (size_t)N_NODES * 4;
  int*   seg_s  = (int*)(ws + off);   off += (size_t)(N_NODES + 1) * 4;
  int*   seg_d  = (int*)(ws + off);   off += (size_t)(N_NODES + 1) * 4;
  float* invdeg = (float*)(ws + off); off += (size_t)N_NODES * 4;
  int*   part   = (int*)(ws + off);   off += (size_t)2 * SCP * 4;                // 162 KB
  int*   bsum   = (int*)(ws + off);   off += (size_t)2 * SCB * 4;
  int*   src_s  = (int*)(ws + off);   off += (size_t)N_EDGES * 4;                // 1.28 MB (fallback)
  int*   dst_s  = (int*)(ws + off);   off += (size_t)N_EDGES * 4;                // 1.28 MB (fallback)
  int*   dpos   = (int*)(ws + off);   off += (size_t)N_EDGES * 4;                // 1.28 MB
  int*   gstart = (int*)(ws + off);   off += (size_t)(NB + 1) * 4;
  float* agg    = (float*)(ws + off); off += (size_t)N_NODES * H * 4;            // 2.56 MB (fallback)
  unsigned int* msg_h = (unsigned int*)(ws + off); off += (size_t)N_EDGES * 16 * 4;   // 20.48 MB
  int use_msg = (ws_size >= off) ? 1 : 0;
  int* pos_s = (int*)Th;   // alias: pos_s only live before first compute_T

  // node embedding + weight packing (independent)
  embed_nodes<<<N_NODES / 8, 256, 0, stream>>>(n_feat, W_atom, b_atom, h);
  pack_We2<<<(33 * 512 + 255) / 256, 256, 0, stream>>>(W_e2, b_e2, Wp);

  // dual counting sort prep: histograms -> multi-block scans -> scatter
  hipMemsetAsync(hist_s, 0, (size_t)2 * N_NODES * 4, stream);  // hist_s+hist_d adjacent
  hist2<<<(N_EDGES + 255) / 256, 256, 0, stream>>>(src, dst, hist_s, hist_d);
  {
    dim3 gs(SCB, 2);
    scan_partial<<<gs, 256, 0, stream>>>(hist_s, hist_d, part, bsum);
    scan_tops<<<1, 256, 0, stream>>>(bsum, gid, gstart);
    scan_final<<<gs, 256, 0, stream>>>(part, bsum, hist_d, cur_s, cur_d,
                                       seg_s, seg_d, invdeg);
  }
  if (use_msg) {
    scatter2_fast<<<(N_EDGES + 255) / 256, 256, 0, stream>>>(src, dst, cur_s, cur_d,
                                                             pos_s, dpos);
  } else {
    scatter2_full<<<(N_EDGES + 255) / 256, 256, 0, stream>>>(src, dst, cur_s, cur_d,
                                                             src_s, dst_s, pos_s, dpos);
  }

  // edge-net first layer, original order in / src-sorted scatter out (layer-invariant)
  edge_r<<<N_EDGES / 32, 256, 0, stream>>>(e_feat, W_bond, b_bond, W_e1, b_e1,
                                           pos_s, rh);

  for (int layer = 0; layer < 2; layer++) {
    dim3 gT(N_NODES / 32, 4);
    compute_T_fused<<<gT, 256, 0, stream>>>(h, Wp, Th, hbias);
    if (use_msg) {
      edge_msg_seg<<<N_NODES / 8, 256, 0, stream>>>(rh, Th, hbias, seg_s,
                                                    dpos, msg_h);
      seg_gru<<<N_NODES / 8, 256, 0, stream>>>(msg_h, seg_d, invdeg,
                                               W_ih, W_hh, b_ih, b_hh, h);
    } else {
      hipMemsetAsync(agg, 0, (size_t)N_NODES * H * 4, stream);
      edge_msg_atomic<<<N_EDGES / 32, 256, 0, stream>>>(rh, Th, hbias, src_s, dst_s,
                                                        agg);
      gru_update<<<N_NODES / 8, 256, 0, stream>>>(agg, invdeg,
                                                  W_ih, W_hh, b_ih, b_hh, h);
    }
  }

  // graph mean readout (segmented, atomic-free)
  readout_graph<<<NB, 256, 0, stream>>>(h, gstart, out);
}